// Round 11
// baseline (278.178 us; speedup 1.0000x reference)
//
#include <hip/hip_runtime.h>
#include <hip/hip_bf16.h>

#define HW 9216
#define NPX 36864

typedef __attribute__((ext_vector_type(8))) short short8;
typedef __attribute__((ext_vector_type(4))) float f32x4;

static __device__ __forceinline__ unsigned short f2bf(float x) {
    union { __hip_bfloat16 h; unsigned short u; } c; c.h = __float2bfloat16(x); return c.u;
}
static __device__ __forceinline__ float bfl(unsigned int u){ return __uint_as_float(u << 16); }
static __device__ __forceinline__ float bfh(unsigned int u){ return __uint_as_float(u & 0xffff0000u); }

// ---------- weight pre-transposes ----------
__global__ __launch_bounds__(256) void prep_weights(
    const float* __restrict__ rw, const float* __restrict__ vw0,
    const float* __restrict__ vw1, const float* __restrict__ vw2,
    const float* __restrict__ fw,
    float* __restrict__ rwT, unsigned short* __restrict__ vwF, unsigned short* __restrict__ fwF)
{
    int idx = blockIdx.x * 256 + threadIdx.x;
    if (idx < 8192) {                       // reduce_w (64,128) -> rwT[i][c]
        int c = idx & 63, i = idx >> 6;
        rwT[idx] = rw[c * 128 + i];
    } else if (idx < 20480) {               // v_w -> MFMA B-fragment order vwF[lvl][nt][kf][lane][j]
        int e = idx - 8192;
        int j = e & 7, lane = (e >> 3) & 63, kf = (e >> 9) & 1, nt = (e >> 10) & 3, lvl = e >> 12;
        int co = nt * 16 + (lane & 15);
        int k = kf * 32 + (lane >> 4) * 8 + j;
        const float* vw = (lvl == 0) ? vw0 : ((lvl == 1) ? vw1 : vw2);
        vwF[e] = f2bf(vw[co * 64 + k]);
    } else if (idx < 167936) {              // fusion_w (64,256,3,3) -> B-fragment order fwF[kc][nt][lane][j]
        int e = idx - 20480;
        int j = e & 7, lane = (e >> 3) & 63, nt = (e >> 9) & 3, kc = e >> 11;   // kc in 0..71
        int co = nt * 16 + (lane & 15);
        int k = kc * 32 + ((lane >> 4) << 3) + j;   // global K index: tap*256 + ci
        int tap = k >> 8, ci = k & 255;
        fwF[e] = f2bf(fw[co * 2304 + ci * 9 + tap]);
    }
}

// ---------- transpose key->qT (NHWC fp32) and sup->fused[ch 0:64] (bf16) ----------
__global__ void pack_kernel(const float* __restrict__ key, const float* __restrict__ sup,
                            float* __restrict__ qT, __hip_bfloat16* __restrict__ fused)
{
    __shared__ float lk[32][33], ls[32][33];
    int tx = threadIdx.x, ty = threadIdx.y;
    int x0 = blockIdx.x * 32, c0 = blockIdx.y * 32;
    int z = blockIdx.z; int b = z / 96, y = z - b * 96;
    #pragma unroll
    for (int i = 0; i < 32; i += 8) {
        int c = c0 + ty + i;
        lk[ty + i][tx] = key[((b * 64 + c) * 96 + y) * 96 + x0 + tx];
        ls[ty + i][tx] = sup[((b * 64 + c) * 96 + y) * 96 + x0 + tx];
    }
    __syncthreads();
    #pragma unroll
    for (int i = 0; i < 32; i += 8) {
        int px = (b * 96 + y) * 96 + x0 + ty + i;
        qT[px * 64 + c0 + tx]     = lk[tx][ty + i];
        fused[px * 256 + c0 + tx] = __hip_bfloat16(ls[tx][ty + i]);
    }
}

// ---------- shifted grouped 3x3 conv, LDS-staged, wave-uniform out-channel ----------
__global__ __launch_bounds__(256) void shift_smooth(const float* __restrict__ sup,
    const float* __restrict__ w, const float* __restrict__ bias, float* __restrict__ smooth)
{
    __shared__ __align__(16) float tile[8][34][36];
    int bid = blockIdx.x;                 // 576 = 4b * 8grp * 9sj * 2half
    int half = bid & 1;
    int sj   = (bid >> 1) % 9;
    int grp  = (bid / 18) & 7;
    int b    = bid / 144;
    int sby = sj / 3, sbx = sj % 3;
    int Y0 = sby * 32, X0 = sbx * 32;
    int sh = 3 * ((grp >= 5) - (grp < 3));
    int mm = (grp < 3) ? grp : ((grp < 5) ? ((grp == 3) ? 0 : 2) : (grp - 5));
    int sw = 3 * mm - 3;
    int t = threadIdx.x;

    const float* supg = sup + (size_t)(b * 64 + grp * 8) * HW;
    #pragma unroll
    for (int pp = 0; pp < 5; pp++) {
        int pos = pp * 256 + t;
        if (pos < 1156) {
            int r = pos / 34, u = pos - r * 34;
            int yy = Y0 - 1 + r, xx = X0 - 1 + u;
            int ys = yy - sh, xs = xx - sw;
            bool ok = (yy >= 0) & (yy < 96) & (xx >= 0) & (xx < 96) &
                      (ys >= 0) & (ys < 96) & (xs >= 0) & (xs < 96);
            int addr = ok ? (ys * 96 + xs) : 0;
            #pragma unroll
            for (int ic = 0; ic < 8; ic++) {
                float v = supg[(size_t)ic * HW + addr];
                tile[ic][r][u] = ok ? v : 0.f;
            }
        }
    }
    __syncthreads();

    int c = __builtin_amdgcn_readfirstlane(grp * 8 + half * 4 + (t >> 6));
    int lane = t & 63;
    int ty4 = lane >> 3, tx4 = lane & 7;
    int py0 = ty4 * 4, x0r = tx4 * 4;

    float bz = bias[c];
    float acc[4][4];
    #pragma unroll
    for (int jr = 0; jr < 4; jr++)
        #pragma unroll
        for (int j = 0; j < 4; j++) acc[jr][j] = bz;

    const float* wp = w + c * 72;
    for (int ic = 0; ic < 8; ic++) {
        float wr[9];
        #pragma unroll
        for (int q = 0; q < 9; q++) wr[q] = wp[ic * 9 + q];
        #pragma unroll
        for (int rr = 0; rr < 6; rr++) {
            float4 fa = *(const float4*)&tile[ic][py0 + rr][x0r];
            float4 fb4 = *(const float4*)&tile[ic][py0 + rr][x0r + 4];
            float f[6] = {fa.x, fa.y, fa.z, fa.w, fb4.x, fb4.y};
            #pragma unroll
            for (int ky = 0; ky < 3; ky++) {
                int jr = rr - ky;
                if (jr >= 0 && jr < 4) {
                    #pragma unroll
                    for (int j = 0; j < 4; j++)
                        acc[jr][j] += wr[ky*3]*f[j] + wr[ky*3+1]*f[j+1] + wr[ky*3+2]*f[j+2];
                }
            }
        }
    }

    float* op = smooth + ((size_t)(b * 64 + c) * 96 + Y0 + py0) * 96 + X0 + x0r;
    #pragma unroll
    for (int jr = 0; jr < 4; jr++) {
        float4 st = {acc[jr][0], acc[jr][1], acc[jr][2], acc[jr][3]};
        *(float4*)(op + (size_t)jr * 96) = st;
    }
}

// ---------- 1x1 reduce conv (128->64): weights in LDS (broadcast), px per lane ----------
__global__ __launch_bounds__(256) void reduce_kernel(const float* __restrict__ sup,
    const float* __restrict__ smooth, const float* __restrict__ rwT,
    const float* __restrict__ rb, float* __restrict__ sup2)
{
    __shared__ __align__(16) float wlds[8192];   // rwT[i][c], 32 KB
    int t = threadIdx.x;
    #pragma unroll
    for (int e = 0; e < 8; e++) {
        int idx = (e * 256 + t) * 4;
        *(float4*)&wlds[idx] = *(const float4*)&rwT[idx];
    }
    __syncthreads();

    int lane = t & 63, wq = t >> 6;
    int px = blockIdx.x * 64 + lane;
    int b = px / HW; int rem = px - b * HW;
    const float* s1 = sup + (size_t)b * 64 * HW + rem;
    const float* s2 = smooth + (size_t)b * 64 * HW + rem;
    float acc[16];
    #pragma unroll
    for (int j = 0; j < 16; j++) acc[j] = rb[wq * 16 + j];

    #pragma unroll 8
    for (int i = 0; i < 64; i++) {
        float v = s1[i * HW];
        const float* wr = &wlds[i * 64 + wq * 16];
        float4 w0 = *(const float4*)wr, w1 = *(const float4*)(wr + 4);
        float4 w2 = *(const float4*)(wr + 8), w3 = *(const float4*)(wr + 12);
        acc[0] += w0.x * v;  acc[1] += w0.y * v;  acc[2] += w0.z * v;  acc[3] += w0.w * v;
        acc[4] += w1.x * v;  acc[5] += w1.y * v;  acc[6] += w1.z * v;  acc[7] += w1.w * v;
        acc[8] += w2.x * v;  acc[9] += w2.y * v;  acc[10] += w2.z * v; acc[11] += w2.w * v;
        acc[12] += w3.x * v; acc[13] += w3.y * v; acc[14] += w3.z * v; acc[15] += w3.w * v;
    }
    #pragma unroll 8
    for (int i = 0; i < 64; i++) {
        float v = s2[i * HW];
        const float* wr = &wlds[(64 + i) * 64 + wq * 16];
        float4 w0 = *(const float4*)wr, w1 = *(const float4*)(wr + 4);
        float4 w2 = *(const float4*)(wr + 8), w3 = *(const float4*)(wr + 12);
        acc[0] += w0.x * v;  acc[1] += w0.y * v;  acc[2] += w0.z * v;  acc[3] += w0.w * v;
        acc[4] += w1.x * v;  acc[5] += w1.y * v;  acc[6] += w1.z * v;  acc[7] += w1.w * v;
        acc[8] += w2.x * v;  acc[9] += w2.y * v;  acc[10] += w2.z * v; acc[11] += w2.w * v;
        acc[12] += w3.x * v; acc[13] += w3.y * v; acc[14] += w3.z * v; acc[15] += w3.w * v;
    }

    float* op = sup2 + (size_t)px * 64 + wq * 16;
    #pragma unroll
    for (int j = 0; j < 16; j += 4) { float4 st = {acc[j], acc[j+1], acc[j+2], acc[j+3]}; *(float4*)(op + j) = st; }
}

// ---------- fused 3-level neighborhood attention (8 threads/px) ----------
// block = 8x4 px tile, 256 thr: pxl = wv*8 + (lane&7), qc = lane>>3 (8 ch-chunks)
template<int KS>
__device__ __forceinline__ void level_softmax(int qc, int y, int x, int ni7, int nj7,
        const _Float16* rpbl, const _Float16* dots_row, _Float16* out_row)
{
    constexpr int R = KS / 2, KK = KS * KS, NB = 2 * KS - 1;
    constexpr int NE = (KK + 7) / 8;
    int ni = min(max(y - R, 0), 96 - KS), nj = min(max(x - R, 0), 96 - KS);
    int di = ni - ni7, dj = nj - nj7;
    int br = KS - 1 + ni - y, bc = KS - 1 + nj - x;
    float sv[NE];
    float mx = -1e30f;
    #pragma unroll
    for (int i = 0; i < NE; i++) {
        int e = qc + i * 8;
        if (e < KK) {
            int ey = e / KS, ex = e - ey * KS;
            float s = (float)dots_row[(di + ey) * 7 + dj + ex] + (float)rpbl[(br + ey) * NB + bc + ex];
            sv[i] = s; mx = fmaxf(mx, s);
        } else sv[i] = -1e30f;
    }
    mx = fmaxf(mx, __shfl_xor(mx, 8)); mx = fmaxf(mx, __shfl_xor(mx, 16)); mx = fmaxf(mx, __shfl_xor(mx, 32));
    float sum = 0.f;
    #pragma unroll
    for (int i = 0; i < NE; i++) { sv[i] = __expf(sv[i] - mx); sum += sv[i]; }
    sum += __shfl_xor(sum, 8); sum += __shfl_xor(sum, 16); sum += __shfl_xor(sum, 32);
    float inv = 1.f / sum;
    #pragma unroll
    for (int i = 0; i < NE; i++) {
        int e = qc + i * 8;
        if (e < KK) out_row[e] = (_Float16)(sv[i] * inv);
    }
}

__global__ __launch_bounds__(256) void natten_fused(
    const float* __restrict__ qT, const float* __restrict__ sup2,
    const unsigned short* __restrict__ vwF,
    const float* __restrict__ vb0, const float* __restrict__ vb1, const float* __restrict__ vb2,
    const float* __restrict__ rpb0, const float* __restrict__ rpb1, const float* __restrict__ rpb2,
    __hip_bfloat16* __restrict__ fused)
{
    __shared__ __align__(16) unsigned short khalo[140 * 72];  // 20160 B; reused as sproj[3][32][72]
    __shared__ _Float16 dots[32][52];                         // 3328 B
    __shared__ _Float16 a3[32][12];                           // 768 B
    __shared__ _Float16 a5[32][28];                           // 1792 B
    __shared__ _Float16 rlds[276];                            // 552 B

    int t = threadIdx.x;
    int bb = blockIdx.y;
    int tx0 = (blockIdx.x % 12) * 8, ty0 = (blockIdx.x / 12) * 4;
    const float* kb = sup2 + (size_t)bb * HW * 64;

    // stage rpb tables (fp16): [0:169)=rpb2, [169:250)=rpb1, [250:275)=rpb0
    for (int e = t; e < 275; e += 256) {
        float v = (e < 169) ? rpb2[e] : ((e < 250) ? rpb1[e - 169] : rpb0[e - 250]);
        rlds[e] = (_Float16)v;
    }

    // stage 10x14 px halo (bf16, 64->72 ch pad): 140 px x 16 ch-quads = 2240 tasks
    for (int it = 0; it < 9; it++) {
        int qidx = it * 256 + t;
        if (qidx < 2240) {
            int cq = qidx & 15, pos = qidx >> 4;
            int py = pos / 14, pxx = pos - py * 14;
            int gy = min(max(ty0 - 3 + py, 0), 95);
            int gx = min(max(tx0 - 3 + pxx, 0), 95);
            float4 v = *(const float4*)(kb + (((size_t)gy * 96 + gx) << 6) + cq * 4);
            ushort4 pk = {f2bf(v.x), f2bf(v.y), f2bf(v.z), f2bf(v.w)};
            *(ushort4*)&khalo[pos * 72 + cq * 4] = pk;
        }
    }
    __syncthreads();

    int lane = t & 63, wv = t >> 6;
    int pxl = wv * 8 + (lane & 7);     // 0..31
    int qc = lane >> 3;                // 0..7 (8 channels each)
    int pty = pxl >> 3, ptx = pxl & 7; // 8 wide x 4 tall
    int y = ty0 + pty, x = tx0 + ptx;
    int gpx = bb * HW + y * 96 + x;

    float qv[8];
    {
        const float* qp = qT + (size_t)gpx * 64 + qc * 8;
        float4 q0 = *(const float4*)qp, q1 = *(const float4*)(qp + 4);
        qv[0] = q0.x; qv[1] = q0.y; qv[2] = q0.z; qv[3] = q0.w;
        qv[4] = q1.x; qv[5] = q1.y; qv[6] = q1.z; qv[7] = q1.w;
    }

    int ni7 = min(max(y - 3, 0), 89), nj7 = min(max(x - 3, 0), 89);
    int ly = ni7 - (ty0 - 3), lx = nj7 - (tx0 - 3);

    // 49 shared dots; each thread: 8-ch partial, reduce over qc (xor 8/16/32)
    for (int oy = 0; oy < 7; oy++) {
        #pragma unroll
        for (int ox = 0; ox < 7; ox++) {
            const unsigned short* kp = &khalo[((ly + oy) * 14 + lx + ox) * 72 + qc * 8];
            uint4 ka = *(const uint4*)kp;
            float p0 = qv[0]*bfl(ka.x) + qv[1]*bfh(ka.x) + qv[2]*bfl(ka.y) + qv[3]*bfh(ka.y);
            float p1 = qv[4]*bfl(ka.z) + qv[5]*bfh(ka.z) + qv[6]*bfl(ka.w) + qv[7]*bfh(ka.w);
            float d = p0 + p1;
            d += __shfl_xor(d, 8);
            d += __shfl_xor(d, 16);
            d += __shfl_xor(d, 32);
            if (qc == 0) dots[pxl][oy * 7 + ox] = (_Float16)d;
        }
    }

    level_softmax<3>(qc, y, x, ni7, nj7, rlds + 250, &dots[pxl][0], &a3[pxl][0]);
    level_softmax<5>(qc, y, x, ni7, nj7, rlds + 169, &dots[pxl][0], &a5[pxl][0]);
    level_softmax<7>(qc, y, x, ni7, nj7, rlds,       &dots[pxl][0], &dots[pxl][0]);

    int ni5 = min(max(y - 2, 0), 91), nj5 = min(max(x - 2, 0), 91);
    int ni3 = min(max(y - 1, 0), 93), nj3 = min(max(x - 1, 0), 93);
    int di5 = ni5 - ni7, dj5 = nj5 - nj7, di3 = ni3 - ni7, dj3 = nj3 - nj7;

    float s2[3][8];
    #pragma unroll
    for (int l = 0; l < 3; l++)
        #pragma unroll
        for (int j = 0; j < 8; j++) s2[l][j] = 0.f;

    for (int oy = 0; oy < 7; oy++) {
        #pragma unroll
        for (int ox = 0; ox < 7; ox++) {
            const unsigned short* kp = &khalo[((ly + oy) * 14 + lx + ox) * 72 + qc * 8];
            uint4 ka = *(const uint4*)kp;
            float kv[8] = {bfl(ka.x), bfh(ka.x), bfl(ka.y), bfh(ka.y),
                           bfl(ka.z), bfh(ka.z), bfl(ka.w), bfh(ka.w)};
            float w7 = (float)dots[pxl][oy * 7 + ox];
            #pragma unroll
            for (int j = 0; j < 8; j++) s2[2][j] += w7 * kv[j];
            int e5y = oy - di5, e5x = ox - dj5;
            if ((unsigned)e5y < 5u && (unsigned)e5x < 5u) {
                float w5 = (float)a5[pxl][e5y * 5 + e5x];
                #pragma unroll
                for (int j = 0; j < 8; j++) s2[1][j] += w5 * kv[j];
            }
            int e3y = oy - di3, e3x = ox - dj3;
            if ((unsigned)e3y < 3u && (unsigned)e3x < 3u) {
                float w3 = (float)a3[pxl][e3y * 3 + e3x];
                #pragma unroll
                for (int j = 0; j < 8; j++) s2[0][j] += w3 * kv[j];
            }
        }
    }
    __syncthreads();   // khalo reads done -> reuse as sproj

    unsigned short* sproj = khalo;   // [lvl*32 + pxl][72]
    #pragma unroll
    for (int l = 0; l < 3; l++) {
        unsigned int pk[4];
        #pragma unroll
        for (int j = 0; j < 4; j++)
            pk[j] = (unsigned int)f2bf(s2[l][2*j]) | ((unsigned int)f2bf(s2[l][2*j+1]) << 16);
        uint4 sv = {pk[0], pk[1], pk[2], pk[3]};
        *(uint4*)&sproj[(l * 32 + pxl) * 72 + qc * 8] = sv;
    }
    __syncthreads();

    // v-projection: wave wv (<3) does level wv's 32x64x64 GEMM (2 m-tiles x 4 nt x K=64)
    if (wv < 3) {
        int l = wv;
        int lm = lane & 15, quad = lane >> 4;
        const float* vbl = (l == 0) ? vb0 : ((l == 1) ? vb1 : vb2);
        #pragma unroll
        for (int mt = 0; mt < 2; mt++) {
            f32x4 acc[4];
            #pragma unroll
            for (int nt = 0; nt < 4; nt++) acc[nt] = (f32x4){0.f, 0.f, 0.f, 0.f};
            #pragma unroll
            for (int kf = 0; kf < 2; kf++) {
                short8 a = *(const short8*)&sproj[(l * 32 + mt * 16 + lm) * 72 + kf * 32 + quad * 8];
                #pragma unroll
                for (int nt = 0; nt < 4; nt++) {
                    short8 bfr = *(const short8*)&vwF[(((l * 4 + nt) * 2 + kf) * 64 + lane) * 8];
                    acc[nt] = __builtin_amdgcn_mfma_f32_16x16x32_bf16(a, bfr, acc[nt], 0, 0, 0);
                }
            }
            #pragma unroll
            for (int nt = 0; nt < 4; nt++)
                #pragma unroll
                for (int r = 0; r < 4; r++) {
                    int p = mt * 16 + quad * 4 + r;        // px in tile
                    int co = nt * 16 + lm;
                    int py = p >> 3, pxx = p & 7;
                    size_t off = ((size_t)(bb * HW + (ty0 + py) * 96 + tx0 + pxx) << 8) + (l + 1) * 64 + co;
                    fused[off] = __hip_bfloat16(acc[nt][r] + vbl[co]);
                }
        }
    }
}

// ---------- 3x3 fusion conv (256->64): LDS-staged implicit-GEMM bf16 MFMA ----------
__global__ __launch_bounds__(256) void fusion_mfma(
    const __hip_bfloat16* __restrict__ fB, const unsigned short* __restrict__ fwF,
    const float* __restrict__ fb, float* __restrict__ out)
{
    __shared__ __align__(16) unsigned short ah[108 * 72];   // 15552 B
    __shared__ float lds_out[64 * 66];                       // 16896 B
    int t = threadIdx.x;
    int wv = t >> 6, lane = t & 63, lm = lane & 15, quad = lane >> 4;
    int X0 = blockIdx.x * 16, Y0 = blockIdx.y * 4, b = blockIdx.z;
    const unsigned short* fBu = (const unsigned short*)fB;

    f32x4 acc[4] = {};

    for (int chunk = 0; chunk < 4; chunk++) {
        __syncthreads();
        #pragma unroll
        for (int ee = 0; ee < 4; ee++) {
            int e = ee * 256 + t;
            if (e < 864) {
                int seg = e & 7, hp = e >> 3;
                int hy = hp / 18, hx = hp - hy * 18;
                int gy = Y0 - 1 + hy, gx = X0 - 1 + hx;
                bool ok = (gy >= 0) & (gy < 96) & (gx >= 0) & (gx < 96);
                short8 v = {};
                if (ok) v = *(const short8*)(fBu + (((size_t)(b * HW + gy * 96 + gx)) << 8) + chunk * 64 + seg * 8);
                *(short8*)&ah[hp * 72 + seg * 8] = v;
            }
        }
        __syncthreads();
        #pragma unroll
        for (int ky = 0; ky < 3; ky++) {
            #pragma unroll
            for (int kx = 0; kx < 3; kx++) {
                #pragma unroll
                for (int kf = 0; kf < 2; kf++) {
                    short8 a = *(const short8*)&ah[((wv + ky) * 18 + lm + kx) * 72 + kf * 32 + quad * 8];
                    int kc = (ky * 3 + kx) * 8 + chunk * 2 + kf;
                    const unsigned short* bp = fwF + ((size_t)(kc * 4) * 64 + lane) * 8;
                    acc[0] = __builtin_amdgcn_mfma_f32_16x16x32_bf16(a, *(const short8*)(bp),        acc[0], 0, 0, 0);
                    acc[1] = __builtin_amdgcn_mfma_f32_16x16x32_bf16(a, *(const short8*)(bp + 512),  acc[1], 0, 0, 0);
                    acc[2] = __builtin_amdgcn_mfma_f32_16x16x32_bf16(a, *(const short8*)(bp + 1024), acc[2], 0, 0, 0);
                    acc[3] = __builtin_amdgcn_mfma_f32_16x16x32_bf16(a, *(const short8*)(bp + 1536), acc[3], 0, 0, 0);
                }
            }
        }
    }

    #pragma unroll
    for (int nt = 0; nt < 4; nt++)
        #pragma unroll
        for (int r = 0; r < 4; r++) {
            int p = wv * 16 + quad * 4 + r;
            int co = nt * 16 + lm;
            lds_out[co * 66 + p] = acc[nt][r];
        }
    __syncthreads();

    int p2 = t & 63, py = p2 >> 4, px2 = p2 & 15;
    float* ob = out + ((size_t)(b * 64) * 96 + Y0 + py) * 96 + X0 + px2;
    #pragma unroll 4
    for (int i = 0; i < 16; i++) {
        int co = (t >> 6) * 16 + i;
        float v = lds_out[co * 66 + p2] + fb[co];
        ob[(size_t)co * HW] = v > 0.f ? v : 0.f;
    }
}

extern "C" void kernel_launch(void* const* d_in, const int* in_sizes, int n_in,
                              void* d_out, int out_size, void* d_ws, size_t ws_size,
                              hipStream_t stream) {
    const float* sup = (const float*)d_in[0];
    const float* key = (const float*)d_in[1];
    const float* smw = (const float*)d_in[2];
    const float* smb = (const float*)d_in[3];
    const float* rw  = (const float*)d_in[4];
    const float* rb  = (const float*)d_in[5];
    const float *vw[3], *vb[3], *rpb[3];
    if (in_sizes[8] == 25) {
        for (int l = 0; l < 3; l++) {
            vw[l]  = (const float*)d_in[6 + 3 * l];
            vb[l]  = (const float*)d_in[7 + 3 * l];
            rpb[l] = (const float*)d_in[8 + 3 * l];
        }
    } else {
        for (int l = 0; l < 3; l++) {
            vw[l]  = (const float*)d_in[6 + 2 * l];
            vb[l]  = (const float*)d_in[7 + 2 * l];
            rpb[l] = (const float*)d_in[12 + l];
        }
    }
    const float* fw = (const float*)d_in[15];
    const float* fb = (const float*)d_in[16];
    float* out = (float*)d_out;

    float* wsf    = (float*)d_ws;
    float* smooth = wsf;                                    // 2359296 f
    float* sup2   = wsf + 2359296;                          // 2359296 f (NHWC)
    float* qT     = wsf + 4718592;                          // 2359296 f (NHWC)
    float* rwT    = wsf + 7077888;                          // 8192 f
    unsigned short* vwF = (unsigned short*)(wsf + 7086080); // 12288 bf16
    __hip_bfloat16* fusedB = (__hip_bfloat16*)(wsf + 7092224);  // 9437184 bf16
    unsigned short* fwF    = (unsigned short*)(wsf + 11810816); // 147456 bf16

    prep_weights<<<dim3(656), dim3(256), 0, stream>>>(rw, vw[0], vw[1], vw[2], fw, rwT, vwF, fwF);
    pack_kernel<<<dim3(3, 2, 384), dim3(32, 8), 0, stream>>>(key, sup, qT, fusedB);
    shift_smooth<<<dim3(576), dim3(256), 0, stream>>>(sup, smw, smb, smooth);
    reduce_kernel<<<dim3(576), dim3(256), 0, stream>>>(sup, smooth, rwT, rb, sup2);
    natten_fused<<<dim3(288, 4), dim3(256), 0, stream>>>(qT, sup2, vwF,
        vb[0], vb[1], vb[2], rpb[0], rpb[1], rpb[2], fusedB);
    fusion_mfma<<<dim3(6, 24, 4), dim3(256), 0, stream>>>(fusedB, fwF, fb, out);
}

// Round 12
// 222.709 us; speedup vs baseline: 1.2491x; 1.2491x over previous
//
#include <hip/hip_runtime.h>
#include <hip/hip_bf16.h>

#define HW 9216
#define NPX 36864

typedef __attribute__((ext_vector_type(8))) short short8;
typedef __attribute__((ext_vector_type(4))) float f32x4;

static __device__ __forceinline__ unsigned short f2bf(float x) {
    union { __hip_bfloat16 h; unsigned short u; } c; c.h = __float2bfloat16(x); return c.u;
}
static __device__ __forceinline__ float bfl(unsigned int u){ return __uint_as_float(u << 16); }
static __device__ __forceinline__ float bfh(unsigned int u){ return __uint_as_float(u & 0xffff0000u); }

// ---------- weight pre-transposes ----------
__global__ __launch_bounds__(256) void prep_weights(
    const float* __restrict__ rw, const float* __restrict__ vw0,
    const float* __restrict__ vw1, const float* __restrict__ vw2,
    const float* __restrict__ fw,
    float* __restrict__ rwT, unsigned short* __restrict__ vwF, unsigned short* __restrict__ fwF)
{
    int idx = blockIdx.x * 256 + threadIdx.x;
    if (idx < 8192) {                       // reduce_w (64,128) -> rwT[i][c]
        int c = idx & 63, i = idx >> 6;
        rwT[idx] = rw[c * 128 + i];
    } else if (idx < 20480) {               // v_w -> MFMA B-fragment order vwF[lvl][nt][kf][lane][j]
        int e = idx - 8192;
        int j = e & 7, lane = (e >> 3) & 63, kf = (e >> 9) & 1, nt = (e >> 10) & 3, lvl = e >> 12;
        int co = nt * 16 + (lane & 15);
        int k = kf * 32 + (lane >> 4) * 8 + j;
        const float* vw = (lvl == 0) ? vw0 : ((lvl == 1) ? vw1 : vw2);
        vwF[e] = f2bf(vw[co * 64 + k]);
    } else if (idx < 167936) {              // fusion_w (64,256,3,3) -> B-fragment order fwF[kc][nt][lane][j]
        int e = idx - 20480;
        int j = e & 7, lane = (e >> 3) & 63, nt = (e >> 9) & 3, kc = e >> 11;   // kc in 0..71
        int co = nt * 16 + (lane & 15);
        int k = kc * 32 + ((lane >> 4) << 3) + j;   // global K index: tap*256 + ci
        int tap = k >> 8, ci = k & 255;
        fwF[e] = f2bf(fw[co * 2304 + ci * 9 + tap]);
    }
}

// ---------- transpose key->qT (NHWC fp32) and sup->fused[ch 0:64] (bf16) ----------
__global__ void pack_kernel(const float* __restrict__ key, const float* __restrict__ sup,
                            float* __restrict__ qT, __hip_bfloat16* __restrict__ fused)
{
    __shared__ float lk[32][33], ls[32][33];
    int tx = threadIdx.x, ty = threadIdx.y;
    int x0 = blockIdx.x * 32, c0 = blockIdx.y * 32;
    int z = blockIdx.z; int b = z / 96, y = z - b * 96;
    #pragma unroll
    for (int i = 0; i < 32; i += 8) {
        int c = c0 + ty + i;
        lk[ty + i][tx] = key[((b * 64 + c) * 96 + y) * 96 + x0 + tx];
        ls[ty + i][tx] = sup[((b * 64 + c) * 96 + y) * 96 + x0 + tx];
    }
    __syncthreads();
    #pragma unroll
    for (int i = 0; i < 32; i += 8) {
        int px = (b * 96 + y) * 96 + x0 + ty + i;
        qT[px * 64 + c0 + tx]     = lk[tx][ty + i];
        fused[px * 256 + c0 + tx] = __hip_bfloat16(ls[tx][ty + i]);
    }
}

// ---------- shifted grouped 3x3 conv, LDS-staged, wave-uniform out-channel ----------
__global__ __launch_bounds__(256) void shift_smooth(const float* __restrict__ sup,
    const float* __restrict__ w, const float* __restrict__ bias, float* __restrict__ smooth)
{
    __shared__ __align__(16) float tile[8][34][36];
    int bid = blockIdx.x;                 // 576 = 4b * 8grp * 9sj * 2half
    int half = bid & 1;
    int sj   = (bid >> 1) % 9;
    int grp  = (bid / 18) & 7;
    int b    = bid / 144;
    int sby = sj / 3, sbx = sj % 3;
    int Y0 = sby * 32, X0 = sbx * 32;
    int sh = 3 * ((grp >= 5) - (grp < 3));
    int mm = (grp < 3) ? grp : ((grp < 5) ? ((grp == 3) ? 0 : 2) : (grp - 5));
    int sw = 3 * mm - 3;
    int t = threadIdx.x;

    const float* supg = sup + (size_t)(b * 64 + grp * 8) * HW;
    #pragma unroll
    for (int pp = 0; pp < 5; pp++) {
        int pos = pp * 256 + t;
        if (pos < 1156) {
            int r = pos / 34, u = pos - r * 34;
            int yy = Y0 - 1 + r, xx = X0 - 1 + u;
            int ys = yy - sh, xs = xx - sw;
            bool ok = (yy >= 0) & (yy < 96) & (xx >= 0) & (xx < 96) &
                      (ys >= 0) & (ys < 96) & (xs >= 0) & (xs < 96);
            int addr = ok ? (ys * 96 + xs) : 0;
            #pragma unroll
            for (int ic = 0; ic < 8; ic++) {
                float v = supg[(size_t)ic * HW + addr];
                tile[ic][r][u] = ok ? v : 0.f;
            }
        }
    }
    __syncthreads();

    int c = __builtin_amdgcn_readfirstlane(grp * 8 + half * 4 + (t >> 6));
    int lane = t & 63;
    int ty4 = lane >> 3, tx4 = lane & 7;
    int py0 = ty4 * 4, x0r = tx4 * 4;

    float bz = bias[c];
    float acc[4][4];
    #pragma unroll
    for (int jr = 0; jr < 4; jr++)
        #pragma unroll
        for (int j = 0; j < 4; j++) acc[jr][j] = bz;

    const float* wp = w + c * 72;
    for (int ic = 0; ic < 8; ic++) {
        float wr[9];
        #pragma unroll
        for (int q = 0; q < 9; q++) wr[q] = wp[ic * 9 + q];
        #pragma unroll
        for (int rr = 0; rr < 6; rr++) {
            float4 fa = *(const float4*)&tile[ic][py0 + rr][x0r];
            float4 fb4 = *(const float4*)&tile[ic][py0 + rr][x0r + 4];
            float f[6] = {fa.x, fa.y, fa.z, fa.w, fb4.x, fb4.y};
            #pragma unroll
            for (int ky = 0; ky < 3; ky++) {
                int jr = rr - ky;
                if (jr >= 0 && jr < 4) {
                    #pragma unroll
                    for (int j = 0; j < 4; j++)
                        acc[jr][j] += wr[ky*3]*f[j] + wr[ky*3+1]*f[j+1] + wr[ky*3+2]*f[j+2];
                }
            }
        }
    }

    float* op = smooth + ((size_t)(b * 64 + c) * 96 + Y0 + py0) * 96 + X0 + x0r;
    #pragma unroll
    for (int jr = 0; jr < 4; jr++) {
        float4 st = {acc[jr][0], acc[jr][1], acc[jr][2], acc[jr][3]};
        *(float4*)(op + (size_t)jr * 96) = st;
    }
}

// ---------- 1x1 reduce conv (128->64): weights in LDS (broadcast), px per lane ----------
__global__ __launch_bounds__(256) void reduce_kernel(const float* __restrict__ sup,
    const float* __restrict__ smooth, const float* __restrict__ rwT,
    const float* __restrict__ rb, float* __restrict__ sup2)
{
    __shared__ __align__(16) float wlds[8192];   // rwT[i][c], 32 KB
    int t = threadIdx.x;
    #pragma unroll
    for (int e = 0; e < 8; e++) {
        int idx = (e * 256 + t) * 4;
        *(float4*)&wlds[idx] = *(const float4*)&rwT[idx];
    }
    __syncthreads();

    int lane = t & 63, wq = t >> 6;
    int px = blockIdx.x * 64 + lane;
    int b = px / HW; int rem = px - b * HW;
    const float* s1 = sup + (size_t)b * 64 * HW + rem;
    const float* s2 = smooth + (size_t)b * 64 * HW + rem;
    float acc[16];
    #pragma unroll
    for (int j = 0; j < 16; j++) acc[j] = rb[wq * 16 + j];

    #pragma unroll 8
    for (int i = 0; i < 64; i++) {
        float v = s1[i * HW];
        const float* wr = &wlds[i * 64 + wq * 16];
        float4 w0 = *(const float4*)wr, w1 = *(const float4*)(wr + 4);
        float4 w2 = *(const float4*)(wr + 8), w3 = *(const float4*)(wr + 12);
        acc[0] += w0.x * v;  acc[1] += w0.y * v;  acc[2] += w0.z * v;  acc[3] += w0.w * v;
        acc[4] += w1.x * v;  acc[5] += w1.y * v;  acc[6] += w1.z * v;  acc[7] += w1.w * v;
        acc[8] += w2.x * v;  acc[9] += w2.y * v;  acc[10] += w2.z * v; acc[11] += w2.w * v;
        acc[12] += w3.x * v; acc[13] += w3.y * v; acc[14] += w3.z * v; acc[15] += w3.w * v;
    }
    #pragma unroll 8
    for (int i = 0; i < 64; i++) {
        float v = s2[i * HW];
        const float* wr = &wlds[(64 + i) * 64 + wq * 16];
        float4 w0 = *(const float4*)wr, w1 = *(const float4*)(wr + 4);
        float4 w2 = *(const float4*)(wr + 8), w3 = *(const float4*)(wr + 12);
        acc[0] += w0.x * v;  acc[1] += w0.y * v;  acc[2] += w0.z * v;  acc[3] += w0.w * v;
        acc[4] += w1.x * v;  acc[5] += w1.y * v;  acc[6] += w1.z * v;  acc[7] += w1.w * v;
        acc[8] += w2.x * v;  acc[9] += w2.y * v;  acc[10] += w2.z * v; acc[11] += w2.w * v;
        acc[12] += w3.x * v; acc[13] += w3.y * v; acc[14] += w3.z * v; acc[15] += w3.w * v;
    }

    float* op = sup2 + (size_t)px * 64 + wq * 16;
    #pragma unroll
    for (int j = 0; j < 16; j += 4) { float4 st = {acc[j], acc[j+1], acc[j+2], acc[j+3]}; *(float4*)(op + j) = st; }
}

// ---------- fused 3-level neighborhood attention (8 threads/px) ----------
// block = 8x4 px tile, 256 thr: pxl = wv*8 + (lane&7), qc = lane>>3 (8 ch-chunks)
template<int KS>
__device__ __forceinline__ void level_softmax(int qc, int y, int x, int ni7, int nj7,
        const _Float16* rpbl, const _Float16* dots_row, _Float16* out_row)
{
    constexpr int R = KS / 2, KK = KS * KS, NB = 2 * KS - 1;
    constexpr int NE = (KK + 7) / 8;
    int ni = min(max(y - R, 0), 96 - KS), nj = min(max(x - R, 0), 96 - KS);
    int di = ni - ni7, dj = nj - nj7;
    int br = KS - 1 + ni - y, bc = KS - 1 + nj - x;
    float sv[NE];
    float mx = -1e30f;
    #pragma unroll
    for (int i = 0; i < NE; i++) {
        int e = qc + i * 8;
        if (e < KK) {
            int ey = e / KS, ex = e - ey * KS;
            float s = (float)dots_row[(di + ey) * 7 + dj + ex] + (float)rpbl[(br + ey) * NB + bc + ex];
            sv[i] = s; mx = fmaxf(mx, s);
        } else sv[i] = -1e30f;
    }
    mx = fmaxf(mx, __shfl_xor(mx, 8)); mx = fmaxf(mx, __shfl_xor(mx, 16)); mx = fmaxf(mx, __shfl_xor(mx, 32));
    float sum = 0.f;
    #pragma unroll
    for (int i = 0; i < NE; i++) { sv[i] = __expf(sv[i] - mx); sum += sv[i]; }
    sum += __shfl_xor(sum, 8); sum += __shfl_xor(sum, 16); sum += __shfl_xor(sum, 32);
    float inv = 1.f / sum;
    #pragma unroll
    for (int i = 0; i < NE; i++) {
        int e = qc + i * 8;
        if (e < KK) out_row[e] = (_Float16)(sv[i] * inv);
    }
}

__global__ __launch_bounds__(256) void natten_fused(
    const float* __restrict__ qT, const float* __restrict__ sup2,
    const unsigned short* __restrict__ vwF,
    const float* __restrict__ vb0, const float* __restrict__ vb1, const float* __restrict__ vb2,
    const float* __restrict__ rpb0, const float* __restrict__ rpb1, const float* __restrict__ rpb2,
    __hip_bfloat16* __restrict__ fused)
{
    __shared__ __align__(16) unsigned short khalo[140 * 72];  // 20160 B; reused as sproj[3][32][72]
    __shared__ _Float16 dots[32][52];                         // 3328 B
    __shared__ _Float16 a3[32][12];                           // 768 B
    __shared__ _Float16 a5[32][28];                           // 1792 B
    __shared__ _Float16 rlds[276];                            // 552 B

    int t = threadIdx.x;
    int bb = blockIdx.y;
    int tx0 = (blockIdx.x % 12) * 8, ty0 = (blockIdx.x / 12) * 4;
    const float* kb = sup2 + (size_t)bb * HW * 64;

    // stage rpb tables (fp16): [0:169)=rpb2, [169:250)=rpb1, [250:275)=rpb0
    for (int e = t; e < 275; e += 256) {
        float v = (e < 169) ? rpb2[e] : ((e < 250) ? rpb1[e - 169] : rpb0[e - 250]);
        rlds[e] = (_Float16)v;
    }

    // stage 10x14 px halo (bf16, 64->72 ch pad): 140 px x 16 ch-quads = 2240 tasks
    for (int it = 0; it < 9; it++) {
        int qidx = it * 256 + t;
        if (qidx < 2240) {
            int cq = qidx & 15, pos = qidx >> 4;
            int py = pos / 14, pxx = pos - py * 14;
            int gy = min(max(ty0 - 3 + py, 0), 95);
            int gx = min(max(tx0 - 3 + pxx, 0), 95);
            float4 v = *(const float4*)(kb + (((size_t)gy * 96 + gx) << 6) + cq * 4);
            ushort4 pk = {f2bf(v.x), f2bf(v.y), f2bf(v.z), f2bf(v.w)};
            *(ushort4*)&khalo[pos * 72 + cq * 4] = pk;
        }
    }
    __syncthreads();

    int lane = t & 63, wv = t >> 6;
    int pxl = wv * 8 + (lane & 7);     // 0..31
    int qc = lane >> 3;                // 0..7 (8 channels each)
    int pty = pxl >> 3, ptx = pxl & 7; // 8 wide x 4 tall
    int y = ty0 + pty, x = tx0 + ptx;
    int gpx = bb * HW + y * 96 + x;

    float qv[8];
    {
        const float* qp = qT + (size_t)gpx * 64 + qc * 8;
        float4 q0 = *(const float4*)qp, q1 = *(const float4*)(qp + 4);
        qv[0] = q0.x; qv[1] = q0.y; qv[2] = q0.z; qv[3] = q0.w;
        qv[4] = q1.x; qv[5] = q1.y; qv[6] = q1.z; qv[7] = q1.w;
    }

    int ni7 = min(max(y - 3, 0), 89), nj7 = min(max(x - 3, 0), 89);
    int ly = ni7 - (ty0 - 3), lx = nj7 - (tx0 - 3);

    // 49 shared dots; each thread: 8-ch partial, reduce over qc (xor 8/16/32)
    // unroll 1 on oy: full 49-iter unroll blew VGPRs to 236 (round 11)
    #pragma unroll 1
    for (int oy = 0; oy < 7; oy++) {
        #pragma unroll
        for (int ox = 0; ox < 7; ox++) {
            const unsigned short* kp = &khalo[((ly + oy) * 14 + lx + ox) * 72 + qc * 8];
            uint4 ka = *(const uint4*)kp;
            float p0 = qv[0]*bfl(ka.x) + qv[1]*bfh(ka.x) + qv[2]*bfl(ka.y) + qv[3]*bfh(ka.y);
            float p1 = qv[4]*bfl(ka.z) + qv[5]*bfh(ka.z) + qv[6]*bfl(ka.w) + qv[7]*bfh(ka.w);
            float d = p0 + p1;
            d += __shfl_xor(d, 8);
            d += __shfl_xor(d, 16);
            d += __shfl_xor(d, 32);
            if (qc == 0) dots[pxl][oy * 7 + ox] = (_Float16)d;
        }
    }

    level_softmax<3>(qc, y, x, ni7, nj7, rlds + 250, &dots[pxl][0], &a3[pxl][0]);
    level_softmax<5>(qc, y, x, ni7, nj7, rlds + 169, &dots[pxl][0], &a5[pxl][0]);
    level_softmax<7>(qc, y, x, ni7, nj7, rlds,       &dots[pxl][0], &dots[pxl][0]);

    int ni5 = min(max(y - 2, 0), 91), nj5 = min(max(x - 2, 0), 91);
    int ni3 = min(max(y - 1, 0), 93), nj3 = min(max(x - 1, 0), 93);
    int di5 = ni5 - ni7, dj5 = nj5 - nj7, di3 = ni3 - ni7, dj3 = nj3 - nj7;

    float s2[3][8];
    #pragma unroll
    for (int l = 0; l < 3; l++)
        #pragma unroll
        for (int j = 0; j < 8; j++) s2[l][j] = 0.f;

    #pragma unroll 1
    for (int oy = 0; oy < 7; oy++) {
        #pragma unroll
        for (int ox = 0; ox < 7; ox++) {
            const unsigned short* kp = &khalo[((ly + oy) * 14 + lx + ox) * 72 + qc * 8];
            uint4 ka = *(const uint4*)kp;
            float kv[8] = {bfl(ka.x), bfh(ka.x), bfl(ka.y), bfh(ka.y),
                           bfl(ka.z), bfh(ka.z), bfl(ka.w), bfh(ka.w)};
            float w7 = (float)dots[pxl][oy * 7 + ox];
            #pragma unroll
            for (int j = 0; j < 8; j++) s2[2][j] += w7 * kv[j];
            int e5y = oy - di5, e5x = ox - dj5;
            if ((unsigned)e5y < 5u && (unsigned)e5x < 5u) {
                float w5 = (float)a5[pxl][e5y * 5 + e5x];
                #pragma unroll
                for (int j = 0; j < 8; j++) s2[1][j] += w5 * kv[j];
            }
            int e3y = oy - di3, e3x = ox - dj3;
            if ((unsigned)e3y < 3u && (unsigned)e3x < 3u) {
                float w3 = (float)a3[pxl][e3y * 3 + e3x];
                #pragma unroll
                for (int j = 0; j < 8; j++) s2[0][j] += w3 * kv[j];
            }
        }
    }
    __syncthreads();   // khalo reads done -> reuse as sproj

    unsigned short* sproj = khalo;   // [lvl*32 + pxl][72]
    #pragma unroll
    for (int l = 0; l < 3; l++) {
        unsigned int pk[4];
        #pragma unroll
        for (int j = 0; j < 4; j++)
            pk[j] = (unsigned int)f2bf(s2[l][2*j]) | ((unsigned int)f2bf(s2[l][2*j+1]) << 16);
        uint4 sv = {pk[0], pk[1], pk[2], pk[3]};
        *(uint4*)&sproj[(l * 32 + pxl) * 72 + qc * 8] = sv;
    }
    __syncthreads();

    // v-projection: wave wv (<3) does level wv's 32x64x64 GEMM (2 m-tiles x 4 nt x K=64)
    if (wv < 3) {
        int l = wv;
        int lm = lane & 15, quad = lane >> 4;
        const float* vbl = (l == 0) ? vb0 : ((l == 1) ? vb1 : vb2);
        #pragma unroll
        for (int mt = 0; mt < 2; mt++) {
            f32x4 acc[4];
            #pragma unroll
            for (int nt = 0; nt < 4; nt++) acc[nt] = (f32x4){0.f, 0.f, 0.f, 0.f};
            #pragma unroll
            for (int kf = 0; kf < 2; kf++) {
                short8 a = *(const short8*)&sproj[(l * 32 + mt * 16 + lm) * 72 + kf * 32 + quad * 8];
                #pragma unroll
                for (int nt = 0; nt < 4; nt++) {
                    short8 bfr = *(const short8*)&vwF[(((l * 4 + nt) * 2 + kf) * 64 + lane) * 8];
                    acc[nt] = __builtin_amdgcn_mfma_f32_16x16x32_bf16(a, bfr, acc[nt], 0, 0, 0);
                }
            }
            #pragma unroll
            for (int nt = 0; nt < 4; nt++)
                #pragma unroll
                for (int r = 0; r < 4; r++) {
                    int p = mt * 16 + quad * 4 + r;        // px in tile
                    int co = nt * 16 + lm;
                    int py = p >> 3, pxx = p & 7;
                    size_t off = ((size_t)(bb * HW + (ty0 + py) * 96 + tx0 + pxx) << 8) + (l + 1) * 64 + co;
                    fused[off] = __hip_bfloat16(acc[nt][r] + vbl[co]);
                }
        }
    }
}

// ---------- 3x3 fusion conv (256->64): LDS-staged implicit-GEMM bf16 MFMA ----------
__global__ __launch_bounds__(256) void fusion_mfma(
    const __hip_bfloat16* __restrict__ fB, const unsigned short* __restrict__ fwF,
    const float* __restrict__ fb, float* __restrict__ out)
{
    __shared__ __align__(16) unsigned short ah[108 * 72];   // 15552 B
    __shared__ float lds_out[64 * 66];                       // 16896 B
    int t = threadIdx.x;
    int wv = t >> 6, lane = t & 63, lm = lane & 15, quad = lane >> 4;
    int X0 = blockIdx.x * 16, Y0 = blockIdx.y * 4, b = blockIdx.z;
    const unsigned short* fBu = (const unsigned short*)fB;

    f32x4 acc[4] = {};

    for (int chunk = 0; chunk < 4; chunk++) {
        __syncthreads();
        #pragma unroll
        for (int ee = 0; ee < 4; ee++) {
            int e = ee * 256 + t;
            if (e < 864) {
                int seg = e & 7, hp = e >> 3;
                int hy = hp / 18, hx = hp - hy * 18;
                int gy = Y0 - 1 + hy, gx = X0 - 1 + hx;
                bool ok = (gy >= 0) & (gy < 96) & (gx >= 0) & (gx < 96);
                short8 v = {};
                if (ok) v = *(const short8*)(fBu + (((size_t)(b * HW + gy * 96 + gx)) << 8) + chunk * 64 + seg * 8);
                *(short8*)&ah[hp * 72 + seg * 8] = v;
            }
        }
        __syncthreads();
        #pragma unroll
        for (int ky = 0; ky < 3; ky++) {
            #pragma unroll
            for (int kx = 0; kx < 3; kx++) {
                #pragma unroll
                for (int kf = 0; kf < 2; kf++) {
                    short8 a = *(const short8*)&ah[((wv + ky) * 18 + lm + kx) * 72 + kf * 32 + quad * 8];
                    int kc = (ky * 3 + kx) * 8 + chunk * 2 + kf;
                    const unsigned short* bp = fwF + ((size_t)(kc * 4) * 64 + lane) * 8;
                    acc[0] = __builtin_amdgcn_mfma_f32_16x16x32_bf16(a, *(const short8*)(bp),        acc[0], 0, 0, 0);
                    acc[1] = __builtin_amdgcn_mfma_f32_16x16x32_bf16(a, *(const short8*)(bp + 512),  acc[1], 0, 0, 0);
                    acc[2] = __builtin_amdgcn_mfma_f32_16x16x32_bf16(a, *(const short8*)(bp + 1024), acc[2], 0, 0, 0);
                    acc[3] = __builtin_amdgcn_mfma_f32_16x16x32_bf16(a, *(const short8*)(bp + 1536), acc[3], 0, 0, 0);
                }
            }
        }
    }

    #pragma unroll
    for (int nt = 0; nt < 4; nt++)
        #pragma unroll
        for (int r = 0; r < 4; r++) {
            int p = wv * 16 + quad * 4 + r;
            int co = nt * 16 + lm;
            lds_out[co * 66 + p] = acc[nt][r];
        }
    __syncthreads();

    int p2 = t & 63, py = p2 >> 4, px2 = p2 & 15;
    float* ob = out + ((size_t)(b * 64) * 96 + Y0 + py) * 96 + X0 + px2;
    #pragma unroll 4
    for (int i = 0; i < 16; i++) {
        int co = (t >> 6) * 16 + i;
        float v = lds_out[co * 66 + p2] + fb[co];
        ob[(size_t)co * HW] = v > 0.f ? v : 0.f;
    }
}

extern "C" void kernel_launch(void* const* d_in, const int* in_sizes, int n_in,
                              void* d_out, int out_size, void* d_ws, size_t ws_size,
                              hipStream_t stream) {
    const float* sup = (const float*)d_in[0];
    const float* key = (const float*)d_in[1];
    const float* smw = (const float*)d_in[2];
    const float* smb = (const float*)d_in[3];
    const float* rw  = (const float*)d_in[4];
    const float* rb  = (const float*)d_in[5];
    const float *vw[3], *vb[3], *rpb[3];
    if (in_sizes[8] == 25) {
        for (int l = 0; l < 3; l++) {
            vw[l]  = (const float*)d_in[6 + 3 * l];
            vb[l]  = (const float*)d_in[7 + 3 * l];
            rpb[l] = (const float*)d_in[8 + 3 * l];
        }
    } else {
        for (int l = 0; l < 3; l++) {
            vw[l]  = (const float*)d_in[6 + 2 * l];
            vb[l]  = (const float*)d_in[7 + 2 * l];
            rpb[l] = (const float*)d_in[12 + l];
        }
    }
    const float* fw = (const float*)d_in[15];
    const float* fb = (const float*)d_in[16];
    float* out = (float*)d_out;

    float* wsf    = (float*)d_ws;
    float* smooth = wsf;                                    // 2359296 f
    float* sup2   = wsf + 2359296;                          // 2359296 f (NHWC)
    float* qT     = wsf + 4718592;                          // 2359296 f (NHWC)
    float* rwT    = wsf + 7077888;                          // 8192 f
    unsigned short* vwF = (unsigned short*)(wsf + 7086080); // 12288 bf16
    __hip_bfloat16* fusedB = (__hip_bfloat16*)(wsf + 7092224);  // 9437184 bf16
    unsigned short* fwF    = (unsigned short*)(wsf + 11810816); // 147456 bf16

    prep_weights<<<dim3(656), dim3(256), 0, stream>>>(rw, vw[0], vw[1], vw[2], fw, rwT, vwF, fwF);
    pack_kernel<<<dim3(3, 2, 384), dim3(32, 8), 0, stream>>>(key, sup, qT, fusedB);
    shift_smooth<<<dim3(576), dim3(256), 0, stream>>>(sup, smw, smb, smooth);
    reduce_kernel<<<dim3(576), dim3(256), 0, stream>>>(sup, smooth, rwT, rb, sup2);
    natten_fused<<<dim3(288, 4), dim3(256), 0, stream>>>(qT, sup2, vwF,
        vb[0], vb[1], vb[2], rpb[0], rpb[1], rpb[2], fusedB);
    fusion_mfma<<<dim3(6, 24, 4), dim3(256), 0, stream>>>(fusedB, fwF, fb, out);
}

// Round 13
// 212.601 us; speedup vs baseline: 1.3085x; 1.0475x over previous
//
#include <hip/hip_runtime.h>
#include <hip/hip_bf16.h>

#define HW 9216
#define NPX 36864

typedef __attribute__((ext_vector_type(8))) short short8;
typedef __attribute__((ext_vector_type(4))) float f32x4;

static __device__ __forceinline__ unsigned short f2bf(float x) {
    union { __hip_bfloat16 h; unsigned short u; } c; c.h = __float2bfloat16(x); return c.u;
}
static __device__ __forceinline__ float bfl(unsigned int u){ return __uint_as_float(u << 16); }
static __device__ __forceinline__ float bfh(unsigned int u){ return __uint_as_float(u & 0xffff0000u); }

// ---------- weight pre-transposes ----------
__global__ __launch_bounds__(256) void prep_weights(
    const float* __restrict__ rw, const float* __restrict__ vw0,
    const float* __restrict__ vw1, const float* __restrict__ vw2,
    const float* __restrict__ fw,
    float* __restrict__ rwT, unsigned short* __restrict__ vwF, unsigned short* __restrict__ fwF)
{
    int idx = blockIdx.x * 256 + threadIdx.x;
    if (idx < 8192) {                       // reduce_w (64,128) -> rwT[i][c]
        int c = idx & 63, i = idx >> 6;
        rwT[idx] = rw[c * 128 + i];
    } else if (idx < 20480) {               // v_w -> MFMA B-fragment order vwF[lvl][nt][kf][lane][j]
        int e = idx - 8192;
        int j = e & 7, lane = (e >> 3) & 63, kf = (e >> 9) & 1, nt = (e >> 10) & 3, lvl = e >> 12;
        int co = nt * 16 + (lane & 15);
        int k = kf * 32 + (lane >> 4) * 8 + j;
        const float* vw = (lvl == 0) ? vw0 : ((lvl == 1) ? vw1 : vw2);
        vwF[e] = f2bf(vw[co * 64 + k]);
    } else if (idx < 167936) {              // fusion_w (64,256,3,3) -> B-fragment order fwF[kc][nt][lane][j]
        int e = idx - 20480;
        int j = e & 7, lane = (e >> 3) & 63, nt = (e >> 9) & 3, kc = e >> 11;   // kc in 0..71
        int co = nt * 16 + (lane & 15);
        int k = kc * 32 + ((lane >> 4) << 3) + j;   // global K index: tap*256 + ci
        int tap = k >> 8, ci = k & 255;
        fwF[e] = f2bf(fw[co * 2304 + ci * 9 + tap]);
    }
}

// ---------- transpose key->qT (NHWC fp32) and sup->fused[ch 0:64] (bf16) ----------
__global__ void pack_kernel(const float* __restrict__ key, const float* __restrict__ sup,
                            float* __restrict__ qT, __hip_bfloat16* __restrict__ fused)
{
    __shared__ float lk[32][33], ls[32][33];
    int tx = threadIdx.x, ty = threadIdx.y;
    int x0 = blockIdx.x * 32, c0 = blockIdx.y * 32;
    int z = blockIdx.z; int b = z / 96, y = z - b * 96;
    #pragma unroll
    for (int i = 0; i < 32; i += 8) {
        int c = c0 + ty + i;
        lk[ty + i][tx] = key[((b * 64 + c) * 96 + y) * 96 + x0 + tx];
        ls[ty + i][tx] = sup[((b * 64 + c) * 96 + y) * 96 + x0 + tx];
    }
    __syncthreads();
    #pragma unroll
    for (int i = 0; i < 32; i += 8) {
        int px = (b * 96 + y) * 96 + x0 + ty + i;
        qT[px * 64 + c0 + tx]     = lk[tx][ty + i];
        fused[px * 256 + c0 + tx] = __hip_bfloat16(ls[tx][ty + i]);
    }
}

// ---------- shifted grouped 3x3 conv, LDS-staged, wave-uniform out-channel ----------
__global__ __launch_bounds__(256) void shift_smooth(const float* __restrict__ sup,
    const float* __restrict__ w, const float* __restrict__ bias, float* __restrict__ smooth)
{
    __shared__ __align__(16) float tile[8][34][36];
    int bid = blockIdx.x;                 // 576 = 4b * 8grp * 9sj * 2half
    int half = bid & 1;
    int sj   = (bid >> 1) % 9;
    int grp  = (bid / 18) & 7;
    int b    = bid / 144;
    int sby = sj / 3, sbx = sj % 3;
    int Y0 = sby * 32, X0 = sbx * 32;
    int sh = 3 * ((grp >= 5) - (grp < 3));
    int mm = (grp < 3) ? grp : ((grp < 5) ? ((grp == 3) ? 0 : 2) : (grp - 5));
    int sw = 3 * mm - 3;
    int t = threadIdx.x;

    const float* supg = sup + (size_t)(b * 64 + grp * 8) * HW;
    #pragma unroll
    for (int pp = 0; pp < 5; pp++) {
        int pos = pp * 256 + t;
        if (pos < 1156) {
            int r = pos / 34, u = pos - r * 34;
            int yy = Y0 - 1 + r, xx = X0 - 1 + u;
            int ys = yy - sh, xs = xx - sw;
            bool ok = (yy >= 0) & (yy < 96) & (xx >= 0) & (xx < 96) &
                      (ys >= 0) & (ys < 96) & (xs >= 0) & (xs < 96);
            int addr = ok ? (ys * 96 + xs) : 0;
            #pragma unroll
            for (int ic = 0; ic < 8; ic++) {
                float v = supg[(size_t)ic * HW + addr];
                tile[ic][r][u] = ok ? v : 0.f;
            }
        }
    }
    __syncthreads();

    int c = __builtin_amdgcn_readfirstlane(grp * 8 + half * 4 + (t >> 6));
    int lane = t & 63;
    int ty4 = lane >> 3, tx4 = lane & 7;
    int py0 = ty4 * 4, x0r = tx4 * 4;

    float bz = bias[c];
    float acc[4][4];
    #pragma unroll
    for (int jr = 0; jr < 4; jr++)
        #pragma unroll
        for (int j = 0; j < 4; j++) acc[jr][j] = bz;

    const float* wp = w + c * 72;
    for (int ic = 0; ic < 8; ic++) {
        float wr[9];
        #pragma unroll
        for (int q = 0; q < 9; q++) wr[q] = wp[ic * 9 + q];
        #pragma unroll
        for (int rr = 0; rr < 6; rr++) {
            float4 fa = *(const float4*)&tile[ic][py0 + rr][x0r];
            float4 fb4 = *(const float4*)&tile[ic][py0 + rr][x0r + 4];
            float f[6] = {fa.x, fa.y, fa.z, fa.w, fb4.x, fb4.y};
            #pragma unroll
            for (int ky = 0; ky < 3; ky++) {
                int jr = rr - ky;
                if (jr >= 0 && jr < 4) {
                    #pragma unroll
                    for (int j = 0; j < 4; j++)
                        acc[jr][j] += wr[ky*3]*f[j] + wr[ky*3+1]*f[j+1] + wr[ky*3+2]*f[j+2];
                }
            }
        }
    }

    float* op = smooth + ((size_t)(b * 64 + c) * 96 + Y0 + py0) * 96 + X0 + x0r;
    #pragma unroll
    for (int jr = 0; jr < 4; jr++) {
        float4 st = {acc[jr][0], acc[jr][1], acc[jr][2], acc[jr][3]};
        *(float4*)(op + (size_t)jr * 96) = st;
    }
}

// ---------- 1x1 reduce conv (128->64): weights in LDS (broadcast), px per lane ----------
__global__ __launch_bounds__(256) void reduce_kernel(const float* __restrict__ sup,
    const float* __restrict__ smooth, const float* __restrict__ rwT,
    const float* __restrict__ rb, float* __restrict__ sup2)
{
    __shared__ __align__(16) float wlds[8192];   // rwT[i][c], 32 KB
    int t = threadIdx.x;
    #pragma unroll
    for (int e = 0; e < 8; e++) {
        int idx = (e * 256 + t) * 4;
        *(float4*)&wlds[idx] = *(const float4*)&rwT[idx];
    }
    __syncthreads();

    int lane = t & 63, wq = t >> 6;
    int px = blockIdx.x * 64 + lane;
    int b = px / HW; int rem = px - b * HW;
    const float* s1 = sup + (size_t)b * 64 * HW + rem;
    const float* s2 = smooth + (size_t)b * 64 * HW + rem;
    float acc[16];
    #pragma unroll
    for (int j = 0; j < 16; j++) acc[j] = rb[wq * 16 + j];

    #pragma unroll 8
    for (int i = 0; i < 64; i++) {
        float v = s1[i * HW];
        const float* wr = &wlds[i * 64 + wq * 16];
        float4 w0 = *(const float4*)wr, w1 = *(const float4*)(wr + 4);
        float4 w2 = *(const float4*)(wr + 8), w3 = *(const float4*)(wr + 12);
        acc[0] += w0.x * v;  acc[1] += w0.y * v;  acc[2] += w0.z * v;  acc[3] += w0.w * v;
        acc[4] += w1.x * v;  acc[5] += w1.y * v;  acc[6] += w1.z * v;  acc[7] += w1.w * v;
        acc[8] += w2.x * v;  acc[9] += w2.y * v;  acc[10] += w2.z * v; acc[11] += w2.w * v;
        acc[12] += w3.x * v; acc[13] += w3.y * v; acc[14] += w3.z * v; acc[15] += w3.w * v;
    }
    #pragma unroll 8
    for (int i = 0; i < 64; i++) {
        float v = s2[i * HW];
        const float* wr = &wlds[(64 + i) * 64 + wq * 16];
        float4 w0 = *(const float4*)wr, w1 = *(const float4*)(wr + 4);
        float4 w2 = *(const float4*)(wr + 8), w3 = *(const float4*)(wr + 12);
        acc[0] += w0.x * v;  acc[1] += w0.y * v;  acc[2] += w0.z * v;  acc[3] += w0.w * v;
        acc[4] += w1.x * v;  acc[5] += w1.y * v;  acc[6] += w1.z * v;  acc[7] += w1.w * v;
        acc[8] += w2.x * v;  acc[9] += w2.y * v;  acc[10] += w2.z * v; acc[11] += w2.w * v;
        acc[12] += w3.x * v; acc[13] += w3.y * v; acc[14] += w3.z * v; acc[15] += w3.w * v;
    }

    float* op = sup2 + (size_t)px * 64 + wq * 16;
    #pragma unroll
    for (int j = 0; j < 16; j += 4) { float4 st = {acc[j], acc[j+1], acc[j+2], acc[j+3]}; *(float4*)(op + j) = st; }
}

// ---------- fused 3-level neighborhood attention (8 threads/px, shuffle-free dots) ----------
template<int KS>
__device__ __forceinline__ void level_softmax(int qc, int y, int x, int ni7, int nj7,
        const _Float16* rpbl, const _Float16* dots_row, _Float16* out_row)
{
    constexpr int R = KS / 2, KK = KS * KS, NB = 2 * KS - 1;
    constexpr int NE = (KK + 7) / 8;
    int ni = min(max(y - R, 0), 96 - KS), nj = min(max(x - R, 0), 96 - KS);
    int di = ni - ni7, dj = nj - nj7;
    int br = KS - 1 + ni - y, bc = KS - 1 + nj - x;
    float sv[NE];
    float mx = -1e30f;
    #pragma unroll
    for (int i = 0; i < NE; i++) {
        int e = qc + i * 8;
        if (e < KK) {
            int ey = e / KS, ex = e - ey * KS;
            float s = (float)dots_row[(di + ey) * 7 + dj + ex] + (float)rpbl[(br + ey) * NB + bc + ex];
            sv[i] = s; mx = fmaxf(mx, s);
        } else sv[i] = -1e30f;
    }
    mx = fmaxf(mx, __shfl_xor(mx, 8)); mx = fmaxf(mx, __shfl_xor(mx, 16)); mx = fmaxf(mx, __shfl_xor(mx, 32));
    float sum = 0.f;
    #pragma unroll
    for (int i = 0; i < NE; i++) { sv[i] = __expf(sv[i] - mx); sum += sv[i]; }
    sum += __shfl_xor(sum, 8); sum += __shfl_xor(sum, 16); sum += __shfl_xor(sum, 32);
    float inv = 1.f / sum;
    #pragma unroll
    for (int i = 0; i < NE; i++) {
        int e = qc + i * 8;
        if (e < KK) out_row[e] = (_Float16)(sv[i] * inv);
    }
}

__global__ __launch_bounds__(256) void natten_fused(
    const float* __restrict__ qT, const float* __restrict__ sup2,
    const unsigned short* __restrict__ vwF,
    const float* __restrict__ vb0, const float* __restrict__ vb1, const float* __restrict__ vb2,
    const float* __restrict__ rpb0, const float* __restrict__ rpb1, const float* __restrict__ rpb2,
    __hip_bfloat16* __restrict__ fused)
{
    __shared__ __align__(16) unsigned short khalo[140 * 72];  // 20160 B; reused as sproj[3][32][72]
    __shared__ __align__(16) float qlds[32][68];              // 8704 B (68: bank-conflict pad)
    __shared__ _Float16 dots[32][52];                         // 3328 B
    __shared__ _Float16 a3[32][12];                           // 768 B
    __shared__ _Float16 a5[32][28];                           // 1792 B
    __shared__ _Float16 rlds[276];                            // 552 B -> ~35.3 KB total

    int t = threadIdx.x;
    int bb = blockIdx.y;
    int tx0 = (blockIdx.x % 12) * 8, ty0 = (blockIdx.x / 12) * 4;
    const float* kb = sup2 + (size_t)bb * HW * 64;

    // stage rpb tables (fp16): [0:169)=rpb2, [169:250)=rpb1, [250:275)=rpb0
    for (int e = t; e < 275; e += 256) {
        float v = (e < 169) ? rpb2[e] : ((e < 250) ? rpb1[e - 169] : rpb0[e - 250]);
        rlds[e] = (_Float16)v;
    }

    // stage 10x14 px k-halo (bf16, 64->72 ch pad)
    for (int it = 0; it < 9; it++) {
        int qidx = it * 256 + t;
        if (qidx < 2240) {
            int cq = qidx & 15, pos = qidx >> 4;
            int py = pos / 14, pxx = pos - py * 14;
            int gy = min(max(ty0 - 3 + py, 0), 95);
            int gx = min(max(tx0 - 3 + pxx, 0), 95);
            float4 v = *(const float4*)(kb + (((size_t)gy * 96 + gx) << 6) + cq * 4);
            ushort4 pk = {f2bf(v.x), f2bf(v.y), f2bf(v.z), f2bf(v.w)};
            *(ushort4*)&khalo[pos * 72 + cq * 4] = pk;
        }
    }
    // stage q-tile fp32: 32 px x 16 float4
    #pragma unroll
    for (int e = t; e < 512; e += 256) {
        int px = e >> 4, seg = e & 15;
        float4 v = *(const float4*)(qT + ((size_t)(bb * HW + (ty0 + (px >> 3)) * 96 + tx0 + (px & 7)) << 6) + seg * 4);
        *(float4*)&qlds[px][seg * 4] = v;
    }
    __syncthreads();

    int lane = t & 63, wv = t >> 6;
    int pxl = wv * 8 + (lane & 7);     // 0..31
    int qc = lane >> 3;                // 0..7
    int pty = pxl >> 3, ptx = pxl & 7; // 8 wide x 4 tall
    int y = ty0 + pty, x = tx0 + ptx;

    int ni7 = min(max(y - 3, 0), 89), nj7 = min(max(x - 3, 0), 89);
    int ly = ni7 - (ty0 - 3), lx = nj7 - (tx0 - 3);

    // dot phase: thread (pxl,qc) computes FULL 64-ch dots for positions p = qc+8i.
    // No cross-lane shuffles; q hoisted per 16-ch chunk from LDS (broadcast reads).
    float dacc[7];
    #pragma unroll
    for (int i = 0; i < 7; i++) dacc[i] = 0.f;
    #pragma unroll 1
    for (int cc = 0; cc < 4; cc++) {
        float qreg[16];
        #pragma unroll
        for (int j = 0; j < 4; j++) {
            float4 q4 = *(const float4*)&qlds[pxl][cc * 16 + j * 4];
            qreg[j*4] = q4.x; qreg[j*4+1] = q4.y; qreg[j*4+2] = q4.z; qreg[j*4+3] = q4.w;
        }
        #pragma unroll
        for (int i = 0; i < 7; i++) {
            int p = qc + 8 * i;
            if (p < 49) {
                int oy = p / 7, ox = p - oy * 7;
                const unsigned short* kp = &khalo[((ly + oy) * 14 + lx + ox) * 72 + cc * 16];
                uint4 ka = *(const uint4*)kp;
                uint4 kc2 = *(const uint4*)(kp + 8);
                float p0 = qreg[0]*bfl(ka.x) + qreg[1]*bfh(ka.x) + qreg[2]*bfl(ka.y) + qreg[3]*bfh(ka.y)
                         + qreg[4]*bfl(ka.z) + qreg[5]*bfh(ka.z) + qreg[6]*bfl(ka.w) + qreg[7]*bfh(ka.w);
                float p1 = qreg[8]*bfl(kc2.x) + qreg[9]*bfh(kc2.x) + qreg[10]*bfl(kc2.y) + qreg[11]*bfh(kc2.y)
                         + qreg[12]*bfl(kc2.z) + qreg[13]*bfh(kc2.z) + qreg[14]*bfl(kc2.w) + qreg[15]*bfh(kc2.w);
                dacc[i] += p0 + p1;
            }
        }
    }
    #pragma unroll
    for (int i = 0; i < 7; i++) {
        int p = qc + 8 * i;
        if (p < 49) dots[pxl][p] = (_Float16)dacc[i];
    }
    __syncthreads();

    level_softmax<3>(qc, y, x, ni7, nj7, rlds + 250, &dots[pxl][0], &a3[pxl][0]);
    level_softmax<5>(qc, y, x, ni7, nj7, rlds + 169, &dots[pxl][0], &a5[pxl][0]);
    level_softmax<7>(qc, y, x, ni7, nj7, rlds,       &dots[pxl][0], &dots[pxl][0]);

    int ni5 = min(max(y - 2, 0), 91), nj5 = min(max(x - 2, 0), 91);
    int ni3 = min(max(y - 1, 0), 93), nj3 = min(max(x - 1, 0), 93);
    int di5 = ni5 - ni7, dj5 = nj5 - nj7, di3 = ni3 - ni7, dj3 = nj3 - nj7;

    float s2[3][8];
    #pragma unroll
    for (int l = 0; l < 3; l++)
        #pragma unroll
        for (int j = 0; j < 8; j++) s2[l][j] = 0.f;

    #pragma unroll 1
    for (int oy = 0; oy < 7; oy++) {
        #pragma unroll
        for (int ox = 0; ox < 7; ox++) {
            const unsigned short* kp = &khalo[((ly + oy) * 14 + lx + ox) * 72 + qc * 8];
            uint4 ka = *(const uint4*)kp;
            float kv[8] = {bfl(ka.x), bfh(ka.x), bfl(ka.y), bfh(ka.y),
                           bfl(ka.z), bfh(ka.z), bfl(ka.w), bfh(ka.w)};
            float w7 = (float)dots[pxl][oy * 7 + ox];
            #pragma unroll
            for (int j = 0; j < 8; j++) s2[2][j] += w7 * kv[j];
            int e5y = oy - di5, e5x = ox - dj5;
            if ((unsigned)e5y < 5u && (unsigned)e5x < 5u) {
                float w5 = (float)a5[pxl][e5y * 5 + e5x];
                #pragma unroll
                for (int j = 0; j < 8; j++) s2[1][j] += w5 * kv[j];
            }
            int e3y = oy - di3, e3x = ox - dj3;
            if ((unsigned)e3y < 3u && (unsigned)e3x < 3u) {
                float w3 = (float)a3[pxl][e3y * 3 + e3x];
                #pragma unroll
                for (int j = 0; j < 8; j++) s2[0][j] += w3 * kv[j];
            }
        }
    }
    __syncthreads();   // khalo reads done -> reuse as sproj

    unsigned short* sproj = khalo;   // [lvl*32 + pxl][72]
    #pragma unroll
    for (int l = 0; l < 3; l++) {
        unsigned int pk[4];
        #pragma unroll
        for (int j = 0; j < 4; j++)
            pk[j] = (unsigned int)f2bf(s2[l][2*j]) | ((unsigned int)f2bf(s2[l][2*j+1]) << 16);
        uint4 sv = {pk[0], pk[1], pk[2], pk[3]};
        *(uint4*)&sproj[(l * 32 + pxl) * 72 + qc * 8] = sv;
    }
    __syncthreads();

    // v-projection: wave wv (<3) does level wv's 32x64x64 GEMM
    if (wv < 3) {
        int l = wv;
        int lm = lane & 15, quad = lane >> 4;
        const float* vbl = (l == 0) ? vb0 : ((l == 1) ? vb1 : vb2);
        #pragma unroll
        for (int mt = 0; mt < 2; mt++) {
            f32x4 acc[4];
            #pragma unroll
            for (int nt = 0; nt < 4; nt++) acc[nt] = (f32x4){0.f, 0.f, 0.f, 0.f};
            #pragma unroll
            for (int kf = 0; kf < 2; kf++) {
                short8 a = *(const short8*)&sproj[(l * 32 + mt * 16 + lm) * 72 + kf * 32 + quad * 8];
                #pragma unroll
                for (int nt = 0; nt < 4; nt++) {
                    short8 bfr = *(const short8*)&vwF[(((l * 4 + nt) * 2 + kf) * 64 + lane) * 8];
                    acc[nt] = __builtin_amdgcn_mfma_f32_16x16x32_bf16(a, bfr, acc[nt], 0, 0, 0);
                }
            }
            #pragma unroll
            for (int nt = 0; nt < 4; nt++)
                #pragma unroll
                for (int r = 0; r < 4; r++) {
                    int p = mt * 16 + quad * 4 + r;
                    int co = nt * 16 + lm;
                    int py = p >> 3, pxx = p & 7;
                    size_t off = ((size_t)(bb * HW + (ty0 + py) * 96 + tx0 + pxx) << 8) + (l + 1) * 64 + co;
                    fused[off] = __hip_bfloat16(acc[nt][r] + vbl[co]);
                }
        }
    }
}

// ---------- 3x3 fusion conv (256->64): LDS-staged implicit-GEMM bf16 MFMA ----------
__global__ __launch_bounds__(256) void fusion_mfma(
    const __hip_bfloat16* __restrict__ fB, const unsigned short* __restrict__ fwF,
    const float* __restrict__ fb, float* __restrict__ out)
{
    __shared__ __align__(16) unsigned short ah[108 * 72];   // 15552 B
    __shared__ float lds_out[64 * 66];                       // 16896 B
    int t = threadIdx.x;
    int wv = t >> 6, lane = t & 63, lm = lane & 15, quad = lane >> 4;
    int X0 = blockIdx.x * 16, Y0 = blockIdx.y * 4, b = blockIdx.z;
    const unsigned short* fBu = (const unsigned short*)fB;

    f32x4 acc[4] = {};

    for (int chunk = 0; chunk < 4; chunk++) {
        __syncthreads();
        #pragma unroll
        for (int ee = 0; ee < 4; ee++) {
            int e = ee * 256 + t;
            if (e < 864) {
                int seg = e & 7, hp = e >> 3;
                int hy = hp / 18, hx = hp - hy * 18;
                int gy = Y0 - 1 + hy, gx = X0 - 1 + hx;
                bool ok = (gy >= 0) & (gy < 96) & (gx >= 0) & (gx < 96);
                short8 v = {};
                if (ok) v = *(const short8*)(fBu + (((size_t)(b * HW + gy * 96 + gx)) << 8) + chunk * 64 + seg * 8);
                *(short8*)&ah[hp * 72 + seg * 8] = v;
            }
        }
        __syncthreads();
        #pragma unroll
        for (int ky = 0; ky < 3; ky++) {
            #pragma unroll
            for (int kx = 0; kx < 3; kx++) {
                #pragma unroll
                for (int kf = 0; kf < 2; kf++) {
                    short8 a = *(const short8*)&ah[((wv + ky) * 18 + lm + kx) * 72 + kf * 32 + quad * 8];
                    int kc = (ky * 3 + kx) * 8 + chunk * 2 + kf;
                    const unsigned short* bp = fwF + ((size_t)(kc * 4) * 64 + lane) * 8;
                    acc[0] = __builtin_amdgcn_mfma_f32_16x16x32_bf16(a, *(const short8*)(bp),        acc[0], 0, 0, 0);
                    acc[1] = __builtin_amdgcn_mfma_f32_16x16x32_bf16(a, *(const short8*)(bp + 512),  acc[1], 0, 0, 0);
                    acc[2] = __builtin_amdgcn_mfma_f32_16x16x32_bf16(a, *(const short8*)(bp + 1024), acc[2], 0, 0, 0);
                    acc[3] = __builtin_amdgcn_mfma_f32_16x16x32_bf16(a, *(const short8*)(bp + 1536), acc[3], 0, 0, 0);
                }
            }
        }
    }

    #pragma unroll
    for (int nt = 0; nt < 4; nt++)
        #pragma unroll
        for (int r = 0; r < 4; r++) {
            int p = wv * 16 + quad * 4 + r;
            int co = nt * 16 + lm;
            lds_out[co * 66 + p] = acc[nt][r];
        }
    __syncthreads();

    int p2 = t & 63, py = p2 >> 4, px2 = p2 & 15;
    float* ob = out + ((size_t)(b * 64) * 96 + Y0 + py) * 96 + X0 + px2;
    #pragma unroll 4
    for (int i = 0; i < 16; i++) {
        int co = (t >> 6) * 16 + i;
        float v = lds_out[co * 66 + p2] + fb[co];
        ob[(size_t)co * HW] = v > 0.f ? v : 0.f;
    }
}

extern "C" void kernel_launch(void* const* d_in, const int* in_sizes, int n_in,
                              void* d_out, int out_size, void* d_ws, size_t ws_size,
                              hipStream_t stream) {
    const float* sup = (const float*)d_in[0];
    const float* key = (const float*)d_in[1];
    const float* smw = (const float*)d_in[2];
    const float* smb = (const float*)d_in[3];
    const float* rw  = (const float*)d_in[4];
    const float* rb  = (const float*)d_in[5];
    const float *vw[3], *vb[3], *rpb[3];
    if (in_sizes[8] == 25) {
        for (int l = 0; l < 3; l++) {
            vw[l]  = (const float*)d_in[6 + 3 * l];
            vb[l]  = (const float*)d_in[7 + 3 * l];
            rpb[l] = (const float*)d_in[8 + 3 * l];
        }
    } else {
        for (int l = 0; l < 3; l++) {
            vw[l]  = (const float*)d_in[6 + 2 * l];
            vb[l]  = (const float*)d_in[7 + 2 * l];
            rpb[l] = (const float*)d_in[12 + l];
        }
    }
    const float* fw = (const float*)d_in[15];
    const float* fb = (const float*)d_in[16];
    float* out = (float*)d_out;

    float* wsf    = (float*)d_ws;
    float* smooth = wsf;                                    // 2359296 f
    float* sup2   = wsf + 2359296;                          // 2359296 f (NHWC)
    float* qT     = wsf + 4718592;                          // 2359296 f (NHWC)
    float* rwT    = wsf + 7077888;                          // 8192 f
    unsigned short* vwF = (unsigned short*)(wsf + 7086080); // 12288 bf16
    __hip_bfloat16* fusedB = (__hip_bfloat16*)(wsf + 7092224);  // 9437184 bf16
    unsigned short* fwF    = (unsigned short*)(wsf + 11810816); // 147456 bf16

    prep_weights<<<dim3(656), dim3(256), 0, stream>>>(rw, vw[0], vw[1], vw[2], fw, rwT, vwF, fwF);
    pack_kernel<<<dim3(3, 2, 384), dim3(32, 8), 0, stream>>>(key, sup, qT, fusedB);
    shift_smooth<<<dim3(576), dim3(256), 0, stream>>>(sup, smw, smb, smooth);
    reduce_kernel<<<dim3(576), dim3(256), 0, stream>>>(sup, smooth, rwT, rb, sup2);
    natten_fused<<<dim3(288, 4), dim3(256), 0, stream>>>(qT, sup2, vwF,
        vb[0], vb[1], vb[2], rpb[0], rpb[1], rpb[2], fusedB);
    fusion_mfma<<<dim3(6, 24, 4), dim3(256), 0, stream>>>(fusedB, fwF, fb, out);
}

// Round 14
// 205.439 us; speedup vs baseline: 1.3541x; 1.0349x over previous
//
#include <hip/hip_runtime.h>
#include <hip/hip_bf16.h>

#define HW 9216
#define NPX 36864

typedef __attribute__((ext_vector_type(8))) short short8;
typedef __attribute__((ext_vector_type(4))) float f32x4;

static __device__ __forceinline__ unsigned short f2bf(float x) {
    union { __hip_bfloat16 h; unsigned short u; } c; c.h = __float2bfloat16(x); return c.u;
}
static __device__ __forceinline__ float bfl(unsigned int u){ return __uint_as_float(u << 16); }
static __device__ __forceinline__ float bfh(unsigned int u){ return __uint_as_float(u & 0xffff0000u); }

// ---------- weight pre-transposes ----------
__global__ __launch_bounds__(256) void prep_weights(
    const float* __restrict__ rw, const float* __restrict__ vw0,
    const float* __restrict__ vw1, const float* __restrict__ vw2,
    const float* __restrict__ fw,
    float* __restrict__ rwT, unsigned short* __restrict__ vwF, unsigned short* __restrict__ fwF)
{
    int idx = blockIdx.x * 256 + threadIdx.x;
    if (idx < 8192) {                       // reduce_w (64,128) -> rwT[i][c]
        int c = idx & 63, i = idx >> 6;
        rwT[idx] = rw[c * 128 + i];
    } else if (idx < 20480) {               // v_w -> MFMA B-fragment order vwF[lvl][nt][kf][lane][j]
        int e = idx - 8192;
        int j = e & 7, lane = (e >> 3) & 63, kf = (e >> 9) & 1, nt = (e >> 10) & 3, lvl = e >> 12;
        int co = nt * 16 + (lane & 15);
        int k = kf * 32 + (lane >> 4) * 8 + j;
        const float* vw = (lvl == 0) ? vw0 : ((lvl == 1) ? vw1 : vw2);
        vwF[e] = f2bf(vw[co * 64 + k]);
    } else if (idx < 167936) {              // fusion_w (64,256,3,3) -> B-fragment order fwF[kc][nt][lane][j]
        int e = idx - 20480;
        int j = e & 7, lane = (e >> 3) & 63, nt = (e >> 9) & 3, kc = e >> 11;   // kc in 0..71
        int co = nt * 16 + (lane & 15);
        int k = kc * 32 + ((lane >> 4) << 3) + j;   // global K index: tap*256 + ci
        int tap = k >> 8, ci = k & 255;
        fwF[e] = f2bf(fw[co * 2304 + ci * 9 + tap]);
    }
}

// ---------- transpose key->qB (NHWC bf16) and sup->fused[ch 0:64] (bf16) ----------
__global__ void pack_kernel(const float* __restrict__ key, const float* __restrict__ sup,
                            __hip_bfloat16* __restrict__ qB, __hip_bfloat16* __restrict__ fused)
{
    __shared__ float lk[32][33], ls[32][33];
    int tx = threadIdx.x, ty = threadIdx.y;
    int x0 = blockIdx.x * 32, c0 = blockIdx.y * 32;
    int z = blockIdx.z; int b = z / 96, y = z - b * 96;
    #pragma unroll
    for (int i = 0; i < 32; i += 8) {
        int c = c0 + ty + i;
        lk[ty + i][tx] = key[((b * 64 + c) * 96 + y) * 96 + x0 + tx];
        ls[ty + i][tx] = sup[((b * 64 + c) * 96 + y) * 96 + x0 + tx];
    }
    __syncthreads();
    #pragma unroll
    for (int i = 0; i < 32; i += 8) {
        int px = (b * 96 + y) * 96 + x0 + ty + i;
        qB[px * 64 + c0 + tx]     = __hip_bfloat16(lk[tx][ty + i]);
        fused[px * 256 + c0 + tx] = __hip_bfloat16(ls[tx][ty + i]);
    }
}

// ---------- shifted grouped 3x3 conv, LDS-staged, wave-uniform out-channel ----------
__global__ __launch_bounds__(256) void shift_smooth(const float* __restrict__ sup,
    const float* __restrict__ w, const float* __restrict__ bias, float* __restrict__ smooth)
{
    __shared__ __align__(16) float tile[8][34][36];
    int bid = blockIdx.x;                 // 576 = 4b * 8grp * 9sj * 2half
    int half = bid & 1;
    int sj   = (bid >> 1) % 9;
    int grp  = (bid / 18) & 7;
    int b    = bid / 144;
    int sby = sj / 3, sbx = sj % 3;
    int Y0 = sby * 32, X0 = sbx * 32;
    int sh = 3 * ((grp >= 5) - (grp < 3));
    int mm = (grp < 3) ? grp : ((grp < 5) ? ((grp == 3) ? 0 : 2) : (grp - 5));
    int sw = 3 * mm - 3;
    int t = threadIdx.x;

    const float* supg = sup + (size_t)(b * 64 + grp * 8) * HW;
    #pragma unroll
    for (int pp = 0; pp < 5; pp++) {
        int pos = pp * 256 + t;
        if (pos < 1156) {
            int r = pos / 34, u = pos - r * 34;
            int yy = Y0 - 1 + r, xx = X0 - 1 + u;
            int ys = yy - sh, xs = xx - sw;
            bool ok = (yy >= 0) & (yy < 96) & (xx >= 0) & (xx < 96) &
                      (ys >= 0) & (ys < 96) & (xs >= 0) & (xs < 96);
            int addr = ok ? (ys * 96 + xs) : 0;
            #pragma unroll
            for (int ic = 0; ic < 8; ic++) {
                float v = supg[(size_t)ic * HW + addr];
                tile[ic][r][u] = ok ? v : 0.f;
            }
        }
    }
    __syncthreads();

    int c = __builtin_amdgcn_readfirstlane(grp * 8 + half * 4 + (t >> 6));
    int lane = t & 63;
    int ty4 = lane >> 3, tx4 = lane & 7;
    int py0 = ty4 * 4, x0r = tx4 * 4;

    float bz = bias[c];
    float acc[4][4];
    #pragma unroll
    for (int jr = 0; jr < 4; jr++)
        #pragma unroll
        for (int j = 0; j < 4; j++) acc[jr][j] = bz;

    const float* wp = w + c * 72;
    for (int ic = 0; ic < 8; ic++) {
        float wr[9];
        #pragma unroll
        for (int q = 0; q < 9; q++) wr[q] = wp[ic * 9 + q];
        #pragma unroll
        for (int rr = 0; rr < 6; rr++) {
            float4 fa = *(const float4*)&tile[ic][py0 + rr][x0r];
            float4 fb4 = *(const float4*)&tile[ic][py0 + rr][x0r + 4];
            float f[6] = {fa.x, fa.y, fa.z, fa.w, fb4.x, fb4.y};
            #pragma unroll
            for (int ky = 0; ky < 3; ky++) {
                int jr = rr - ky;
                if (jr >= 0 && jr < 4) {
                    #pragma unroll
                    for (int j = 0; j < 4; j++)
                        acc[jr][j] += wr[ky*3]*f[j] + wr[ky*3+1]*f[j+1] + wr[ky*3+2]*f[j+2];
                }
            }
        }
    }

    float* op = smooth + ((size_t)(b * 64 + c) * 96 + Y0 + py0) * 96 + X0 + x0r;
    #pragma unroll
    for (int jr = 0; jr < 4; jr++) {
        float4 st = {acc[jr][0], acc[jr][1], acc[jr][2], acc[jr][3]};
        *(float4*)(op + (size_t)jr * 96) = st;
    }
}

// ---------- 1x1 reduce conv (128->64): weights in LDS (broadcast), px per lane ----------
__global__ __launch_bounds__(256) void reduce_kernel(const float* __restrict__ sup,
    const float* __restrict__ smooth, const float* __restrict__ rwT,
    const float* __restrict__ rb, float* __restrict__ sup2)
{
    __shared__ __align__(16) float wlds[8192];   // rwT[i][c], 32 KB
    int t = threadIdx.x;
    #pragma unroll
    for (int e = 0; e < 8; e++) {
        int idx = (e * 256 + t) * 4;
        *(float4*)&wlds[idx] = *(const float4*)&rwT[idx];
    }
    __syncthreads();

    int lane = t & 63, wq = t >> 6;
    int px = blockIdx.x * 64 + lane;
    int b = px / HW; int rem = px - b * HW;
    const float* s1 = sup + (size_t)b * 64 * HW + rem;
    const float* s2 = smooth + (size_t)b * 64 * HW + rem;
    float acc[16];
    #pragma unroll
    for (int j = 0; j < 16; j++) acc[j] = rb[wq * 16 + j];

    #pragma unroll 8
    for (int i = 0; i < 64; i++) {
        float v = s1[i * HW];
        const float* wr = &wlds[i * 64 + wq * 16];
        float4 w0 = *(const float4*)wr, w1 = *(const float4*)(wr + 4);
        float4 w2 = *(const float4*)(wr + 8), w3 = *(const float4*)(wr + 12);
        acc[0] += w0.x * v;  acc[1] += w0.y * v;  acc[2] += w0.z * v;  acc[3] += w0.w * v;
        acc[4] += w1.x * v;  acc[5] += w1.y * v;  acc[6] += w1.z * v;  acc[7] += w1.w * v;
        acc[8] += w2.x * v;  acc[9] += w2.y * v;  acc[10] += w2.z * v; acc[11] += w2.w * v;
        acc[12] += w3.x * v; acc[13] += w3.y * v; acc[14] += w3.z * v; acc[15] += w3.w * v;
    }
    #pragma unroll 8
    for (int i = 0; i < 64; i++) {
        float v = s2[i * HW];
        const float* wr = &wlds[(64 + i) * 64 + wq * 16];
        float4 w0 = *(const float4*)wr, w1 = *(const float4*)(wr + 4);
        float4 w2 = *(const float4*)(wr + 8), w3 = *(const float4*)(wr + 12);
        acc[0] += w0.x * v;  acc[1] += w0.y * v;  acc[2] += w0.z * v;  acc[3] += w0.w * v;
        acc[4] += w1.x * v;  acc[5] += w1.y * v;  acc[6] += w1.z * v;  acc[7] += w1.w * v;
        acc[8] += w2.x * v;  acc[9] += w2.y * v;  acc[10] += w2.z * v; acc[11] += w2.w * v;
        acc[12] += w3.x * v; acc[13] += w3.y * v; acc[14] += w3.z * v; acc[15] += w3.w * v;
    }

    float* op = sup2 + (size_t)px * 64 + wq * 16;
    #pragma unroll
    for (int j = 0; j < 16; j += 4) { float4 st = {acc[j], acc[j+1], acc[j+2], acc[j+3]}; *(float4*)(op + j) = st; }
}

// ---------- fused 3-level neighborhood attention (MFMA QK dots) ----------
// dotsF[px][hp]: scores in halo coords (hp = hy*14+hx, 10x14 halo). Window of px
// starts at (lyL,lxL) in halo coords for each level.
template<int KS>
__device__ __forceinline__ void level_softmax(int qc, int y, int x, int ty0, int tx0,
        const _Float16* rpbl, const _Float16* dots_row, _Float16* out_row, bool inplace)
{
    constexpr int R = KS / 2, KK = KS * KS, NB = 2 * KS - 1;
    constexpr int NE = (KK + 7) / 8;
    int ni = min(max(y - R, 0), 96 - KS), nj = min(max(x - R, 0), 96 - KS);
    int lyL = ni - (ty0 - 3), lxL = nj - (tx0 - 3);     // halo coords of window origin
    int br = KS - 1 + ni - y, bc = KS - 1 + nj - x;
    float sv[NE];
    float mx = -1e30f;
    #pragma unroll
    for (int i = 0; i < NE; i++) {
        int e = qc + i * 8;
        if (e < KK) {
            int ey = e / KS, ex = e - ey * KS;
            float s = (float)dots_row[(lyL + ey) * 14 + lxL + ex] + (float)rpbl[(br + ey) * NB + bc + ex];
            sv[i] = s; mx = fmaxf(mx, s);
        } else sv[i] = -1e30f;
    }
    mx = fmaxf(mx, __shfl_xor(mx, 8)); mx = fmaxf(mx, __shfl_xor(mx, 16)); mx = fmaxf(mx, __shfl_xor(mx, 32));
    float sum = 0.f;
    #pragma unroll
    for (int i = 0; i < NE; i++) { sv[i] = __expf(sv[i] - mx); sum += sv[i]; }
    sum += __shfl_xor(sum, 8); sum += __shfl_xor(sum, 16); sum += __shfl_xor(sum, 32);
    float inv = 1.f / sum;
    #pragma unroll
    for (int i = 0; i < NE; i++) {
        int e = qc + i * 8;
        if (e < KK) {
            int ey = e / KS, ex = e - ey * KS;
            _Float16 wv16 = (_Float16)(sv[i] * inv);
            if (inplace) ((_Float16*)dots_row)[(lyL + ey) * 14 + lxL + ex] = wv16;
            else out_row[e] = wv16;
        }
    }
}

__global__ __launch_bounds__(256) void natten_fused(
    const __hip_bfloat16* __restrict__ qB, const float* __restrict__ sup2,
    const unsigned short* __restrict__ vwF,
    const float* __restrict__ vb0, const float* __restrict__ vb1, const float* __restrict__ vb2,
    const float* __restrict__ rpb0, const float* __restrict__ rpb1, const float* __restrict__ rpb2,
    __hip_bfloat16* __restrict__ fused)
{
    __shared__ __align__(16) unsigned short khalo[140 * 72];  // 20160 B; reused as sproj[3][32][72]
    __shared__ __align__(16) unsigned short qlds[32 * 72];    // 4608 B (bf16 q, MFMA A layout)
    __shared__ _Float16 dotsF[32][148];                       // 9472 B (scores in halo coords)
    __shared__ _Float16 a3[32][12];                           // 768 B
    __shared__ _Float16 a5[32][28];                           // 1792 B
    __shared__ _Float16 rlds[276];                            // 552 B  -> ~37.4 KB

    int t = threadIdx.x;
    int bb = blockIdx.y;
    int tx0 = (blockIdx.x % 12) * 8, ty0 = (blockIdx.x / 12) * 4;
    const float* kb = sup2 + (size_t)bb * HW * 64;

    // stage rpb tables (fp16): [0:169)=rpb2, [169:250)=rpb1, [250:275)=rpb0
    for (int e = t; e < 275; e += 256) {
        float v = (e < 169) ? rpb2[e] : ((e < 250) ? rpb1[e - 169] : rpb0[e - 250]);
        rlds[e] = (_Float16)v;
    }

    // stage 10x14 px k-halo (bf16, 64->72 ch pad)
    for (int it = 0; it < 9; it++) {
        int qidx = it * 256 + t;
        if (qidx < 2240) {
            int cq = qidx & 15, pos = qidx >> 4;
            int py = pos / 14, pxx = pos - py * 14;
            int gy = min(max(ty0 - 3 + py, 0), 95);
            int gx = min(max(tx0 - 3 + pxx, 0), 95);
            float4 v = *(const float4*)(kb + (((size_t)gy * 96 + gx) << 6) + cq * 4);
            ushort4 pk = {f2bf(v.x), f2bf(v.y), f2bf(v.z), f2bf(v.w)};
            *(ushort4*)&khalo[pos * 72 + cq * 4] = pk;
        }
    }
    // stage q-tile bf16: 32 px x 8 short8
    if (t < 256) {
        int px = t >> 3, seg = t & 7;
        short8 v = *(const short8*)((const unsigned short*)qB +
            ((size_t)(bb * HW + (ty0 + (px >> 3)) * 96 + tx0 + (px & 7)) << 6) + seg * 8);
        *(short8*)&qlds[px * 72 + seg * 8] = v;
    }
    __syncthreads();

    int lane = t & 63, wv = t >> 6;
    int lm = lane & 15, quad = lane >> 4;

    // MFMA QK dots: 32px x 144pos x 64ch GEMM; wave wv does n-tiles wv, wv+4, wv+8
    #pragma unroll
    for (int ni = 0; ni < 3; ni++) {
        int nt = wv + ni * 4;
        if (nt <= 8) {
            int hp = nt * 16 + lm;
            int hpr = min(hp, 139);
            f32x4 acc0 = {0.f, 0.f, 0.f, 0.f}, acc1 = {0.f, 0.f, 0.f, 0.f};
            #pragma unroll
            for (int kt = 0; kt < 2; kt++) {
                short8 bfrag = *(const short8*)&khalo[hpr * 72 + kt * 32 + quad * 8];
                short8 a0 = *(const short8*)&qlds[lm * 72 + kt * 32 + quad * 8];
                short8 a1 = *(const short8*)&qlds[(16 + lm) * 72 + kt * 32 + quad * 8];
                acc0 = __builtin_amdgcn_mfma_f32_16x16x32_bf16(a0, bfrag, acc0, 0, 0, 0);
                acc1 = __builtin_amdgcn_mfma_f32_16x16x32_bf16(a1, bfrag, acc1, 0, 0, 0);
            }
            if (hp < 140) {
                #pragma unroll
                for (int r = 0; r < 4; r++) {
                    dotsF[quad * 4 + r][hp]      = (_Float16)acc0[r];
                    dotsF[16 + quad * 4 + r][hp] = (_Float16)acc1[r];
                }
            }
        }
    }
    __syncthreads();

    int pxl = wv * 8 + (lane & 7);     // 0..31
    int qc = lane >> 3;                // 0..7
    int pty = pxl >> 3, ptx = pxl & 7;
    int y = ty0 + pty, x = tx0 + ptx;

    int ni7 = min(max(y - 3, 0), 89), nj7 = min(max(x - 3, 0), 89);
    int ly = ni7 - (ty0 - 3), lx = nj7 - (tx0 - 3);

    level_softmax<3>(qc, y, x, ty0, tx0, rlds + 250, &dotsF[pxl][0], &a3[pxl][0], false);
    level_softmax<5>(qc, y, x, ty0, tx0, rlds + 169, &dotsF[pxl][0], &a5[pxl][0], false);
    level_softmax<7>(qc, y, x, ty0, tx0, rlds,       &dotsF[pxl][0], nullptr,     true);

    int ni5 = min(max(y - 2, 0), 91), nj5 = min(max(x - 2, 0), 91);
    int ni3 = min(max(y - 1, 0), 93), nj3 = min(max(x - 1, 0), 93);
    int di5 = ni5 - ni7, dj5 = nj5 - nj7, di3 = ni3 - ni7, dj3 = nj3 - nj7;

    float s2[3][8];
    #pragma unroll
    for (int l = 0; l < 3; l++)
        #pragma unroll
        for (int j = 0; j < 8; j++) s2[l][j] = 0.f;

    #pragma unroll 1
    for (int oy = 0; oy < 7; oy++) {
        #pragma unroll
        for (int ox = 0; ox < 7; ox++) {
            const unsigned short* kp = &khalo[((ly + oy) * 14 + lx + ox) * 72 + qc * 8];
            uint4 ka = *(const uint4*)kp;
            float kv[8] = {bfl(ka.x), bfh(ka.x), bfl(ka.y), bfh(ka.y),
                           bfl(ka.z), bfh(ka.z), bfl(ka.w), bfh(ka.w)};
            float w7 = (float)dotsF[pxl][(ly + oy) * 14 + lx + ox];
            #pragma unroll
            for (int j = 0; j < 8; j++) s2[2][j] += w7 * kv[j];
            int e5y = oy - di5, e5x = ox - dj5;
            if ((unsigned)e5y < 5u && (unsigned)e5x < 5u) {
                float w5 = (float)a5[pxl][e5y * 5 + e5x];
                #pragma unroll
                for (int j = 0; j < 8; j++) s2[1][j] += w5 * kv[j];
            }
            int e3y = oy - di3, e3x = ox - dj3;
            if ((unsigned)e3y < 3u && (unsigned)e3x < 3u) {
                float w3 = (float)a3[pxl][e3y * 3 + e3x];
                #pragma unroll
                for (int j = 0; j < 8; j++) s2[0][j] += w3 * kv[j];
            }
        }
    }
    __syncthreads();   // khalo reads done -> reuse as sproj

    unsigned short* sproj = khalo;   // [lvl*32 + pxl][72]
    #pragma unroll
    for (int l = 0; l < 3; l++) {
        unsigned int pk[4];
        #pragma unroll
        for (int j = 0; j < 4; j++)
            pk[j] = (unsigned int)f2bf(s2[l][2*j]) | ((unsigned int)f2bf(s2[l][2*j+1]) << 16);
        uint4 sv = {pk[0], pk[1], pk[2], pk[3]};
        *(uint4*)&sproj[(l * 32 + pxl) * 72 + qc * 8] = sv;
    }
    __syncthreads();

    // v-projection: wave wv (<3) does level wv's 32x64x64 GEMM
    if (wv < 3) {
        int l = wv;
        const float* vbl = (l == 0) ? vb0 : ((l == 1) ? vb1 : vb2);
        #pragma unroll
        for (int mt = 0; mt < 2; mt++) {
            f32x4 acc[4];
            #pragma unroll
            for (int nt = 0; nt < 4; nt++) acc[nt] = (f32x4){0.f, 0.f, 0.f, 0.f};
            #pragma unroll
            for (int kf = 0; kf < 2; kf++) {
                short8 a = *(const short8*)&sproj[(l * 32 + mt * 16 + lm) * 72 + kf * 32 + quad * 8];
                #pragma unroll
                for (int nt = 0; nt < 4; nt++) {
                    short8 bfr = *(const short8*)&vwF[(((l * 4 + nt) * 2 + kf) * 64 + lane) * 8];
                    acc[nt] = __builtin_amdgcn_mfma_f32_16x16x32_bf16(a, bfr, acc[nt], 0, 0, 0);
                }
            }
            #pragma unroll
            for (int nt = 0; nt < 4; nt++)
                #pragma unroll
                for (int r = 0; r < 4; r++) {
                    int p = mt * 16 + quad * 4 + r;
                    int co = nt * 16 + lm;
                    int py = p >> 3, pxx = p & 7;
                    size_t off = ((size_t)(bb * HW + (ty0 + py) * 96 + tx0 + pxx) << 8) + (l + 1) * 64 + co;
                    fused[off] = __hip_bfloat16(acc[nt][r] + vbl[co]);
                }
        }
    }
}

// ---------- 3x3 fusion conv (256->64): LDS-staged implicit-GEMM bf16 MFMA ----------
__global__ __launch_bounds__(256) void fusion_mfma(
    const __hip_bfloat16* __restrict__ fB, const unsigned short* __restrict__ fwF,
    const float* __restrict__ fb, float* __restrict__ out)
{
    __shared__ __align__(16) unsigned short ah[108 * 72];   // 15552 B
    __shared__ float lds_out[64 * 66];                       // 16896 B
    int t = threadIdx.x;
    int wv = t >> 6, lane = t & 63, lm = lane & 15, quad = lane >> 4;
    int X0 = blockIdx.x * 16, Y0 = blockIdx.y * 4, b = blockIdx.z;
    const unsigned short* fBu = (const unsigned short*)fB;

    f32x4 acc[4] = {};

    for (int chunk = 0; chunk < 4; chunk++) {
        __syncthreads();
        #pragma unroll
        for (int ee = 0; ee < 4; ee++) {
            int e = ee * 256 + t;
            if (e < 864) {
                int seg = e & 7, hp = e >> 3;
                int hy = hp / 18, hx = hp - hy * 18;
                int gy = Y0 - 1 + hy, gx = X0 - 1 + hx;
                bool ok = (gy >= 0) & (gy < 96) & (gx >= 0) & (gx < 96);
                short8 v = {};
                if (ok) v = *(const short8*)(fBu + (((size_t)(b * HW + gy * 96 + gx)) << 8) + chunk * 64 + seg * 8);
                *(short8*)&ah[hp * 72 + seg * 8] = v;
            }
        }
        __syncthreads();
        #pragma unroll
        for (int ky = 0; ky < 3; ky++) {
            #pragma unroll
            for (int kx = 0; kx < 3; kx++) {
                #pragma unroll
                for (int kf = 0; kf < 2; kf++) {
                    short8 a = *(const short8*)&ah[((wv + ky) * 18 + lm + kx) * 72 + kf * 32 + quad * 8];
                    int kc = (ky * 3 + kx) * 8 + chunk * 2 + kf;
                    const unsigned short* bp = fwF + ((size_t)(kc * 4) * 64 + lane) * 8;
                    acc[0] = __builtin_amdgcn_mfma_f32_16x16x32_bf16(a, *(const short8*)(bp),        acc[0], 0, 0, 0);
                    acc[1] = __builtin_amdgcn_mfma_f32_16x16x32_bf16(a, *(const short8*)(bp + 512),  acc[1], 0, 0, 0);
                    acc[2] = __builtin_amdgcn_mfma_f32_16x16x32_bf16(a, *(const short8*)(bp + 1024), acc[2], 0, 0, 0);
                    acc[3] = __builtin_amdgcn_mfma_f32_16x16x32_bf16(a, *(const short8*)(bp + 1536), acc[3], 0, 0, 0);
                }
            }
        }
    }

    #pragma unroll
    for (int nt = 0; nt < 4; nt++)
        #pragma unroll
        for (int r = 0; r < 4; r++) {
            int p = wv * 16 + quad * 4 + r;
            int co = nt * 16 + lm;
            lds_out[co * 66 + p] = acc[nt][r];
        }
    __syncthreads();

    int p2 = t & 63, py = p2 >> 4, px2 = p2 & 15;
    float* ob = out + ((size_t)(b * 64) * 96 + Y0 + py) * 96 + X0 + px2;
    #pragma unroll 4
    for (int i = 0; i < 16; i++) {
        int co = (t >> 6) * 16 + i;
        float v = lds_out[co * 66 + p2] + fb[co];
        ob[(size_t)co * HW] = v > 0.f ? v : 0.f;
    }
}

extern "C" void kernel_launch(void* const* d_in, const int* in_sizes, int n_in,
                              void* d_out, int out_size, void* d_ws, size_t ws_size,
                              hipStream_t stream) {
    const float* sup = (const float*)d_in[0];
    const float* key = (const float*)d_in[1];
    const float* smw = (const float*)d_in[2];
    const float* smb = (const float*)d_in[3];
    const float* rw  = (const float*)d_in[4];
    const float* rb  = (const float*)d_in[5];
    const float *vw[3], *vb[3], *rpb[3];
    if (in_sizes[8] == 25) {
        for (int l = 0; l < 3; l++) {
            vw[l]  = (const float*)d_in[6 + 3 * l];
            vb[l]  = (const float*)d_in[7 + 3 * l];
            rpb[l] = (const float*)d_in[8 + 3 * l];
        }
    } else {
        for (int l = 0; l < 3; l++) {
            vw[l]  = (const float*)d_in[6 + 2 * l];
            vb[l]  = (const float*)d_in[7 + 2 * l];
            rpb[l] = (const float*)d_in[12 + l];
        }
    }
    const float* fw = (const float*)d_in[15];
    const float* fb = (const float*)d_in[16];
    float* out = (float*)d_out;

    float* wsf    = (float*)d_ws;
    float* smooth = wsf;                                    // 2359296 f
    float* sup2   = wsf + 2359296;                          // 2359296 f (NHWC)
    __hip_bfloat16* qBuf = (__hip_bfloat16*)(wsf + 4718592); // 2359296 bf16 (uses half the old qT slot)
    float* rwT    = wsf + 7077888;                          // 8192 f
    unsigned short* vwF = (unsigned short*)(wsf + 7086080); // 12288 bf16
    __hip_bfloat16* fusedB = (__hip_bfloat16*)(wsf + 7092224);  // 9437184 bf16
    unsigned short* fwF    = (unsigned short*)(wsf + 11810816); // 147456 bf16

    prep_weights<<<dim3(656), dim3(256), 0, stream>>>(rw, vw[0], vw[1], vw[2], fw, rwT, vwF, fwF);
    pack_kernel<<<dim3(3, 2, 384), dim3(32, 8), 0, stream>>>(key, sup, qBuf, fusedB);
    shift_smooth<<<dim3(576), dim3(256), 0, stream>>>(sup, smw, smb, smooth);
    reduce_kernel<<<dim3(576), dim3(256), 0, stream>>>(sup, smooth, rwT, rb, sup2);
    natten_fused<<<dim3(288, 4), dim3(256), 0, stream>>>(qBuf, sup2, vwF,
        vb[0], vb[1], vb[2], rpb[0], rpb[1], rpb[2], fusedB);
    fusion_mfma<<<dim3(6, 24, 4), dim3(256), 0, stream>>>(fusedB, fwF, fb, out);
}

// Round 15
// 202.994 us; speedup vs baseline: 1.3704x; 1.0120x over previous
//
#include <hip/hip_runtime.h>
#include <hip/hip_bf16.h>

#define HW 9216
#define NPX 36864

typedef __attribute__((ext_vector_type(8))) short short8;
typedef __attribute__((ext_vector_type(4))) float f32x4;

static __device__ __forceinline__ unsigned short f2bf(float x) {
    union { __hip_bfloat16 h; unsigned short u; } c; c.h = __float2bfloat16(x); return c.u;
}
static __device__ __forceinline__ float bfl(unsigned int u){ return __uint_as_float(u << 16); }
static __device__ __forceinline__ float bfh(unsigned int u){ return __uint_as_float(u & 0xffff0000u); }

// ---------- weight pre-transposes ----------
__global__ __launch_bounds__(256) void prep_weights(
    const float* __restrict__ rw, const float* __restrict__ vw0,
    const float* __restrict__ vw1, const float* __restrict__ vw2,
    const float* __restrict__ fw,
    float* __restrict__ rwT, unsigned short* __restrict__ vwF, unsigned short* __restrict__ fwF)
{
    int idx = blockIdx.x * 256 + threadIdx.x;
    if (idx < 8192) {                       // reduce_w (64,128) -> rwT[i][c]
        int c = idx & 63, i = idx >> 6;
        rwT[idx] = rw[c * 128 + i];
    } else if (idx < 20480) {               // v_w -> MFMA B-fragment order vwF[lvl][nt][kf][lane][j]
        int e = idx - 8192;
        int j = e & 7, lane = (e >> 3) & 63, kf = (e >> 9) & 1, nt = (e >> 10) & 3, lvl = e >> 12;
        int co = nt * 16 + (lane & 15);
        int k = kf * 32 + (lane >> 4) * 8 + j;
        const float* vw = (lvl == 0) ? vw0 : ((lvl == 1) ? vw1 : vw2);
        vwF[e] = f2bf(vw[co * 64 + k]);
    } else if (idx < 167936) {              // fusion_w (64,256,3,3) -> B-fragment order fwF[kc][nt][lane][j]
        int e = idx - 20480;
        int j = e & 7, lane = (e >> 3) & 63, nt = (e >> 9) & 3, kc = e >> 11;   // kc in 0..71
        int co = nt * 16 + (lane & 15);
        int k = kc * 32 + ((lane >> 4) << 3) + j;   // global K index: tap*256 + ci
        int tap = k >> 8, ci = k & 255;
        fwF[e] = f2bf(fw[co * 2304 + ci * 9 + tap]);
    }
}

// ---------- transpose key->qB (NHWC bf16) and sup->fused[ch 0:64] (bf16) ----------
__global__ void pack_kernel(const float* __restrict__ key, const float* __restrict__ sup,
                            __hip_bfloat16* __restrict__ qB, __hip_bfloat16* __restrict__ fused)
{
    __shared__ float lk[32][33], ls[32][33];
    int tx = threadIdx.x, ty = threadIdx.y;
    int x0 = blockIdx.x * 32, c0 = blockIdx.y * 32;
    int z = blockIdx.z; int b = z / 96, y = z - b * 96;
    #pragma unroll
    for (int i = 0; i < 32; i += 8) {
        int c = c0 + ty + i;
        lk[ty + i][tx] = key[((b * 64 + c) * 96 + y) * 96 + x0 + tx];
        ls[ty + i][tx] = sup[((b * 64 + c) * 96 + y) * 96 + x0 + tx];
    }
    __syncthreads();
    #pragma unroll
    for (int i = 0; i < 32; i += 8) {
        int px = (b * 96 + y) * 96 + x0 + ty + i;
        qB[px * 64 + c0 + tx]     = __hip_bfloat16(lk[tx][ty + i]);
        fused[px * 256 + c0 + tx] = __hip_bfloat16(ls[tx][ty + i]);
    }
}

// ---------- shifted grouped 3x3 conv, LDS-staged, wave-uniform out-channel ----------
__global__ __launch_bounds__(256) void shift_smooth(const float* __restrict__ sup,
    const float* __restrict__ w, const float* __restrict__ bias, float* __restrict__ smooth)
{
    __shared__ __align__(16) float tile[8][34][36];
    int bid = blockIdx.x;                 // 576 = 4b * 8grp * 9sj * 2half
    int half = bid & 1;
    int sj   = (bid >> 1) % 9;
    int grp  = (bid / 18) & 7;
    int b    = bid / 144;
    int sby = sj / 3, sbx = sj % 3;
    int Y0 = sby * 32, X0 = sbx * 32;
    int sh = 3 * ((grp >= 5) - (grp < 3));
    int mm = (grp < 3) ? grp : ((grp < 5) ? ((grp == 3) ? 0 : 2) : (grp - 5));
    int sw = 3 * mm - 3;
    int t = threadIdx.x;

    const float* supg = sup + (size_t)(b * 64 + grp * 8) * HW;
    #pragma unroll
    for (int pp = 0; pp < 5; pp++) {
        int pos = pp * 256 + t;
        if (pos < 1156) {
            int r = pos / 34, u = pos - r * 34;
            int yy = Y0 - 1 + r, xx = X0 - 1 + u;
            int ys = yy - sh, xs = xx - sw;
            bool ok = (yy >= 0) & (yy < 96) & (xx >= 0) & (xx < 96) &
                      (ys >= 0) & (ys < 96) & (xs >= 0) & (xs < 96);
            int addr = ok ? (ys * 96 + xs) : 0;
            #pragma unroll
            for (int ic = 0; ic < 8; ic++) {
                float v = supg[(size_t)ic * HW + addr];
                tile[ic][r][u] = ok ? v : 0.f;
            }
        }
    }
    __syncthreads();

    int c = __builtin_amdgcn_readfirstlane(grp * 8 + half * 4 + (t >> 6));
    int lane = t & 63;
    int ty4 = lane >> 3, tx4 = lane & 7;
    int py0 = ty4 * 4, x0r = tx4 * 4;

    float bz = bias[c];
    float acc[4][4];
    #pragma unroll
    for (int jr = 0; jr < 4; jr++)
        #pragma unroll
        for (int j = 0; j < 4; j++) acc[jr][j] = bz;

    const float* wp = w + c * 72;
    for (int ic = 0; ic < 8; ic++) {
        float wr[9];
        #pragma unroll
        for (int q = 0; q < 9; q++) wr[q] = wp[ic * 9 + q];
        #pragma unroll
        for (int rr = 0; rr < 6; rr++) {
            float4 fa = *(const float4*)&tile[ic][py0 + rr][x0r];
            float4 fb4 = *(const float4*)&tile[ic][py0 + rr][x0r + 4];
            float f[6] = {fa.x, fa.y, fa.z, fa.w, fb4.x, fb4.y};
            #pragma unroll
            for (int ky = 0; ky < 3; ky++) {
                int jr = rr - ky;
                if (jr >= 0 && jr < 4) {
                    #pragma unroll
                    for (int j = 0; j < 4; j++)
                        acc[jr][j] += wr[ky*3]*f[j] + wr[ky*3+1]*f[j+1] + wr[ky*3+2]*f[j+2];
                }
            }
        }
    }

    float* op = smooth + ((size_t)(b * 64 + c) * 96 + Y0 + py0) * 96 + X0 + x0r;
    #pragma unroll
    for (int jr = 0; jr < 4; jr++) {
        float4 st = {acc[jr][0], acc[jr][1], acc[jr][2], acc[jr][3]};
        *(float4*)(op + (size_t)jr * 96) = st;
    }
}

// ---------- 1x1 reduce conv (128->64): weights in LDS (broadcast), px per lane ----------
__global__ __launch_bounds__(256) void reduce_kernel(const float* __restrict__ sup,
    const float* __restrict__ smooth, const float* __restrict__ rwT,
    const float* __restrict__ rb, float* __restrict__ sup2)
{
    __shared__ __align__(16) float wlds[8192];   // rwT[i][c], 32 KB
    int t = threadIdx.x;
    #pragma unroll
    for (int e = 0; e < 8; e++) {
        int idx = (e * 256 + t) * 4;
        *(float4*)&wlds[idx] = *(const float4*)&rwT[idx];
    }
    __syncthreads();

    int lane = t & 63, wq = t >> 6;
    int px = blockIdx.x * 64 + lane;
    int b = px / HW; int rem = px - b * HW;
    const float* s1 = sup + (size_t)b * 64 * HW + rem;
    const float* s2 = smooth + (size_t)b * 64 * HW + rem;
    float acc[16];
    #pragma unroll
    for (int j = 0; j < 16; j++) acc[j] = rb[wq * 16 + j];

    #pragma unroll 8
    for (int i = 0; i < 64; i++) {
        float v = s1[i * HW];
        const float* wr = &wlds[i * 64 + wq * 16];
        float4 w0 = *(const float4*)wr, w1 = *(const float4*)(wr + 4);
        float4 w2 = *(const float4*)(wr + 8), w3 = *(const float4*)(wr + 12);
        acc[0] += w0.x * v;  acc[1] += w0.y * v;  acc[2] += w0.z * v;  acc[3] += w0.w * v;
        acc[4] += w1.x * v;  acc[5] += w1.y * v;  acc[6] += w1.z * v;  acc[7] += w1.w * v;
        acc[8] += w2.x * v;  acc[9] += w2.y * v;  acc[10] += w2.z * v; acc[11] += w2.w * v;
        acc[12] += w3.x * v; acc[13] += w3.y * v; acc[14] += w3.z * v; acc[15] += w3.w * v;
    }
    #pragma unroll 8
    for (int i = 0; i < 64; i++) {
        float v = s2[i * HW];
        const float* wr = &wlds[(64 + i) * 64 + wq * 16];
        float4 w0 = *(const float4*)wr, w1 = *(const float4*)(wr + 4);
        float4 w2 = *(const float4*)(wr + 8), w3 = *(const float4*)(wr + 12);
        acc[0] += w0.x * v;  acc[1] += w0.y * v;  acc[2] += w0.z * v;  acc[3] += w0.w * v;
        acc[4] += w1.x * v;  acc[5] += w1.y * v;  acc[6] += w1.z * v;  acc[7] += w1.w * v;
        acc[8] += w2.x * v;  acc[9] += w2.y * v;  acc[10] += w2.z * v; acc[11] += w2.w * v;
        acc[12] += w3.x * v; acc[13] += w3.y * v; acc[14] += w3.z * v; acc[15] += w3.w * v;
    }

    float* op = sup2 + (size_t)px * 64 + wq * 16;
    #pragma unroll
    for (int j = 0; j < 16; j += 4) { float4 st = {acc[j], acc[j+1], acc[j+2], acc[j+3]}; *(float4*)(op + j) = st; }
}

// ---------- fused 3-level neighborhood attention (MFMA QK dots) ----------
template<int KS>
__device__ __forceinline__ void level_softmax(int qc, int y, int x, int ty0, int tx0,
        const _Float16* rpbl, const _Float16* dots_row, _Float16* out_row, bool inplace)
{
    constexpr int R = KS / 2, KK = KS * KS, NB = 2 * KS - 1;
    constexpr int NE = (KK + 7) / 8;
    int ni = min(max(y - R, 0), 96 - KS), nj = min(max(x - R, 0), 96 - KS);
    int lyL = ni - (ty0 - 3), lxL = nj - (tx0 - 3);     // halo coords of window origin
    int br = KS - 1 + ni - y, bc = KS - 1 + nj - x;
    float sv[NE];
    float mx = -1e30f;
    #pragma unroll
    for (int i = 0; i < NE; i++) {
        int e = qc + i * 8;
        if (e < KK) {
            int ey = e / KS, ex = e - ey * KS;
            float s = (float)dots_row[(lyL + ey) * 14 + lxL + ex] + (float)rpbl[(br + ey) * NB + bc + ex];
            sv[i] = s; mx = fmaxf(mx, s);
        } else sv[i] = -1e30f;
    }
    mx = fmaxf(mx, __shfl_xor(mx, 8)); mx = fmaxf(mx, __shfl_xor(mx, 16)); mx = fmaxf(mx, __shfl_xor(mx, 32));
    float sum = 0.f;
    #pragma unroll
    for (int i = 0; i < NE; i++) { sv[i] = __expf(sv[i] - mx); sum += sv[i]; }
    sum += __shfl_xor(sum, 8); sum += __shfl_xor(sum, 16); sum += __shfl_xor(sum, 32);
    float inv = 1.f / sum;
    #pragma unroll
    for (int i = 0; i < NE; i++) {
        int e = qc + i * 8;
        if (e < KK) {
            int ey = e / KS, ex = e - ey * KS;
            _Float16 wv16 = (_Float16)(sv[i] * inv);
            if (inplace) ((_Float16*)dots_row)[(lyL + ey) * 14 + lxL + ex] = wv16;
            else out_row[e] = wv16;
        }
    }
}

__global__ __launch_bounds__(256) void natten_fused(
    const __hip_bfloat16* __restrict__ qB, const float* __restrict__ sup2,
    const unsigned short* __restrict__ vwF,
    const float* __restrict__ vb0, const float* __restrict__ vb1, const float* __restrict__ vb2,
    const float* __restrict__ rpb0, const float* __restrict__ rpb1, const float* __restrict__ rpb2,
    __hip_bfloat16* __restrict__ fused)
{
    __shared__ __align__(16) unsigned short khalo[140 * 72];  // 20160 B; reused as sproj[3][32][72]
    __shared__ __align__(16) unsigned short qlds[32 * 72];    // 4608 B (bf16 q, MFMA A layout)
    __shared__ _Float16 dotsF[32][148];                       // 9472 B (scores in halo coords)
    __shared__ _Float16 a3[32][12];                           // 768 B
    __shared__ _Float16 a5[32][28];                           // 1792 B
    __shared__ _Float16 rlds[276];                            // 552 B  -> ~37.4 KB

    int t = threadIdx.x;
    int bb = blockIdx.y;
    int tx0 = (blockIdx.x % 12) * 8, ty0 = (blockIdx.x / 12) * 4;
    const float* kb = sup2 + (size_t)bb * HW * 64;

    for (int e = t; e < 275; e += 256) {
        float v = (e < 169) ? rpb2[e] : ((e < 250) ? rpb1[e - 169] : rpb0[e - 250]);
        rlds[e] = (_Float16)v;
    }

    for (int it = 0; it < 9; it++) {
        int qidx = it * 256 + t;
        if (qidx < 2240) {
            int cq = qidx & 15, pos = qidx >> 4;
            int py = pos / 14, pxx = pos - py * 14;
            int gy = min(max(ty0 - 3 + py, 0), 95);
            int gx = min(max(tx0 - 3 + pxx, 0), 95);
            float4 v = *(const float4*)(kb + (((size_t)gy * 96 + gx) << 6) + cq * 4);
            ushort4 pk = {f2bf(v.x), f2bf(v.y), f2bf(v.z), f2bf(v.w)};
            *(ushort4*)&khalo[pos * 72 + cq * 4] = pk;
        }
    }
    if (t < 256) {
        int px = t >> 3, seg = t & 7;
        short8 v = *(const short8*)((const unsigned short*)qB +
            ((size_t)(bb * HW + (ty0 + (px >> 3)) * 96 + tx0 + (px & 7)) << 6) + seg * 8);
        *(short8*)&qlds[px * 72 + seg * 8] = v;
    }
    __syncthreads();

    int lane = t & 63, wv = t >> 6;
    int lm = lane & 15, quad = lane >> 4;

    // MFMA QK dots: 32px x 144pos x 64ch GEMM; wave wv does n-tiles wv, wv+4, wv+8
    #pragma unroll
    for (int ni = 0; ni < 3; ni++) {
        int nt = wv + ni * 4;
        if (nt <= 8) {
            int hp = nt * 16 + lm;
            int hpr = min(hp, 139);
            f32x4 acc0 = {0.f, 0.f, 0.f, 0.f}, acc1 = {0.f, 0.f, 0.f, 0.f};
            #pragma unroll
            for (int kt = 0; kt < 2; kt++) {
                short8 bfrag = *(const short8*)&khalo[hpr * 72 + kt * 32 + quad * 8];
                short8 a0 = *(const short8*)&qlds[lm * 72 + kt * 32 + quad * 8];
                short8 a1 = *(const short8*)&qlds[(16 + lm) * 72 + kt * 32 + quad * 8];
                acc0 = __builtin_amdgcn_mfma_f32_16x16x32_bf16(a0, bfrag, acc0, 0, 0, 0);
                acc1 = __builtin_amdgcn_mfma_f32_16x16x32_bf16(a1, bfrag, acc1, 0, 0, 0);
            }
            if (hp < 140) {
                #pragma unroll
                for (int r = 0; r < 4; r++) {
                    dotsF[quad * 4 + r][hp]      = (_Float16)acc0[r];
                    dotsF[16 + quad * 4 + r][hp] = (_Float16)acc1[r];
                }
            }
        }
    }
    __syncthreads();

    int pxl = wv * 8 + (lane & 7);     // 0..31
    int qc = lane >> 3;                // 0..7
    int pty = pxl >> 3, ptx = pxl & 7;
    int y = ty0 + pty, x = tx0 + ptx;

    int ni7 = min(max(y - 3, 0), 89), nj7 = min(max(x - 3, 0), 89);
    int ly = ni7 - (ty0 - 3), lx = nj7 - (tx0 - 3);

    level_softmax<3>(qc, y, x, ty0, tx0, rlds + 250, &dotsF[pxl][0], &a3[pxl][0], false);
    level_softmax<5>(qc, y, x, ty0, tx0, rlds + 169, &dotsF[pxl][0], &a5[pxl][0], false);
    level_softmax<7>(qc, y, x, ty0, tx0, rlds,       &dotsF[pxl][0], nullptr,     true);

    int ni5 = min(max(y - 2, 0), 91), nj5 = min(max(x - 2, 0), 91);
    int ni3 = min(max(y - 1, 0), 93), nj3 = min(max(x - 1, 0), 93);
    int di5 = ni5 - ni7, dj5 = nj5 - nj7, di3 = ni3 - ni7, dj3 = nj3 - nj7;

    float s2[3][8];
    #pragma unroll
    for (int l = 0; l < 3; l++)
        #pragma unroll
        for (int j = 0; j < 8; j++) s2[l][j] = 0.f;

    #pragma unroll 1
    for (int oy = 0; oy < 7; oy++) {
        #pragma unroll
        for (int ox = 0; ox < 7; ox++) {
            const unsigned short* kp = &khalo[((ly + oy) * 14 + lx + ox) * 72 + qc * 8];
            uint4 ka = *(const uint4*)kp;
            float kv[8] = {bfl(ka.x), bfh(ka.x), bfl(ka.y), bfh(ka.y),
                           bfl(ka.z), bfh(ka.z), bfl(ka.w), bfh(ka.w)};
            float w7 = (float)dotsF[pxl][(ly + oy) * 14 + lx + ox];
            #pragma unroll
            for (int j = 0; j < 8; j++) s2[2][j] += w7 * kv[j];
            int e5y = oy - di5, e5x = ox - dj5;
            if ((unsigned)e5y < 5u && (unsigned)e5x < 5u) {
                float w5 = (float)a5[pxl][e5y * 5 + e5x];
                #pragma unroll
                for (int j = 0; j < 8; j++) s2[1][j] += w5 * kv[j];
            }
            int e3y = oy - di3, e3x = ox - dj3;
            if ((unsigned)e3y < 3u && (unsigned)e3x < 3u) {
                float w3 = (float)a3[pxl][e3y * 3 + e3x];
                #pragma unroll
                for (int j = 0; j < 8; j++) s2[0][j] += w3 * kv[j];
            }
        }
    }
    __syncthreads();   // khalo reads done -> reuse as sproj

    unsigned short* sproj = khalo;   // [lvl*32 + pxl][72]
    #pragma unroll
    for (int l = 0; l < 3; l++) {
        unsigned int pk[4];
        #pragma unroll
        for (int j = 0; j < 4; j++)
            pk[j] = (unsigned int)f2bf(s2[l][2*j]) | ((unsigned int)f2bf(s2[l][2*j+1]) << 16);
        uint4 sv = {pk[0], pk[1], pk[2], pk[3]};
        *(uint4*)&sproj[(l * 32 + pxl) * 72 + qc * 8] = sv;
    }
    __syncthreads();

    if (wv < 3) {
        int l = wv;
        const float* vbl = (l == 0) ? vb0 : ((l == 1) ? vb1 : vb2);
        #pragma unroll
        for (int mt = 0; mt < 2; mt++) {
            f32x4 acc[4];
            #pragma unroll
            for (int nt = 0; nt < 4; nt++) acc[nt] = (f32x4){0.f, 0.f, 0.f, 0.f};
            #pragma unroll
            for (int kf = 0; kf < 2; kf++) {
                short8 a = *(const short8*)&sproj[(l * 32 + mt * 16 + lm) * 72 + kf * 32 + quad * 8];
                #pragma unroll
                for (int nt = 0; nt < 4; nt++) {
                    short8 bfr = *(const short8*)&vwF[(((l * 4 + nt) * 2 + kf) * 64 + lane) * 8];
                    acc[nt] = __builtin_amdgcn_mfma_f32_16x16x32_bf16(a, bfr, acc[nt], 0, 0, 0);
                }
            }
            #pragma unroll
            for (int nt = 0; nt < 4; nt++)
                #pragma unroll
                for (int r = 0; r < 4; r++) {
                    int p = mt * 16 + quad * 4 + r;
                    int co = nt * 16 + lm;
                    int py = p >> 3, pxx = p & 7;
                    size_t off = ((size_t)(bb * HW + (ty0 + py) * 96 + tx0 + pxx) << 8) + (l + 1) * 64 + co;
                    fused[off] = __hip_bfloat16(acc[nt][r] + vbl[co]);
                }
        }
    }
}

// ---------- 3x3 fusion conv (256->64): 16x8 px tile, 2 m-tiles/wave (B reuse x2) ----------
__global__ __launch_bounds__(256) void fusion_mfma(
    const __hip_bfloat16* __restrict__ fB, const unsigned short* __restrict__ fwF,
    const float* __restrict__ fb, float* __restrict__ out)
{
    __shared__ __align__(16) unsigned char smem[33408];  // union: halo (25.9 KB) / epilogue (33.3 KB)
    unsigned short* ah = (unsigned short*)smem;          // [180 px][72]
    float* lds_out = (float*)smem;                       // [64 co][130]
    int t = threadIdx.x;
    int wv = t >> 6, lane = t & 63, lm = lane & 15, quad = lane >> 4;
    int X0 = blockIdx.x * 16, Y0 = blockIdx.y * 8, b = blockIdx.z;
    const unsigned short* fBu = (const unsigned short*)fB;

    f32x4 acc[2][4] = {};

    for (int chunk = 0; chunk < 4; chunk++) {
        __syncthreads();
        // stage 18x10 halo for this 64-ci chunk: 180 px x 8 segs
        #pragma unroll
        for (int ee = 0; ee < 6; ee++) {
            int e = ee * 256 + t;
            if (e < 1440) {
                int seg = e & 7, hp = e >> 3;
                int hy = hp / 18, hx = hp - hy * 18;
                int gy = Y0 - 1 + hy, gx = X0 - 1 + hx;
                bool ok = (gy >= 0) & (gy < 96) & (gx >= 0) & (gx < 96);
                short8 v = {};
                if (ok) v = *(const short8*)(fBu + (((size_t)(b * HW + gy * 96 + gx)) << 8) + chunk * 64 + seg * 8);
                *(short8*)&ah[hp * 72 + seg * 8] = v;
            }
        }
        __syncthreads();
        #pragma unroll
        for (int ky = 0; ky < 3; ky++) {
            #pragma unroll
            for (int kx = 0; kx < 3; kx++) {
                #pragma unroll
                for (int kf = 0; kf < 2; kf++) {
                    int kc = (ky * 3 + kx) * 8 + chunk * 2 + kf;
                    const unsigned short* bp = fwF + ((size_t)(kc * 4) * 64 + lane) * 8;
                    short8 b0 = *(const short8*)(bp);
                    short8 b1 = *(const short8*)(bp + 512);
                    short8 b2 = *(const short8*)(bp + 1024);
                    short8 b3 = *(const short8*)(bp + 1536);
                    #pragma unroll
                    for (int mt = 0; mt < 2; mt++) {
                        int R = 2 * wv + mt;
                        short8 a = *(const short8*)&ah[((R + ky) * 18 + lm + kx) * 72 + kf * 32 + quad * 8];
                        acc[mt][0] = __builtin_amdgcn_mfma_f32_16x16x32_bf16(a, b0, acc[mt][0], 0, 0, 0);
                        acc[mt][1] = __builtin_amdgcn_mfma_f32_16x16x32_bf16(a, b1, acc[mt][1], 0, 0, 0);
                        acc[mt][2] = __builtin_amdgcn_mfma_f32_16x16x32_bf16(a, b2, acc[mt][2], 0, 0, 0);
                        acc[mt][3] = __builtin_amdgcn_mfma_f32_16x16x32_bf16(a, b3, acc[mt][3], 0, 0, 0);
                    }
                }
            }
        }
    }

    __syncthreads();   // ah reads done -> reuse as lds_out
    #pragma unroll
    for (int mt = 0; mt < 2; mt++)
        #pragma unroll
        for (int nt = 0; nt < 4; nt++)
            #pragma unroll
            for (int r = 0; r < 4; r++) {
                int p = (2 * wv + mt) * 16 + quad * 4 + r;   // linear px: row*16 + x
                int co = nt * 16 + lm;
                lds_out[co * 130 + p] = acc[mt][nt][r];
            }
    __syncthreads();

    int p2 = t & 127, py = p2 >> 4, px2 = p2 & 15;
    float* ob = out + ((size_t)(b * 64) * 96 + Y0 + py) * 96 + X0 + px2;
    #pragma unroll 4
    for (int i = 0; i < 32; i++) {
        int co = (t >> 7) * 32 + i;
        float v = lds_out[co * 130 + p2] + fb[co];
        ob[(size_t)co * HW] = v > 0.f ? v : 0.f;
    }
}

extern "C" void kernel_launch(void* const* d_in, const int* in_sizes, int n_in,
                              void* d_out, int out_size, void* d_ws, size_t ws_size,
                              hipStream_t stream) {
    const float* sup = (const float*)d_in[0];
    const float* key = (const float*)d_in[1];
    const float* smw = (const float*)d_in[2];
    const float* smb = (const float*)d_in[3];
    const float* rw  = (const float*)d_in[4];
    const float* rb  = (const float*)d_in[5];
    const float *vw[3], *vb[3], *rpb[3];
    if (in_sizes[8] == 25) {
        for (int l = 0; l < 3; l++) {
            vw[l]  = (const float*)d_in[6 + 3 * l];
            vb[l]  = (const float*)d_in[7 + 3 * l];
            rpb[l] = (const float*)d_in[8 + 3 * l];
        }
    } else {
        for (int l = 0; l < 3; l++) {
            vw[l]  = (const float*)d_in[6 + 2 * l];
            vb[l]  = (const float*)d_in[7 + 2 * l];
            rpb[l] = (const float*)d_in[12 + l];
        }
    }
    const float* fw = (const float*)d_in[15];
    const float* fb = (const float*)d_in[16];
    float* out = (float*)d_out;

    float* wsf    = (float*)d_ws;
    float* smooth = wsf;                                    // 2359296 f
    float* sup2   = wsf + 2359296;                          // 2359296 f (NHWC)
    __hip_bfloat16* qBuf = (__hip_bfloat16*)(wsf + 4718592); // 2359296 bf16
    float* rwT    = wsf + 7077888;                          // 8192 f
    unsigned short* vwF = (unsigned short*)(wsf + 7086080); // 12288 bf16
    __hip_bfloat16* fusedB = (__hip_bfloat16*)(wsf + 7092224);  // 9437184 bf16
    unsigned short* fwF    = (unsigned short*)(wsf + 11810816); // 147456 bf16

    prep_weights<<<dim3(656), dim3(256), 0, stream>>>(rw, vw[0], vw[1], vw[2], fw, rwT, vwF, fwF);
    pack_kernel<<<dim3(3, 2, 384), dim3(32, 8), 0, stream>>>(key, sup, qBuf, fusedB);
    shift_smooth<<<dim3(576), dim3(256), 0, stream>>>(sup, smw, smb, smooth);
    reduce_kernel<<<dim3(576), dim3(256), 0, stream>>>(sup, smooth, rwT, rb, sup2);
    natten_fused<<<dim3(288, 4), dim3(256), 0, stream>>>(qBuf, sup2, vwF,
        vb[0], vb[1], vb[2], rpb[0], rpb[1], rpb[2], fusedB);
    fusion_mfma<<<dim3(6, 12, 4), dim3(256), 0, stream>>>(fusedB, fwF, fb, out);
}

// Round 16
// 188.378 us; speedup vs baseline: 1.4767x; 1.0776x over previous
//
#include <hip/hip_runtime.h>
#include <hip/hip_bf16.h>

#define HW 9216
#define NPX 36864

typedef __attribute__((ext_vector_type(8))) short short8;
typedef __attribute__((ext_vector_type(4))) float f32x4;

static __device__ __forceinline__ unsigned short f2bf(float x) {
    union { __hip_bfloat16 h; unsigned short u; } c; c.h = __float2bfloat16(x); return c.u;
}
static __device__ __forceinline__ float bfl(unsigned int u){ return __uint_as_float(u << 16); }
static __device__ __forceinline__ float bfh(unsigned int u){ return __uint_as_float(u & 0xffff0000u); }

// ---------- weight pre-transposes ----------
__global__ __launch_bounds__(256) void prep_weights(
    const float* __restrict__ rw, const float* __restrict__ vw0,
    const float* __restrict__ vw1, const float* __restrict__ vw2,
    const float* __restrict__ fw,
    unsigned short* __restrict__ rwF, unsigned short* __restrict__ vwF, unsigned short* __restrict__ fwF)
{
    int idx = blockIdx.x * 256 + threadIdx.x;
    if (idx < 8192) {                       // reduce_w (64,128) -> B-fragment order rwF[nt][kf][lane][j]
        int e = idx;
        int j = e & 7, lane = (e >> 3) & 63, kf = (e >> 9) & 3, nt = e >> 11;   // nt 0..3
        int co = nt * 16 + (lane & 15);
        int k = kf * 32 + (lane >> 4) * 8 + j;
        rwF[e] = f2bf(rw[co * 128 + k]);
    } else if (idx < 20480) {               // v_w -> MFMA B-fragment order vwF[lvl][nt][kf][lane][j]
        int e = idx - 8192;
        int j = e & 7, lane = (e >> 3) & 63, kf = (e >> 9) & 1, nt = (e >> 10) & 3, lvl = e >> 12;
        int co = nt * 16 + (lane & 15);
        int k = kf * 32 + (lane >> 4) * 8 + j;
        const float* vw = (lvl == 0) ? vw0 : ((lvl == 1) ? vw1 : vw2);
        vwF[e] = f2bf(vw[co * 64 + k]);
    } else if (idx < 167936) {              // fusion_w (64,256,3,3) -> B-fragment order fwF[kc][nt][lane][j]
        int e = idx - 20480;
        int j = e & 7, lane = (e >> 3) & 63, nt = (e >> 9) & 3, kc = e >> 11;   // kc in 0..71
        int co = nt * 16 + (lane & 15);
        int k = kc * 32 + ((lane >> 4) << 3) + j;   // global K index: tap*256 + ci
        int tap = k >> 8, ci = k & 255;
        fwF[e] = f2bf(fw[co * 2304 + ci * 9 + tap]);
    }
}

// ---------- transpose key->qB (NHWC bf16) and sup->fused[ch 0:64] (bf16) ----------
__global__ void pack_kernel(const float* __restrict__ key, const float* __restrict__ sup,
                            __hip_bfloat16* __restrict__ qB, __hip_bfloat16* __restrict__ fused)
{
    __shared__ float lk[32][33], ls[32][33];
    int tx = threadIdx.x, ty = threadIdx.y;
    int x0 = blockIdx.x * 32, c0 = blockIdx.y * 32;
    int z = blockIdx.z; int b = z / 96, y = z - b * 96;
    #pragma unroll
    for (int i = 0; i < 32; i += 8) {
        int c = c0 + ty + i;
        lk[ty + i][tx] = key[((b * 64 + c) * 96 + y) * 96 + x0 + tx];
        ls[ty + i][tx] = sup[((b * 64 + c) * 96 + y) * 96 + x0 + tx];
    }
    __syncthreads();
    #pragma unroll
    for (int i = 0; i < 32; i += 8) {
        int px = (b * 96 + y) * 96 + x0 + ty + i;
        qB[px * 64 + c0 + tx]     = __hip_bfloat16(lk[tx][ty + i]);
        fused[px * 256 + c0 + tx] = __hip_bfloat16(ls[tx][ty + i]);
    }
}

// ---------- shifted grouped 3x3 conv, LDS-staged, wave-uniform out-channel ----------
__global__ __launch_bounds__(256) void shift_smooth(const float* __restrict__ sup,
    const float* __restrict__ w, const float* __restrict__ bias, float* __restrict__ smooth)
{
    __shared__ __align__(16) float tile[8][34][36];
    int bid = blockIdx.x;                 // 576 = 4b * 8grp * 9sj * 2half
    int half = bid & 1;
    int sj   = (bid >> 1) % 9;
    int grp  = (bid / 18) & 7;
    int b    = bid / 144;
    int sby = sj / 3, sbx = sj % 3;
    int Y0 = sby * 32, X0 = sbx * 32;
    int sh = 3 * ((grp >= 5) - (grp < 3));
    int mm = (grp < 3) ? grp : ((grp < 5) ? ((grp == 3) ? 0 : 2) : (grp - 5));
    int sw = 3 * mm - 3;
    int t = threadIdx.x;

    const float* supg = sup + (size_t)(b * 64 + grp * 8) * HW;
    #pragma unroll
    for (int pp = 0; pp < 5; pp++) {
        int pos = pp * 256 + t;
        if (pos < 1156) {
            int r = pos / 34, u = pos - r * 34;
            int yy = Y0 - 1 + r, xx = X0 - 1 + u;
            int ys = yy - sh, xs = xx - sw;
            bool ok = (yy >= 0) & (yy < 96) & (xx >= 0) & (xx < 96) &
                      (ys >= 0) & (ys < 96) & (xs >= 0) & (xs < 96);
            int addr = ok ? (ys * 96 + xs) : 0;
            #pragma unroll
            for (int ic = 0; ic < 8; ic++) {
                float v = supg[(size_t)ic * HW + addr];
                tile[ic][r][u] = ok ? v : 0.f;
            }
        }
    }
    __syncthreads();

    int c = __builtin_amdgcn_readfirstlane(grp * 8 + half * 4 + (t >> 6));
    int lane = t & 63;
    int ty4 = lane >> 3, tx4 = lane & 7;
    int py0 = ty4 * 4, x0r = tx4 * 4;

    float bz = bias[c];
    float acc[4][4];
    #pragma unroll
    for (int jr = 0; jr < 4; jr++)
        #pragma unroll
        for (int j = 0; j < 4; j++) acc[jr][j] = bz;

    const float* wp = w + c * 72;
    for (int ic = 0; ic < 8; ic++) {
        float wr[9];
        #pragma unroll
        for (int q = 0; q < 9; q++) wr[q] = wp[ic * 9 + q];
        #pragma unroll
        for (int rr = 0; rr < 6; rr++) {
            float4 fa = *(const float4*)&tile[ic][py0 + rr][x0r];
            float4 fb4 = *(const float4*)&tile[ic][py0 + rr][x0r + 4];
            float f[6] = {fa.x, fa.y, fa.z, fa.w, fb4.x, fb4.y};
            #pragma unroll
            for (int ky = 0; ky < 3; ky++) {
                int jr = rr - ky;
                if (jr >= 0 && jr < 4) {
                    #pragma unroll
                    for (int j = 0; j < 4; j++)
                        acc[jr][j] += wr[ky*3]*f[j] + wr[ky*3+1]*f[j+1] + wr[ky*3+2]*f[j+2];
                }
            }
        }
    }

    float* op = smooth + ((size_t)(b * 64 + c) * 96 + Y0 + py0) * 96 + X0 + x0r;
    #pragma unroll
    for (int jr = 0; jr < 4; jr++) {
        float4 st = {acc[jr][0], acc[jr][1], acc[jr][2], acc[jr][3]};
        *(float4*)(op + (size_t)jr * 96) = st;
    }
}

// ---------- 1x1 reduce conv (128->64) as bf16 MFMA; sup2 out bf16 NHWC ----------
// A[64px][128ci]: ci 0:64 from fusedB (bf16 NHWC, free), 64:128 from smooth (fp32 NCHW).
__global__ __launch_bounds__(256) void reduce_mfma(
    const __hip_bfloat16* __restrict__ fB, const float* __restrict__ smooth,
    const unsigned short* __restrict__ rwF, const float* __restrict__ rb,
    unsigned short* __restrict__ sup2B)
{
    __shared__ __align__(16) unsigned short A[64 * 136];   // stride 136: 16B-aligned frags
    int t = threadIdx.x;
    int gpx0 = blockIdx.x * 64;
    int b = gpx0 / HW, rem0 = gpx0 - b * HW;
    const unsigned short* fBu = (const unsigned short*)fB;

    // sup half: 64 px x 8 segs short8 from fusedB[px][0:64]
    #pragma unroll
    for (int it = 0; it < 2; it++) {
        int e = it * 256 + t;
        int px = e >> 3, seg = e & 7;
        short8 v = *(const short8*)(fBu + ((size_t)(gpx0 + px) << 8) + seg * 8);
        *(short8*)&A[px * 136 + seg * 8] = v;
    }
    // smooth half: 4096 tasks, wave-coalesced global reads (px = t&63)
    #pragma unroll
    for (int it = 0; it < 16; it++) {
        int e = it * 256 + t;
        int px = e & 63, ci = e >> 6;
        float v = smooth[(size_t)(b * 64 + ci) * HW + rem0 + px];
        A[px * 136 + 64 + ci] = f2bf(v);
    }
    __syncthreads();

    int lane = t & 63, wv = t >> 6;
    int lm = lane & 15, quad = lane >> 4;
    f32x4 acc[4] = {};
    #pragma unroll
    for (int kf = 0; kf < 4; kf++) {
        short8 a = *(const short8*)&A[(wv * 16 + lm) * 136 + kf * 32 + quad * 8];
        #pragma unroll
        for (int nt = 0; nt < 4; nt++) {
            short8 bfr = *(const short8*)&rwF[((nt * 4 + kf) * 64 + lane) * 8];
            acc[nt] = __builtin_amdgcn_mfma_f32_16x16x32_bf16(a, bfr, acc[nt], 0, 0, 0);
        }
    }
    #pragma unroll
    for (int nt = 0; nt < 4; nt++)
        #pragma unroll
        for (int r = 0; r < 4; r++) {
            int px = wv * 16 + quad * 4 + r;
            int co = nt * 16 + lm;
            sup2B[(size_t)(gpx0 + px) * 64 + co] = f2bf(acc[nt][r] + rb[co]);
        }
}

// ---------- fused 3-level neighborhood attention (MFMA QK dots) ----------
template<int KS>
__device__ __forceinline__ void level_softmax(int qc, int y, int x, int ty0, int tx0,
        const _Float16* rpbl, const _Float16* dots_row, _Float16* out_row, bool inplace)
{
    constexpr int R = KS / 2, KK = KS * KS, NB = 2 * KS - 1;
    constexpr int NE = (KK + 7) / 8;
    int ni = min(max(y - R, 0), 96 - KS), nj = min(max(x - R, 0), 96 - KS);
    int lyL = ni - (ty0 - 3), lxL = nj - (tx0 - 3);
    int br = KS - 1 + ni - y, bc = KS - 1 + nj - x;
    float sv[NE];
    float mx = -1e30f;
    #pragma unroll
    for (int i = 0; i < NE; i++) {
        int e = qc + i * 8;
        if (e < KK) {
            int ey = e / KS, ex = e - ey * KS;
            float s = (float)dots_row[(lyL + ey) * 14 + lxL + ex] + (float)rpbl[(br + ey) * NB + bc + ex];
            sv[i] = s; mx = fmaxf(mx, s);
        } else sv[i] = -1e30f;
    }
    mx = fmaxf(mx, __shfl_xor(mx, 8)); mx = fmaxf(mx, __shfl_xor(mx, 16)); mx = fmaxf(mx, __shfl_xor(mx, 32));
    float sum = 0.f;
    #pragma unroll
    for (int i = 0; i < NE; i++) { sv[i] = __expf(sv[i] - mx); sum += sv[i]; }
    sum += __shfl_xor(sum, 8); sum += __shfl_xor(sum, 16); sum += __shfl_xor(sum, 32);
    float inv = 1.f / sum;
    #pragma unroll
    for (int i = 0; i < NE; i++) {
        int e = qc + i * 8;
        if (e < KK) {
            int ey = e / KS, ex = e - ey * KS;
            _Float16 wv16 = (_Float16)(sv[i] * inv);
            if (inplace) ((_Float16*)dots_row)[(lyL + ey) * 14 + lxL + ex] = wv16;
            else out_row[e] = wv16;
        }
    }
}

__global__ __launch_bounds__(256) void natten_fused(
    const __hip_bfloat16* __restrict__ qB, const unsigned short* __restrict__ sup2B,
    const unsigned short* __restrict__ vwF,
    const float* __restrict__ vb0, const float* __restrict__ vb1, const float* __restrict__ vb2,
    const float* __restrict__ rpb0, const float* __restrict__ rpb1, const float* __restrict__ rpb2,
    __hip_bfloat16* __restrict__ fused)
{
    __shared__ __align__(16) unsigned short khalo[140 * 72];  // 20160 B; reused as sproj[3][32][72]
    __shared__ __align__(16) unsigned short qlds[32 * 72];    // 4608 B
    __shared__ _Float16 dotsF[32][148];                       // 9472 B
    __shared__ _Float16 a3[32][12];                           // 768 B
    __shared__ _Float16 a5[32][28];                           // 1792 B
    __shared__ _Float16 rlds[276];                            // 552 B

    int t = threadIdx.x;
    int bb = blockIdx.y;
    int tx0 = (blockIdx.x % 12) * 8, ty0 = (blockIdx.x / 12) * 4;
    const unsigned short* kbB = sup2B + (size_t)bb * HW * 64;

    for (int e = t; e < 275; e += 256) {
        float v = (e < 169) ? rpb2[e] : ((e < 250) ? rpb1[e - 169] : rpb0[e - 250]);
        rlds[e] = (_Float16)v;
    }

    // stage 10x14 px k-halo (bf16 already): 140 px x 8 segs short8 = 1120 tasks
    #pragma unroll
    for (int it = 0; it < 5; it++) {
        int e = it * 256 + t;
        if (e < 1120) {
            int seg = e & 7, pos = e >> 3;
            int py = pos / 14, pxx = pos - py * 14;
            int gy = min(max(ty0 - 3 + py, 0), 95);
            int gx = min(max(tx0 - 3 + pxx, 0), 95);
            short8 v = *(const short8*)(kbB + (((size_t)gy * 96 + gx) << 6) + seg * 8);
            *(short8*)&khalo[pos * 72 + seg * 8] = v;
        }
    }
    if (t < 256) {
        int px = t >> 3, seg = t & 7;
        short8 v = *(const short8*)((const unsigned short*)qB +
            ((size_t)(bb * HW + (ty0 + (px >> 3)) * 96 + tx0 + (px & 7)) << 6) + seg * 8);
        *(short8*)&qlds[px * 72 + seg * 8] = v;
    }
    __syncthreads();

    int lane = t & 63, wv = t >> 6;
    int lm = lane & 15, quad = lane >> 4;

    // MFMA QK dots: wave wv does n-tiles wv, wv+4, wv+8
    #pragma unroll
    for (int ni = 0; ni < 3; ni++) {
        int nt = wv + ni * 4;
        if (nt <= 8) {
            int hp = nt * 16 + lm;
            int hpr = min(hp, 139);
            f32x4 acc0 = {0.f, 0.f, 0.f, 0.f}, acc1 = {0.f, 0.f, 0.f, 0.f};
            #pragma unroll
            for (int kt = 0; kt < 2; kt++) {
                short8 bfrag = *(const short8*)&khalo[hpr * 72 + kt * 32 + quad * 8];
                short8 a0 = *(const short8*)&qlds[lm * 72 + kt * 32 + quad * 8];
                short8 a1 = *(const short8*)&qlds[(16 + lm) * 72 + kt * 32 + quad * 8];
                acc0 = __builtin_amdgcn_mfma_f32_16x16x32_bf16(a0, bfrag, acc0, 0, 0, 0);
                acc1 = __builtin_amdgcn_mfma_f32_16x16x32_bf16(a1, bfrag, acc1, 0, 0, 0);
            }
            if (hp < 140) {
                #pragma unroll
                for (int r = 0; r < 4; r++) {
                    dotsF[quad * 4 + r][hp]      = (_Float16)acc0[r];
                    dotsF[16 + quad * 4 + r][hp] = (_Float16)acc1[r];
                }
            }
        }
    }
    __syncthreads();

    int pxl = wv * 8 + (lane & 7);
    int qc = lane >> 3;
    int pty = pxl >> 3, ptx = pxl & 7;
    int y = ty0 + pty, x = tx0 + ptx;

    int ni7 = min(max(y - 3, 0), 89), nj7 = min(max(x - 3, 0), 89);
    int ly = ni7 - (ty0 - 3), lx = nj7 - (tx0 - 3);

    level_softmax<3>(qc, y, x, ty0, tx0, rlds + 250, &dotsF[pxl][0], &a3[pxl][0], false);
    level_softmax<5>(qc, y, x, ty0, tx0, rlds + 169, &dotsF[pxl][0], &a5[pxl][0], false);
    level_softmax<7>(qc, y, x, ty0, tx0, rlds,       &dotsF[pxl][0], nullptr,     true);

    int ni5 = min(max(y - 2, 0), 91), nj5 = min(max(x - 2, 0), 91);
    int ni3 = min(max(y - 1, 0), 93), nj3 = min(max(x - 1, 0), 93);
    int di5 = ni5 - ni7, dj5 = nj5 - nj7, di3 = ni3 - ni7, dj3 = nj3 - nj7;

    float s2[3][8];
    #pragma unroll
    for (int l = 0; l < 3; l++)
        #pragma unroll
        for (int j = 0; j < 8; j++) s2[l][j] = 0.f;

    #pragma unroll 1
    for (int oy = 0; oy < 7; oy++) {
        #pragma unroll
        for (int ox = 0; ox < 7; ox++) {
            const unsigned short* kp = &khalo[((ly + oy) * 14 + lx + ox) * 72 + qc * 8];
            uint4 ka = *(const uint4*)kp;
            float kv[8] = {bfl(ka.x), bfh(ka.x), bfl(ka.y), bfh(ka.y),
                           bfl(ka.z), bfh(ka.z), bfl(ka.w), bfh(ka.w)};
            float w7 = (float)dotsF[pxl][(ly + oy) * 14 + lx + ox];
            #pragma unroll
            for (int j = 0; j < 8; j++) s2[2][j] += w7 * kv[j];
            int e5y = oy - di5, e5x = ox - dj5;
            if ((unsigned)e5y < 5u && (unsigned)e5x < 5u) {
                float w5 = (float)a5[pxl][e5y * 5 + e5x];
                #pragma unroll
                for (int j = 0; j < 8; j++) s2[1][j] += w5 * kv[j];
            }
            int e3y = oy - di3, e3x = ox - dj3;
            if ((unsigned)e3y < 3u && (unsigned)e3x < 3u) {
                float w3 = (float)a3[pxl][e3y * 3 + e3x];
                #pragma unroll
                for (int j = 0; j < 8; j++) s2[0][j] += w3 * kv[j];
            }
        }
    }
    __syncthreads();   // khalo reads done -> reuse as sproj

    unsigned short* sproj = khalo;
    #pragma unroll
    for (int l = 0; l < 3; l++) {
        unsigned int pk[4];
        #pragma unroll
        for (int j = 0; j < 4; j++)
            pk[j] = (unsigned int)f2bf(s2[l][2*j]) | ((unsigned int)f2bf(s2[l][2*j+1]) << 16);
        uint4 sv = {pk[0], pk[1], pk[2], pk[3]};
        *(uint4*)&sproj[(l * 32 + pxl) * 72 + qc * 8] = sv;
    }
    __syncthreads();

    if (wv < 3) {
        int l = wv;
        const float* vbl = (l == 0) ? vb0 : ((l == 1) ? vb1 : vb2);
        #pragma unroll
        for (int mt = 0; mt < 2; mt++) {
            f32x4 acc[4];
            #pragma unroll
            for (int nt = 0; nt < 4; nt++) acc[nt] = (f32x4){0.f, 0.f, 0.f, 0.f};
            #pragma unroll
            for (int kf = 0; kf < 2; kf++) {
                short8 a = *(const short8*)&sproj[(l * 32 + mt * 16 + lm) * 72 + kf * 32 + quad * 8];
                #pragma unroll
                for (int nt = 0; nt < 4; nt++) {
                    short8 bfr = *(const short8*)&vwF[(((l * 4 + nt) * 2 + kf) * 64 + lane) * 8];
                    acc[nt] = __builtin_amdgcn_mfma_f32_16x16x32_bf16(a, bfr, acc[nt], 0, 0, 0);
                }
            }
            #pragma unroll
            for (int nt = 0; nt < 4; nt++)
                #pragma unroll
                for (int r = 0; r < 4; r++) {
                    int p = mt * 16 + quad * 4 + r;
                    int co = nt * 16 + lm;
                    int py = p >> 3, pxx = p & 7;
                    size_t off = ((size_t)(bb * HW + (ty0 + py) * 96 + tx0 + pxx) << 8) + (l + 1) * 64 + co;
                    fused[off] = __hip_bfloat16(acc[nt][r] + vbl[co]);
                }
        }
    }
}

// ---------- 3x3 fusion conv (256->64): 16x8 px tile, 2 m-tiles/wave ----------
__global__ __launch_bounds__(256) void fusion_mfma(
    const __hip_bfloat16* __restrict__ fB, const unsigned short* __restrict__ fwF,
    const float* __restrict__ fb, float* __restrict__ out)
{
    __shared__ __align__(16) unsigned char smem[33408];
    unsigned short* ah = (unsigned short*)smem;          // [180 px][72]
    float* lds_out = (float*)smem;                       // [64 co][130]
    int t = threadIdx.x;
    int wv = t >> 6, lane = t & 63, lm = lane & 15, quad = lane >> 4;
    int X0 = blockIdx.x * 16, Y0 = blockIdx.y * 8, b = blockIdx.z;
    const unsigned short* fBu = (const unsigned short*)fB;

    f32x4 acc[2][4] = {};

    for (int chunk = 0; chunk < 4; chunk++) {
        __syncthreads();
        #pragma unroll
        for (int ee = 0; ee < 6; ee++) {
            int e = ee * 256 + t;
            if (e < 1440) {
                int seg = e & 7, hp = e >> 3;
                int hy = hp / 18, hx = hp - hy * 18;
                int gy = Y0 - 1 + hy, gx = X0 - 1 + hx;
                bool ok = (gy >= 0) & (gy < 96) & (gx >= 0) & (gx < 96);
                short8 v = {};
                if (ok) v = *(const short8*)(fBu + (((size_t)(b * HW + gy * 96 + gx)) << 8) + chunk * 64 + seg * 8);
                *(short8*)&ah[hp * 72 + seg * 8] = v;
            }
        }
        __syncthreads();
        #pragma unroll
        for (int ky = 0; ky < 3; ky++) {
            #pragma unroll
            for (int kx = 0; kx < 3; kx++) {
                #pragma unroll
                for (int kf = 0; kf < 2; kf++) {
                    int kc = (ky * 3 + kx) * 8 + chunk * 2 + kf;
                    const unsigned short* bp = fwF + ((size_t)(kc * 4) * 64 + lane) * 8;
                    short8 b0 = *(const short8*)(bp);
                    short8 b1 = *(const short8*)(bp + 512);
                    short8 b2 = *(const short8*)(bp + 1024);
                    short8 b3 = *(const short8*)(bp + 1536);
                    #pragma unroll
                    for (int mt = 0; mt < 2; mt++) {
                        int R = 2 * wv + mt;
                        short8 a = *(const short8*)&ah[((R + ky) * 18 + lm + kx) * 72 + kf * 32 + quad * 8];
                        acc[mt][0] = __builtin_amdgcn_mfma_f32_16x16x32_bf16(a, b0, acc[mt][0], 0, 0, 0);
                        acc[mt][1] = __builtin_amdgcn_mfma_f32_16x16x32_bf16(a, b1, acc[mt][1], 0, 0, 0);
                        acc[mt][2] = __builtin_amdgcn_mfma_f32_16x16x32_bf16(a, b2, acc[mt][2], 0, 0, 0);
                        acc[mt][3] = __builtin_amdgcn_mfma_f32_16x16x32_bf16(a, b3, acc[mt][3], 0, 0, 0);
                    }
                }
            }
        }
    }

    __syncthreads();
    #pragma unroll
    for (int mt = 0; mt < 2; mt++)
        #pragma unroll
        for (int nt = 0; nt < 4; nt++)
            #pragma unroll
            for (int r = 0; r < 4; r++) {
                int p = (2 * wv + mt) * 16 + quad * 4 + r;
                int co = nt * 16 + lm;
                lds_out[co * 130 + p] = acc[mt][nt][r];
            }
    __syncthreads();

    int p2 = t & 127, py = p2 >> 4, px2 = p2 & 15;
    float* ob = out + ((size_t)(b * 64) * 96 + Y0 + py) * 96 + X0 + px2;
    #pragma unroll 4
    for (int i = 0; i < 32; i++) {
        int co = (t >> 7) * 32 + i;
        float v = lds_out[co * 130 + p2] + fb[co];
        ob[(size_t)co * HW] = v > 0.f ? v : 0.f;
    }
}

extern "C" void kernel_launch(void* const* d_in, const int* in_sizes, int n_in,
                              void* d_out, int out_size, void* d_ws, size_t ws_size,
                              hipStream_t stream) {
    const float* sup = (const float*)d_in[0];
    const float* key = (const float*)d_in[1];
    const float* smw = (const float*)d_in[2];
    const float* smb = (const float*)d_in[3];
    const float* rw  = (const float*)d_in[4];
    const float* rb  = (const float*)d_in[5];
    const float *vw[3], *vb[3], *rpb[3];
    if (in_sizes[8] == 25) {
        for (int l = 0; l < 3; l++) {
            vw[l]  = (const float*)d_in[6 + 3 * l];
            vb[l]  = (const float*)d_in[7 + 3 * l];
            rpb[l] = (const float*)d_in[8 + 3 * l];
        }
    } else {
        for (int l = 0; l < 3; l++) {
            vw[l]  = (const float*)d_in[6 + 2 * l];
            vb[l]  = (const float*)d_in[7 + 2 * l];
            rpb[l] = (const float*)d_in[12 + l];
        }
    }
    const float* fw = (const float*)d_in[15];
    const float* fb = (const float*)d_in[16];
    float* out = (float*)d_out;

    float* wsf    = (float*)d_ws;
    float* smooth = wsf;                                       // 2359296 f
    unsigned short* sup2B = (unsigned short*)(wsf + 2359296);  // 2359296 bf16 (NHWC)
    __hip_bfloat16* qBuf = (__hip_bfloat16*)(wsf + 4718592);   // 2359296 bf16
    unsigned short* rwF = (unsigned short*)(wsf + 7077888);    // 8192 bf16
    unsigned short* vwF = (unsigned short*)(wsf + 7086080);    // 12288 bf16
    __hip_bfloat16* fusedB = (__hip_bfloat16*)(wsf + 7092224);  // 9437184 bf16
    unsigned short* fwF    = (unsigned short*)(wsf + 11810816); // 147456 bf16

    prep_weights<<<dim3(656), dim3(256), 0, stream>>>(rw, vw[0], vw[1], vw[2], fw, rwF, vwF, fwF);
    pack_kernel<<<dim3(3, 2, 384), dim3(32, 8), 0, stream>>>(key, sup, qBuf, fusedB);
    shift_smooth<<<dim3(576), dim3(256), 0, stream>>>(sup, smw, smb, smooth);
    reduce_mfma<<<dim3(576), dim3(256), 0, stream>>>(fusedB, smooth, rwF, rb, sup2B);
    natten_fused<<<dim3(288, 4), dim3(256), 0, stream>>>(qBuf, sup2B, vwF,
        vb[0], vb[1], vb[2], rpb[0], rpb[1], rpb[2], fusedB);
    fusion_mfma<<<dim3(6, 12, 4), dim3(256), 0, stream>>>(fusedB, fwF, fb, out);
}

// Round 17
// 184.751 us; speedup vs baseline: 1.5057x; 1.0196x over previous
//
#include <hip/hip_runtime.h>
#include <hip/hip_bf16.h>

#define HW 9216
#define NPX 36864

typedef __attribute__((ext_vector_type(8))) short short8;
typedef __attribute__((ext_vector_type(4))) float f32x4;

static __device__ __forceinline__ unsigned short f2bf(float x) {
    union { __hip_bfloat16 h; unsigned short u; } c; c.h = __float2bfloat16(x); return c.u;
}
static __device__ __forceinline__ float bfl(unsigned int u){ return __uint_as_float(u << 16); }
static __device__ __forceinline__ float bfh(unsigned int u){ return __uint_as_float(u & 0xffff0000u); }

// ---------- pack (key->qB, sup->fused[0:64]) + fused weight pre-transposes ----------
__global__ void pack_kernel(const float* __restrict__ key, const float* __restrict__ sup,
                            __hip_bfloat16* __restrict__ qB, __hip_bfloat16* __restrict__ fused,
                            const float* __restrict__ rw, const float* __restrict__ vw0,
                            const float* __restrict__ vw1, const float* __restrict__ vw2,
                            const float* __restrict__ fw,
                            unsigned short* __restrict__ rwF, unsigned short* __restrict__ vwF,
                            unsigned short* __restrict__ fwF)
{
    __shared__ float lk[32][33], ls[32][33];
    int tx = threadIdx.x, ty = threadIdx.y;
    int t = ty * 32 + tx;

    // weight transposes folded in: first 656 flat blocks handle 167936 elements
    int bid = (blockIdx.z * gridDim.y + blockIdx.y) * gridDim.x + blockIdx.x;
    int idx = bid * 256 + t;
    if (idx < 8192) {                       // reduce_w (64,128) -> B-frag rwF[nt][kf][lane][j]
        int e = idx;
        int j = e & 7, lane = (e >> 3) & 63, kf = (e >> 9) & 3, nt = e >> 11;
        int co = nt * 16 + (lane & 15);
        int k = kf * 32 + (lane >> 4) * 8 + j;
        rwF[e] = f2bf(rw[co * 128 + k]);
    } else if (idx < 20480) {               // v_w -> B-frag vwF[lvl][nt][kf][lane][j]
        int e = idx - 8192;
        int j = e & 7, lane = (e >> 3) & 63, kf = (e >> 9) & 1, nt = (e >> 10) & 3, lvl = e >> 12;
        int co = nt * 16 + (lane & 15);
        int k = kf * 32 + (lane >> 4) * 8 + j;
        const float* vw = (lvl == 0) ? vw0 : ((lvl == 1) ? vw1 : vw2);
        vwF[e] = f2bf(vw[co * 64 + k]);
    } else if (idx < 167936) {              // fusion_w -> B-frag fwF[kc][nt][lane][j]
        int e = idx - 20480;
        int j = e & 7, lane = (e >> 3) & 63, nt = (e >> 9) & 3, kc = e >> 11;
        int co = nt * 16 + (lane & 15);
        int k = kc * 32 + ((lane >> 4) << 3) + j;
        int tap = k >> 8, ci = k & 255;
        fwF[e] = f2bf(fw[co * 2304 + ci * 9 + tap]);
    }

    int x0 = blockIdx.x * 32, c0 = blockIdx.y * 32;
    int z = blockIdx.z; int b = z / 96, y = z - b * 96;
    #pragma unroll
    for (int i = 0; i < 32; i += 8) {
        int c = c0 + ty + i;
        lk[ty + i][tx] = key[((b * 64 + c) * 96 + y) * 96 + x0 + tx];
        ls[ty + i][tx] = sup[((b * 64 + c) * 96 + y) * 96 + x0 + tx];
    }
    __syncthreads();
    #pragma unroll
    for (int i = 0; i < 32; i += 8) {
        int px = (b * 96 + y) * 96 + x0 + ty + i;
        qB[px * 64 + c0 + tx]     = __hip_bfloat16(lk[tx][ty + i]);
        fused[px * 256 + c0 + tx] = __hip_bfloat16(ls[tx][ty + i]);
    }
}

// ---------- shifted grouped 3x3 conv, LDS-staged, wave-uniform out-channel ----------
__global__ __launch_bounds__(256) void shift_smooth(const float* __restrict__ sup,
    const float* __restrict__ w, const float* __restrict__ bias, float* __restrict__ smooth)
{
    __shared__ __align__(16) float tile[8][34][36];
    int bid = blockIdx.x;                 // 576 = 4b * 8grp * 9sj * 2half
    int half = bid & 1;
    int sj   = (bid >> 1) % 9;
    int grp  = (bid / 18) & 7;
    int b    = bid / 144;
    int sby = sj / 3, sbx = sj % 3;
    int Y0 = sby * 32, X0 = sbx * 32;
    int sh = 3 * ((grp >= 5) - (grp < 3));
    int mm = (grp < 3) ? grp : ((grp < 5) ? ((grp == 3) ? 0 : 2) : (grp - 5));
    int sw = 3 * mm - 3;
    int t = threadIdx.x;

    const float* supg = sup + (size_t)(b * 64 + grp * 8) * HW;
    #pragma unroll
    for (int pp = 0; pp < 5; pp++) {
        int pos = pp * 256 + t;
        if (pos < 1156) {
            int r = pos / 34, u = pos - r * 34;
            int yy = Y0 - 1 + r, xx = X0 - 1 + u;
            int ys = yy - sh, xs = xx - sw;
            bool ok = (yy >= 0) & (yy < 96) & (xx >= 0) & (xx < 96) &
                      (ys >= 0) & (ys < 96) & (xs >= 0) & (xs < 96);
            int addr = ok ? (ys * 96 + xs) : 0;
            #pragma unroll
            for (int ic = 0; ic < 8; ic++) {
                float v = supg[(size_t)ic * HW + addr];
                tile[ic][r][u] = ok ? v : 0.f;
            }
        }
    }
    __syncthreads();

    int c = __builtin_amdgcn_readfirstlane(grp * 8 + half * 4 + (t >> 6));
    int lane = t & 63;
    int ty4 = lane >> 3, tx4 = lane & 7;
    int py0 = ty4 * 4, x0r = tx4 * 4;

    float bz = bias[c];
    float acc[4][4];
    #pragma unroll
    for (int jr = 0; jr < 4; jr++)
        #pragma unroll
        for (int j = 0; j < 4; j++) acc[jr][j] = bz;

    const float* wp = w + c * 72;
    for (int ic = 0; ic < 8; ic++) {
        float wr[9];
        #pragma unroll
        for (int q = 0; q < 9; q++) wr[q] = wp[ic * 9 + q];
        #pragma unroll
        for (int rr = 0; rr < 6; rr++) {
            float4 fa = *(const float4*)&tile[ic][py0 + rr][x0r];
            float4 fb4 = *(const float4*)&tile[ic][py0 + rr][x0r + 4];
            float f[6] = {fa.x, fa.y, fa.z, fa.w, fb4.x, fb4.y};
            #pragma unroll
            for (int ky = 0; ky < 3; ky++) {
                int jr = rr - ky;
                if (jr >= 0 && jr < 4) {
                    #pragma unroll
                    for (int j = 0; j < 4; j++)
                        acc[jr][j] += wr[ky*3]*f[j] + wr[ky*3+1]*f[j+1] + wr[ky*3+2]*f[j+2];
                }
            }
        }
    }

    float* op = smooth + ((size_t)(b * 64 + c) * 96 + Y0 + py0) * 96 + X0 + x0r;
    #pragma unroll
    for (int jr = 0; jr < 4; jr++) {
        float4 st = {acc[jr][0], acc[jr][1], acc[jr][2], acc[jr][3]};
        *(float4*)(op + (size_t)jr * 96) = st;
    }
}

// ---------- 1x1 reduce conv (128->64) as bf16 MFMA; sup2 out bf16 NHWC ----------
__global__ __launch_bounds__(256) void reduce_mfma(
    const __hip_bfloat16* __restrict__ fB, const float* __restrict__ smooth,
    const unsigned short* __restrict__ rwF, const float* __restrict__ rb,
    unsigned short* __restrict__ sup2B)
{
    __shared__ __align__(16) unsigned short A[64 * 136];
    int t = threadIdx.x;
    int gpx0 = blockIdx.x * 64;
    int b = gpx0 / HW, rem0 = gpx0 - b * HW;
    const unsigned short* fBu = (const unsigned short*)fB;

    #pragma unroll
    for (int it = 0; it < 2; it++) {
        int e = it * 256 + t;
        int px = e >> 3, seg = e & 7;
        short8 v = *(const short8*)(fBu + ((size_t)(gpx0 + px) << 8) + seg * 8);
        *(short8*)&A[px * 136 + seg * 8] = v;
    }
    #pragma unroll
    for (int it = 0; it < 16; it++) {
        int e = it * 256 + t;
        int px = e & 63, ci = e >> 6;
        float v = smooth[(size_t)(b * 64 + ci) * HW + rem0 + px];
        A[px * 136 + 64 + ci] = f2bf(v);
    }
    __syncthreads();

    int lane = t & 63, wv = t >> 6;
    int lm = lane & 15, quad = lane >> 4;
    f32x4 acc[4] = {};
    #pragma unroll
    for (int kf = 0; kf < 4; kf++) {
        short8 a = *(const short8*)&A[(wv * 16 + lm) * 136 + kf * 32 + quad * 8];
        #pragma unroll
        for (int nt = 0; nt < 4; nt++) {
            short8 bfr = *(const short8*)&rwF[((nt * 4 + kf) * 64 + lane) * 8];
            acc[nt] = __builtin_amdgcn_mfma_f32_16x16x32_bf16(a, bfr, acc[nt], 0, 0, 0);
        }
    }
    #pragma unroll
    for (int nt = 0; nt < 4; nt++)
        #pragma unroll
        for (int r = 0; r < 4; r++) {
            int px = wv * 16 + quad * 4 + r;
            int co = nt * 16 + lm;
            sup2B[(size_t)(gpx0 + px) * 64 + co] = f2bf(acc[nt][r] + rb[co]);
        }
}

// ---------- fused 3-level neighborhood attention (MFMA QK dots) ----------
template<int KS>
__device__ __forceinline__ void level_softmax(int qc, int y, int x, int ty0, int tx0,
        const _Float16* rpbl, const _Float16* dots_row, _Float16* out_row, bool inplace)
{
    constexpr int R = KS / 2, KK = KS * KS, NB = 2 * KS - 1;
    constexpr int NE = (KK + 7) / 8;
    int ni = min(max(y - R, 0), 96 - KS), nj = min(max(x - R, 0), 96 - KS);
    int lyL = ni - (ty0 - 3), lxL = nj - (tx0 - 3);
    int br = KS - 1 + ni - y, bc = KS - 1 + nj - x;
    float sv[NE];
    float mx = -1e30f;
    #pragma unroll
    for (int i = 0; i < NE; i++) {
        int e = qc + i * 8;
        if (e < KK) {
            int ey = e / KS, ex = e - ey * KS;
            float s = (float)dots_row[(lyL + ey) * 14 + lxL + ex] + (float)rpbl[(br + ey) * NB + bc + ex];
            sv[i] = s; mx = fmaxf(mx, s);
        } else sv[i] = -1e30f;
    }
    mx = fmaxf(mx, __shfl_xor(mx, 8)); mx = fmaxf(mx, __shfl_xor(mx, 16)); mx = fmaxf(mx, __shfl_xor(mx, 32));
    float sum = 0.f;
    #pragma unroll
    for (int i = 0; i < NE; i++) { sv[i] = __expf(sv[i] - mx); sum += sv[i]; }
    sum += __shfl_xor(sum, 8); sum += __shfl_xor(sum, 16); sum += __shfl_xor(sum, 32);
    float inv = 1.f / sum;
    #pragma unroll
    for (int i = 0; i < NE; i++) {
        int e = qc + i * 8;
        if (e < KK) {
            int ey = e / KS, ex = e - ey * KS;
            _Float16 wv16 = (_Float16)(sv[i] * inv);
            if (inplace) ((_Float16*)dots_row)[(lyL + ey) * 14 + lxL + ex] = wv16;
            else out_row[e] = wv16;
        }
    }
}

__global__ __launch_bounds__(256) void natten_fused(
    const __hip_bfloat16* __restrict__ qB, const unsigned short* __restrict__ sup2B,
    const unsigned short* __restrict__ vwF,
    const float* __restrict__ vb0, const float* __restrict__ vb1, const float* __restrict__ vb2,
    const float* __restrict__ rpb0, const float* __restrict__ rpb1, const float* __restrict__ rpb2,
    __hip_bfloat16* __restrict__ fused)
{
    __shared__ __align__(16) unsigned short khalo[140 * 72];
    __shared__ __align__(16) unsigned short qlds[32 * 72];
    __shared__ _Float16 dotsF[32][148];
    __shared__ _Float16 a3[32][12];
    __shared__ _Float16 a5[32][28];
    __shared__ _Float16 rlds[276];

    int t = threadIdx.x;
    int bb = blockIdx.y;
    int tx0 = (blockIdx.x % 12) * 8, ty0 = (blockIdx.x / 12) * 4;
    const unsigned short* kbB = sup2B + (size_t)bb * HW * 64;

    for (int e = t; e < 275; e += 256) {
        float v = (e < 169) ? rpb2[e] : ((e < 250) ? rpb1[e - 169] : rpb0[e - 250]);
        rlds[e] = (_Float16)v;
    }

    #pragma unroll
    for (int it = 0; it < 5; it++) {
        int e = it * 256 + t;
        if (e < 1120) {
            int seg = e & 7, pos = e >> 3;
            int py = pos / 14, pxx = pos - py * 14;
            int gy = min(max(ty0 - 3 + py, 0), 95);
            int gx = min(max(tx0 - 3 + pxx, 0), 95);
            short8 v = *(const short8*)(kbB + (((size_t)gy * 96 + gx) << 6) + seg * 8);
            *(short8*)&khalo[pos * 72 + seg * 8] = v;
        }
    }
    if (t < 256) {
        int px = t >> 3, seg = t & 7;
        short8 v = *(const short8*)((const unsigned short*)qB +
            ((size_t)(bb * HW + (ty0 + (px >> 3)) * 96 + tx0 + (px & 7)) << 6) + seg * 8);
        *(short8*)&qlds[px * 72 + seg * 8] = v;
    }
    __syncthreads();

    int lane = t & 63, wv = t >> 6;
    int lm = lane & 15, quad = lane >> 4;

    #pragma unroll
    for (int ni = 0; ni < 3; ni++) {
        int nt = wv + ni * 4;
        if (nt <= 8) {
            int hp = nt * 16 + lm;
            int hpr = min(hp, 139);
            f32x4 acc0 = {0.f, 0.f, 0.f, 0.f}, acc1 = {0.f, 0.f, 0.f, 0.f};
            #pragma unroll
            for (int kt = 0; kt < 2; kt++) {
                short8 bfrag = *(const short8*)&khalo[hpr * 72 + kt * 32 + quad * 8];
                short8 a0 = *(const short8*)&qlds[lm * 72 + kt * 32 + quad * 8];
                short8 a1 = *(const short8*)&qlds[(16 + lm) * 72 + kt * 32 + quad * 8];
                acc0 = __builtin_amdgcn_mfma_f32_16x16x32_bf16(a0, bfrag, acc0, 0, 0, 0);
                acc1 = __builtin_amdgcn_mfma_f32_16x16x32_bf16(a1, bfrag, acc1, 0, 0, 0);
            }
            if (hp < 140) {
                #pragma unroll
                for (int r = 0; r < 4; r++) {
                    dotsF[quad * 4 + r][hp]      = (_Float16)acc0[r];
                    dotsF[16 + quad * 4 + r][hp] = (_Float16)acc1[r];
                }
            }
        }
    }
    __syncthreads();

    int pxl = wv * 8 + (lane & 7);
    int qc = lane >> 3;
    int pty = pxl >> 3, ptx = pxl & 7;
    int y = ty0 + pty, x = tx0 + ptx;

    int ni7 = min(max(y - 3, 0), 89), nj7 = min(max(x - 3, 0), 89);
    int ly = ni7 - (ty0 - 3), lx = nj7 - (tx0 - 3);

    level_softmax<3>(qc, y, x, ty0, tx0, rlds + 250, &dotsF[pxl][0], &a3[pxl][0], false);
    level_softmax<5>(qc, y, x, ty0, tx0, rlds + 169, &dotsF[pxl][0], &a5[pxl][0], false);
    level_softmax<7>(qc, y, x, ty0, tx0, rlds,       &dotsF[pxl][0], nullptr,     true);

    int ni5 = min(max(y - 2, 0), 91), nj5 = min(max(x - 2, 0), 91);
    int ni3 = min(max(y - 1, 0), 93), nj3 = min(max(x - 1, 0), 93);
    int di5 = ni5 - ni7, dj5 = nj5 - nj7, di3 = ni3 - ni7, dj3 = nj3 - nj7;

    float s2[3][8];
    #pragma unroll
    for (int l = 0; l < 3; l++)
        #pragma unroll
        for (int j = 0; j < 8; j++) s2[l][j] = 0.f;

    #pragma unroll 1
    for (int oy = 0; oy < 7; oy++) {
        #pragma unroll
        for (int ox = 0; ox < 7; ox++) {
            const unsigned short* kp = &khalo[((ly + oy) * 14 + lx + ox) * 72 + qc * 8];
            uint4 ka = *(const uint4*)kp;
            float kv[8] = {bfl(ka.x), bfh(ka.x), bfl(ka.y), bfh(ka.y),
                           bfl(ka.z), bfh(ka.z), bfl(ka.w), bfh(ka.w)};
            float w7 = (float)dotsF[pxl][(ly + oy) * 14 + lx + ox];
            #pragma unroll
            for (int j = 0; j < 8; j++) s2[2][j] += w7 * kv[j];
            int e5y = oy - di5, e5x = ox - dj5;
            if ((unsigned)e5y < 5u && (unsigned)e5x < 5u) {
                float w5 = (float)a5[pxl][e5y * 5 + e5x];
                #pragma unroll
                for (int j = 0; j < 8; j++) s2[1][j] += w5 * kv[j];
            }
            int e3y = oy - di3, e3x = ox - dj3;
            if ((unsigned)e3y < 3u && (unsigned)e3x < 3u) {
                float w3 = (float)a3[pxl][e3y * 3 + e3x];
                #pragma unroll
                for (int j = 0; j < 8; j++) s2[0][j] += w3 * kv[j];
            }
        }
    }
    __syncthreads();

    unsigned short* sproj = khalo;
    #pragma unroll
    for (int l = 0; l < 3; l++) {
        unsigned int pk[4];
        #pragma unroll
        for (int j = 0; j < 4; j++)
            pk[j] = (unsigned int)f2bf(s2[l][2*j]) | ((unsigned int)f2bf(s2[l][2*j+1]) << 16);
        uint4 sv = {pk[0], pk[1], pk[2], pk[3]};
        *(uint4*)&sproj[(l * 32 + pxl) * 72 + qc * 8] = sv;
    }
    __syncthreads();

    if (wv < 3) {
        int l = wv;
        const float* vbl = (l == 0) ? vb0 : ((l == 1) ? vb1 : vb2);
        #pragma unroll
        for (int mt = 0; mt < 2; mt++) {
            f32x4 acc[4];
            #pragma unroll
            for (int nt = 0; nt < 4; nt++) acc[nt] = (f32x4){0.f, 0.f, 0.f, 0.f};
            #pragma unroll
            for (int kf = 0; kf < 2; kf++) {
                short8 a = *(const short8*)&sproj[(l * 32 + mt * 16 + lm) * 72 + kf * 32 + quad * 8];
                #pragma unroll
                for (int nt = 0; nt < 4; nt++) {
                    short8 bfr = *(const short8*)&vwF[(((l * 4 + nt) * 2 + kf) * 64 + lane) * 8];
                    acc[nt] = __builtin_amdgcn_mfma_f32_16x16x32_bf16(a, bfr, acc[nt], 0, 0, 0);
                }
            }
            #pragma unroll
            for (int nt = 0; nt < 4; nt++)
                #pragma unroll
                for (int r = 0; r < 4; r++) {
                    int p = mt * 16 + quad * 4 + r;
                    int co = nt * 16 + lm;
                    int py = p >> 3, pxx = p & 7;
                    size_t off = ((size_t)(bb * HW + (ty0 + py) * 96 + tx0 + pxx) << 8) + (l + 1) * 64 + co;
                    fused[off] = __hip_bfloat16(acc[nt][r] + vbl[co]);
                }
        }
    }
}

// ---------- 3x3 fusion conv (256->64): 16x4 tile, 128 thr, 2 m-tiles/wave ----------
__global__ __launch_bounds__(128) void fusion_mfma(
    const __hip_bfloat16* __restrict__ fB, const unsigned short* __restrict__ fwF,
    const float* __restrict__ fb, float* __restrict__ out)
{
    __shared__ __align__(16) unsigned char smem[16896];  // union: halo 15552 / epilogue 16896
    unsigned short* ah = (unsigned short*)smem;          // [108 px][72]  (18x6 halo)
    float* lds_out = (float*)smem;                       // [64 co][66]
    int t = threadIdx.x;
    int wv = t >> 6, lane = t & 63, lm = lane & 15, quad = lane >> 4;
    int X0 = blockIdx.x * 16, Y0 = blockIdx.y * 4, b = blockIdx.z;
    const unsigned short* fBu = (const unsigned short*)fB;

    f32x4 acc[2][4] = {};

    for (int chunk = 0; chunk < 4; chunk++) {
        __syncthreads();
        // stage 18x6 halo for this 64-ci chunk: 864 tasks over 128 thr
        #pragma unroll
        for (int ee = 0; ee < 7; ee++) {
            int e = ee * 128 + t;
            if (e < 864) {
                int seg = e & 7, hp = e >> 3;
                int hy = hp / 18, hx = hp - hy * 18;
                int gy = Y0 - 1 + hy, gx = X0 - 1 + hx;
                bool ok = (gy >= 0) & (gy < 96) & (gx >= 0) & (gx < 96);
                short8 v = {};
                if (ok) v = *(const short8*)(fBu + (((size_t)(b * HW + gy * 96 + gx)) << 8) + chunk * 64 + seg * 8);
                *(short8*)&ah[hp * 72 + seg * 8] = v;
            }
        }
        __syncthreads();
        #pragma unroll
        for (int ky = 0; ky < 3; ky++) {
            #pragma unroll
            for (int kx = 0; kx < 3; kx++) {
                #pragma unroll
                for (int kf = 0; kf < 2; kf++) {
                    int kc = (ky * 3 + kx) * 8 + chunk * 2 + kf;
                    const unsigned short* bp = fwF + ((size_t)(kc * 4) * 64 + lane) * 8;
                    short8 b0 = *(const short8*)(bp);
                    short8 b1 = *(const short8*)(bp + 512);
                    short8 b2 = *(const short8*)(bp + 1024);
                    short8 b3 = *(const short8*)(bp + 1536);
                    #pragma unroll
                    for (int mt = 0; mt < 2; mt++) {
                        int R = 2 * wv + mt;                 // row 0..3
                        short8 a = *(const short8*)&ah[((R + ky) * 18 + lm + kx) * 72 + kf * 32 + quad * 8];
                        acc[mt][0] = __builtin_amdgcn_mfma_f32_16x16x32_bf16(a, b0, acc[mt][0], 0, 0, 0);
                        acc[mt][1] = __builtin_amdgcn_mfma_f32_16x16x32_bf16(a, b1, acc[mt][1], 0, 0, 0);
                        acc[mt][2] = __builtin_amdgcn_mfma_f32_16x16x32_bf16(a, b2, acc[mt][2], 0, 0, 0);
                        acc[mt][3] = __builtin_amdgcn_mfma_f32_16x16x32_bf16(a, b3, acc[mt][3], 0, 0, 0);
                    }
                }
            }
        }
    }

    __syncthreads();   // ah reads done -> reuse as lds_out
    #pragma unroll
    for (int mt = 0; mt < 2; mt++)
        #pragma unroll
        for (int nt = 0; nt < 4; nt++)
            #pragma unroll
            for (int r = 0; r < 4; r++) {
                int p = (2 * wv + mt) * 16 + quad * 4 + r;   // row*16 + x
                int co = nt * 16 + lm;
                lds_out[co * 66 + p] = acc[mt][nt][r];
            }
    __syncthreads();

    int p2 = t & 63, py = p2 >> 4, px2 = p2 & 15;
    float* ob = out + ((size_t)(b * 64) * 96 + Y0 + py) * 96 + X0 + px2;
    #pragma unroll 4
    for (int i = 0; i < 32; i++) {
        int co = (t >> 6) * 32 + i;                           // 2 groups x 32 co
        float v = lds_out[co * 66 + p2] + fb[co];
        ob[(size_t)co * HW] = v > 0.f ? v : 0.f;
    }
}

extern "C" void kernel_launch(void* const* d_in, const int* in_sizes, int n_in,
                              void* d_out, int out_size, void* d_ws, size_t ws_size,
                              hipStream_t stream) {
    const float* sup = (const float*)d_in[0];
    const float* key = (const float*)d_in[1];
    const float* smw = (const float*)d_in[2];
    const float* smb = (const float*)d_in[3];
    const float* rw  = (const float*)d_in[4];
    const float* rb  = (const float*)d_in[5];
    const float *vw[3], *vb[3], *rpb[3];
    if (in_sizes[8] == 25) {
        for (int l = 0; l < 3; l++) {
            vw[l]  = (const float*)d_in[6 + 3 * l];
            vb[l]  = (const float*)d_in[7 + 3 * l];
            rpb[l] = (const float*)d_in[8 + 3 * l];
        }
    } else {
        for (int l = 0; l < 3; l++) {
            vw[l]  = (const float*)d_in[6 + 2 * l];
            vb[l]  = (const float*)d_in[7 + 2 * l];
            rpb[l] = (const float*)d_in[12 + l];
        }
    }
    const float* fw = (const float*)d_in[15];
    const float* fb = (const float*)d_in[16];
    float* out = (float*)d_out;

    float* wsf    = (float*)d_ws;
    float* smooth = wsf;                                       // 2359296 f
    unsigned short* sup2B = (unsigned short*)(wsf + 2359296);  // 2359296 bf16 (NHWC)
    __hip_bfloat16* qBuf = (__hip_bfloat16*)(wsf + 4718592);   // 2359296 bf16
    unsigned short* rwF = (unsigned short*)(wsf + 7077888);    // 8192 bf16
    unsigned short* vwF = (unsigned short*)(wsf + 7086080);    // 12288 bf16
    __hip_bfloat16* fusedB = (__hip_bfloat16*)(wsf + 7092224);  // 9437184 bf16
    unsigned short* fwF    = (unsigned short*)(wsf + 11810816); // 147456 bf16

    pack_kernel<<<dim3(3, 2, 384), dim3(32, 8), 0, stream>>>(key, sup, qBuf, fusedB,
        rw, vw[0], vw[1], vw[2], fw, rwF, vwF, fwF);
    shift_smooth<<<dim3(576), dim3(256), 0, stream>>>(sup, smw, smb, smooth);
    reduce_mfma<<<dim3(576), dim3(256), 0, stream>>>(fusedB, smooth, rwF, rb, sup2B);
    natten_fused<<<dim3(288, 4), dim3(256), 0, stream>>>(qBuf, sup2B, vwF,
        vb[0], vb[1], vb[2], rpb[0], rpb[1], rpb[2], fusedB);
    fusion_mfma<<<dim3(6, 24, 4), dim3(128), 0, stream>>>(fusedB, fwF, fb, out);
}

// Round 18
// 181.520 us; speedup vs baseline: 1.5325x; 1.0178x over previous
//
#include <hip/hip_runtime.h>
#include <hip/hip_bf16.h>

#define HW 9216
#define NPX 36864

typedef __attribute__((ext_vector_type(8))) short short8;
typedef __attribute__((ext_vector_type(4))) float f32x4;

static __device__ __forceinline__ unsigned short f2bf(float x) {
    union { __hip_bfloat16 h; unsigned short u; } c; c.h = __float2bfloat16(x); return c.u;
}
static __device__ __forceinline__ float bfl(unsigned int u){ return __uint_as_float(u << 16); }
static __device__ __forceinline__ float bfh(unsigned int u){ return __uint_as_float(u & 0xffff0000u); }

// ---------- pack (key->qB, sup->fused[0:64]) + fused weight pre-transposes ----------
__global__ void pack_kernel(const float* __restrict__ key, const float* __restrict__ sup,
                            __hip_bfloat16* __restrict__ qB, __hip_bfloat16* __restrict__ fused,
                            const float* __restrict__ rw, const float* __restrict__ vw0,
                            const float* __restrict__ vw1, const float* __restrict__ vw2,
                            const float* __restrict__ fw,
                            unsigned short* __restrict__ rwF, unsigned short* __restrict__ vwF,
                            unsigned short* __restrict__ fwF)
{
    __shared__ float lk[32][33], ls[32][33];
    int tx = threadIdx.x, ty = threadIdx.y;
    int t = ty * 32 + tx;

    int bid = (blockIdx.z * gridDim.y + blockIdx.y) * gridDim.x + blockIdx.x;
    int idx = bid * 256 + t;
    if (idx < 8192) {                       // reduce_w (64,128) -> B-frag rwF[nt][kf][lane][j]
        int e = idx;
        int j = e & 7, lane = (e >> 3) & 63, kf = (e >> 9) & 3, nt = e >> 11;
        int co = nt * 16 + (lane & 15);
        int k = kf * 32 + (lane >> 4) * 8 + j;
        rwF[e] = f2bf(rw[co * 128 + k]);
    } else if (idx < 20480) {               // v_w -> B-frag vwF[lvl][nt][kf][lane][j]
        int e = idx - 8192;
        int j = e & 7, lane = (e >> 3) & 63, kf = (e >> 9) & 1, nt = (e >> 10) & 3, lvl = e >> 12;
        int co = nt * 16 + (lane & 15);
        int k = kf * 32 + (lane >> 4) * 8 + j;
        const float* vw = (lvl == 0) ? vw0 : ((lvl == 1) ? vw1 : vw2);
        vwF[e] = f2bf(vw[co * 64 + k]);
    } else if (idx < 167936) {              // fusion_w -> B-frag fwF[kc][nt][lane][j]
        int e = idx - 20480;
        int j = e & 7, lane = (e >> 3) & 63, nt = (e >> 9) & 3, kc = e >> 11;
        int co = nt * 16 + (lane & 15);
        int k = kc * 32 + ((lane >> 4) << 3) + j;
        int tap = k >> 8, ci = k & 255;
        fwF[e] = f2bf(fw[co * 2304 + ci * 9 + tap]);
    }

    int x0 = blockIdx.x * 32, c0 = blockIdx.y * 32;
    int z = blockIdx.z; int b = z / 96, y = z - b * 96;
    #pragma unroll
    for (int i = 0; i < 32; i += 8) {
        int c = c0 + ty + i;
        lk[ty + i][tx] = key[((b * 64 + c) * 96 + y) * 96 + x0 + tx];
        ls[ty + i][tx] = sup[((b * 64 + c) * 96 + y) * 96 + x0 + tx];
    }
    __syncthreads();
    #pragma unroll
    for (int i = 0; i < 32; i += 8) {
        int px = (b * 96 + y) * 96 + x0 + ty + i;
        qB[px * 64 + c0 + tx]     = __hip_bfloat16(lk[tx][ty + i]);
        fused[px * 256 + c0 + tx] = __hip_bfloat16(ls[tx][ty + i]);
    }
}

// ---------- shifted grouped 3x3 conv: halo staged ONCE, 2 channels/wave, bf16 out ----------
__global__ __launch_bounds__(256) void shift_smooth(const float* __restrict__ sup,
    const float* __restrict__ w, const float* __restrict__ bias, unsigned short* __restrict__ smoothB)
{
    __shared__ __align__(16) float tile[8][34][36];
    int bid = blockIdx.x;                 // 288 = 4b * 8grp * 9sj
    int sj   = bid % 9;
    int grp  = (bid / 9) & 7;
    int b    = bid / 72;
    int sby = sj / 3, sbx = sj % 3;
    int Y0 = sby * 32, X0 = sbx * 32;
    int sh = 3 * ((grp >= 5) - (grp < 3));
    int mm = (grp < 3) ? grp : ((grp < 5) ? ((grp == 3) ? 0 : 2) : (grp - 5));
    int sw = 3 * mm - 3;
    int t = threadIdx.x;

    const float* supg = sup + (size_t)(b * 64 + grp * 8) * HW;
    #pragma unroll
    for (int pp = 0; pp < 5; pp++) {
        int pos = pp * 256 + t;
        if (pos < 1156) {
            int r = pos / 34, u = pos - r * 34;
            int yy = Y0 - 1 + r, xx = X0 - 1 + u;
            int ys = yy - sh, xs = xx - sw;
            bool ok = (yy >= 0) & (yy < 96) & (xx >= 0) & (xx < 96) &
                      (ys >= 0) & (ys < 96) & (xs >= 0) & (xs < 96);
            int addr = ok ? (ys * 96 + xs) : 0;
            #pragma unroll
            for (int ic = 0; ic < 8; ic++) {
                float v = supg[(size_t)ic * HW + addr];
                tile[ic][r][u] = ok ? v : 0.f;
            }
        }
    }
    __syncthreads();

    int wv = t >> 6;
    int ca = __builtin_amdgcn_readfirstlane(grp * 8 + wv);       // channel A
    int cb = __builtin_amdgcn_readfirstlane(grp * 8 + 4 + wv);   // channel B
    int lane = t & 63;
    int ty4 = lane >> 3, tx4 = lane & 7;
    int py0 = ty4 * 4, x0r = tx4 * 4;

    float acc[2][4][4];
    float bza = bias[ca], bzb = bias[cb];
    #pragma unroll
    for (int jr = 0; jr < 4; jr++)
        #pragma unroll
        for (int j = 0; j < 4; j++) { acc[0][jr][j] = bza; acc[1][jr][j] = bzb; }

    const float* wpa = w + ca * 72;
    const float* wpb = w + cb * 72;
    for (int ic = 0; ic < 8; ic++) {
        float wra[9], wrb[9];
        #pragma unroll
        for (int q = 0; q < 9; q++) { wra[q] = wpa[ic * 9 + q]; wrb[q] = wpb[ic * 9 + q]; }
        #pragma unroll
        for (int rr = 0; rr < 6; rr++) {
            float4 fa = *(const float4*)&tile[ic][py0 + rr][x0r];
            float4 fb4 = *(const float4*)&tile[ic][py0 + rr][x0r + 4];
            float f[6] = {fa.x, fa.y, fa.z, fa.w, fb4.x, fb4.y};
            #pragma unroll
            for (int ky = 0; ky < 3; ky++) {
                int jr = rr - ky;
                if (jr >= 0 && jr < 4) {
                    #pragma unroll
                    for (int j = 0; j < 4; j++) {
                        acc[0][jr][j] += wra[ky*3]*f[j] + wra[ky*3+1]*f[j+1] + wra[ky*3+2]*f[j+2];
                        acc[1][jr][j] += wrb[ky*3]*f[j] + wrb[ky*3+1]*f[j+1] + wrb[ky*3+2]*f[j+2];
                    }
                }
            }
        }
    }

    #pragma unroll
    for (int s = 0; s < 2; s++) {
        int c = s ? cb : ca;
        unsigned short* op = smoothB + ((size_t)(b * 64 + c) * 96 + Y0 + py0) * 96 + X0 + x0r;
        #pragma unroll
        for (int jr = 0; jr < 4; jr++) {
            ushort4 st = {f2bf(acc[s][jr][0]), f2bf(acc[s][jr][1]),
                          f2bf(acc[s][jr][2]), f2bf(acc[s][jr][3])};
            *(ushort4*)(op + (size_t)jr * 96) = st;
        }
    }
}

// ---------- 1x1 reduce conv (128->64) as bf16 MFMA; sup2 out bf16 NHWC ----------
__global__ __launch_bounds__(256) void reduce_mfma(
    const __hip_bfloat16* __restrict__ fB, const unsigned short* __restrict__ smoothB,
    const unsigned short* __restrict__ rwF, const float* __restrict__ rb,
    unsigned short* __restrict__ sup2B)
{
    __shared__ __align__(16) unsigned short A[64 * 136];
    int t = threadIdx.x;
    int gpx0 = blockIdx.x * 64;
    int b = gpx0 / HW, rem0 = gpx0 - b * HW;
    const unsigned short* fBu = (const unsigned short*)fB;

    #pragma unroll
    for (int it = 0; it < 2; it++) {
        int e = it * 256 + t;
        int px = e >> 3, seg = e & 7;
        short8 v = *(const short8*)(fBu + ((size_t)(gpx0 + px) << 8) + seg * 8);
        *(short8*)&A[px * 136 + seg * 8] = v;
    }
    // smooth half: bf16 already -> raw ushort copy, 128 B/wave coalesced
    #pragma unroll
    for (int it = 0; it < 16; it++) {
        int e = it * 256 + t;
        int px = e & 63, ci = e >> 6;
        A[px * 136 + 64 + ci] = smoothB[(size_t)(b * 64 + ci) * HW + rem0 + px];
    }
    __syncthreads();

    int lane = t & 63, wv = t >> 6;
    int lm = lane & 15, quad = lane >> 4;
    f32x4 acc[4] = {};
    #pragma unroll
    for (int kf = 0; kf < 4; kf++) {
        short8 a = *(const short8*)&A[(wv * 16 + lm) * 136 + kf * 32 + quad * 8];
        #pragma unroll
        for (int nt = 0; nt < 4; nt++) {
            short8 bfr = *(const short8*)&rwF[((nt * 4 + kf) * 64 + lane) * 8];
            acc[nt] = __builtin_amdgcn_mfma_f32_16x16x32_bf16(a, bfr, acc[nt], 0, 0, 0);
        }
    }
    #pragma unroll
    for (int nt = 0; nt < 4; nt++)
        #pragma unroll
        for (int r = 0; r < 4; r++) {
            int px = wv * 16 + quad * 4 + r;
            int co = nt * 16 + lm;
            sup2B[(size_t)(gpx0 + px) * 64 + co] = f2bf(acc[nt][r] + rb[co]);
        }
}

// ---------- fused 3-level neighborhood attention (MFMA QK dots) ----------
template<int KS>
__device__ __forceinline__ void level_softmax(int qc, int y, int x, int ty0, int tx0,
        const _Float16* rpbl, const _Float16* dots_row, _Float16* out_row, bool inplace)
{
    constexpr int R = KS / 2, KK = KS * KS, NB = 2 * KS - 1;
    constexpr int NE = (KK + 7) / 8;
    int ni = min(max(y - R, 0), 96 - KS), nj = min(max(x - R, 0), 96 - KS);
    int lyL = ni - (ty0 - 3), lxL = nj - (tx0 - 3);
    int br = KS - 1 + ni - y, bc = KS - 1 + nj - x;
    float sv[NE];
    float mx = -1e30f;
    #pragma unroll
    for (int i = 0; i < NE; i++) {
        int e = qc + i * 8;
        if (e < KK) {
            int ey = e / KS, ex = e - ey * KS;
            float s = (float)dots_row[(lyL + ey) * 14 + lxL + ex] + (float)rpbl[(br + ey) * NB + bc + ex];
            sv[i] = s; mx = fmaxf(mx, s);
        } else sv[i] = -1e30f;
    }
    mx = fmaxf(mx, __shfl_xor(mx, 8)); mx = fmaxf(mx, __shfl_xor(mx, 16)); mx = fmaxf(mx, __shfl_xor(mx, 32));
    float sum = 0.f;
    #pragma unroll
    for (int i = 0; i < NE; i++) { sv[i] = __expf(sv[i] - mx); sum += sv[i]; }
    sum += __shfl_xor(sum, 8); sum += __shfl_xor(sum, 16); sum += __shfl_xor(sum, 32);
    float inv = 1.f / sum;
    #pragma unroll
    for (int i = 0; i < NE; i++) {
        int e = qc + i * 8;
        if (e < KK) {
            int ey = e / KS, ex = e - ey * KS;
            _Float16 wv16 = (_Float16)(sv[i] * inv);
            if (inplace) ((_Float16*)dots_row)[(lyL + ey) * 14 + lxL + ex] = wv16;
            else out_row[e] = wv16;
        }
    }
}

__global__ __launch_bounds__(256) void natten_fused(
    const __hip_bfloat16* __restrict__ qB, const unsigned short* __restrict__ sup2B,
    const unsigned short* __restrict__ vwF,
    const float* __restrict__ vb0, const float* __restrict__ vb1, const float* __restrict__ vb2,
    const float* __restrict__ rpb0, const float* __restrict__ rpb1, const float* __restrict__ rpb2,
    __hip_bfloat16* __restrict__ fused)
{
    __shared__ __align__(16) unsigned short khalo[140 * 72];
    __shared__ __align__(16) unsigned short qlds[32 * 72];
    __shared__ _Float16 dotsF[32][148];
    __shared__ _Float16 a3[32][12];
    __shared__ _Float16 a5[32][28];
    __shared__ _Float16 rlds[276];

    int t = threadIdx.x;
    int bb = blockIdx.y;
    int tx0 = (blockIdx.x % 12) * 8, ty0 = (blockIdx.x / 12) * 4;
    const unsigned short* kbB = sup2B + (size_t)bb * HW * 64;

    for (int e = t; e < 275; e += 256) {
        float v = (e < 169) ? rpb2[e] : ((e < 250) ? rpb1[e - 169] : rpb0[e - 250]);
        rlds[e] = (_Float16)v;
    }

    #pragma unroll
    for (int it = 0; it < 5; it++) {
        int e = it * 256 + t;
        if (e < 1120) {
            int seg = e & 7, pos = e >> 3;
            int py = pos / 14, pxx = pos - py * 14;
            int gy = min(max(ty0 - 3 + py, 0), 95);
            int gx = min(max(tx0 - 3 + pxx, 0), 95);
            short8 v = *(const short8*)(kbB + (((size_t)gy * 96 + gx) << 6) + seg * 8);
            *(short8*)&khalo[pos * 72 + seg * 8] = v;
        }
    }
    if (t < 256) {
        int px = t >> 3, seg = t & 7;
        short8 v = *(const short8*)((const unsigned short*)qB +
            ((size_t)(bb * HW + (ty0 + (px >> 3)) * 96 + tx0 + (px & 7)) << 6) + seg * 8);
        *(short8*)&qlds[px * 72 + seg * 8] = v;
    }
    __syncthreads();

    int lane = t & 63, wv = t >> 6;
    int lm = lane & 15, quad = lane >> 4;

    #pragma unroll
    for (int ni = 0; ni < 3; ni++) {
        int nt = wv + ni * 4;
        if (nt <= 8) {
            int hp = nt * 16 + lm;
            int hpr = min(hp, 139);
            f32x4 acc0 = {0.f, 0.f, 0.f, 0.f}, acc1 = {0.f, 0.f, 0.f, 0.f};
            #pragma unroll
            for (int kt = 0; kt < 2; kt++) {
                short8 bfrag = *(const short8*)&khalo[hpr * 72 + kt * 32 + quad * 8];
                short8 a0 = *(const short8*)&qlds[lm * 72 + kt * 32 + quad * 8];
                short8 a1 = *(const short8*)&qlds[(16 + lm) * 72 + kt * 32 + quad * 8];
                acc0 = __builtin_amdgcn_mfma_f32_16x16x32_bf16(a0, bfrag, acc0, 0, 0, 0);
                acc1 = __builtin_amdgcn_mfma_f32_16x16x32_bf16(a1, bfrag, acc1, 0, 0, 0);
            }
            if (hp < 140) {
                #pragma unroll
                for (int r = 0; r < 4; r++) {
                    dotsF[quad * 4 + r][hp]      = (_Float16)acc0[r];
                    dotsF[16 + quad * 4 + r][hp] = (_Float16)acc1[r];
                }
            }
        }
    }
    __syncthreads();

    int pxl = wv * 8 + (lane & 7);
    int qc = lane >> 3;
    int pty = pxl >> 3, ptx = pxl & 7;
    int y = ty0 + pty, x = tx0 + ptx;

    int ni7 = min(max(y - 3, 0), 89), nj7 = min(max(x - 3, 0), 89);
    int ly = ni7 - (ty0 - 3), lx = nj7 - (tx0 - 3);

    level_softmax<3>(qc, y, x, ty0, tx0, rlds + 250, &dotsF[pxl][0], &a3[pxl][0], false);
    level_softmax<5>(qc, y, x, ty0, tx0, rlds + 169, &dotsF[pxl][0], &a5[pxl][0], false);
    level_softmax<7>(qc, y, x, ty0, tx0, rlds,       &dotsF[pxl][0], nullptr,     true);

    int ni5 = min(max(y - 2, 0), 91), nj5 = min(max(x - 2, 0), 91);
    int ni3 = min(max(y - 1, 0), 93), nj3 = min(max(x - 1, 0), 93);
    int di5 = ni5 - ni7, dj5 = nj5 - nj7, di3 = ni3 - ni7, dj3 = nj3 - nj7;

    float s2[3][8];
    #pragma unroll
    for (int l = 0; l < 3; l++)
        #pragma unroll
        for (int j = 0; j < 8; j++) s2[l][j] = 0.f;

    #pragma unroll 1
    for (int oy = 0; oy < 7; oy++) {
        #pragma unroll
        for (int ox = 0; ox < 7; ox++) {
            const unsigned short* kp = &khalo[((ly + oy) * 14 + lx + ox) * 72 + qc * 8];
            uint4 ka = *(const uint4*)kp;
            float kv[8] = {bfl(ka.x), bfh(ka.x), bfl(ka.y), bfh(ka.y),
                           bfl(ka.z), bfh(ka.z), bfl(ka.w), bfh(ka.w)};
            float w7 = (float)dotsF[pxl][(ly + oy) * 14 + lx + ox];
            #pragma unroll
            for (int j = 0; j < 8; j++) s2[2][j] += w7 * kv[j];
            int e5y = oy - di5, e5x = ox - dj5;
            if ((unsigned)e5y < 5u && (unsigned)e5x < 5u) {
                float w5 = (float)a5[pxl][e5y * 5 + e5x];
                #pragma unroll
                for (int j = 0; j < 8; j++) s2[1][j] += w5 * kv[j];
            }
            int e3y = oy - di3, e3x = ox - dj3;
            if ((unsigned)e3y < 3u && (unsigned)e3x < 3u) {
                float w3 = (float)a3[pxl][e3y * 3 + e3x];
                #pragma unroll
                for (int j = 0; j < 8; j++) s2[0][j] += w3 * kv[j];
            }
        }
    }
    __syncthreads();

    unsigned short* sproj = khalo;
    #pragma unroll
    for (int l = 0; l < 3; l++) {
        unsigned int pk[4];
        #pragma unroll
        for (int j = 0; j < 4; j++)
            pk[j] = (unsigned int)f2bf(s2[l][2*j]) | ((unsigned int)f2bf(s2[l][2*j+1]) << 16);
        uint4 sv = {pk[0], pk[1], pk[2], pk[3]};
        *(uint4*)&sproj[(l * 32 + pxl) * 72 + qc * 8] = sv;
    }
    __syncthreads();

    if (wv < 3) {
        int l = wv;
        const float* vbl = (l == 0) ? vb0 : ((l == 1) ? vb1 : vb2);
        #pragma unroll
        for (int mt = 0; mt < 2; mt++) {
            f32x4 acc[4];
            #pragma unroll
            for (int nt = 0; nt < 4; nt++) acc[nt] = (f32x4){0.f, 0.f, 0.f, 0.f};
            #pragma unroll
            for (int kf = 0; kf < 2; kf++) {
                short8 a = *(const short8*)&sproj[(l * 32 + mt * 16 + lm) * 72 + kf * 32 + quad * 8];
                #pragma unroll
                for (int nt = 0; nt < 4; nt++) {
                    short8 bfr = *(const short8*)&vwF[(((l * 4 + nt) * 2 + kf) * 64 + lane) * 8];
                    acc[nt] = __builtin_amdgcn_mfma_f32_16x16x32_bf16(a, bfr, acc[nt], 0, 0, 0);
                }
            }
            #pragma unroll
            for (int nt = 0; nt < 4; nt++)
                #pragma unroll
                for (int r = 0; r < 4; r++) {
                    int p = mt * 16 + quad * 4 + r;
                    int co = nt * 16 + lm;
                    int py = p >> 3, pxx = p & 7;
                    size_t off = ((size_t)(bb * HW + (ty0 + py) * 96 + tx0 + pxx) << 8) + (l + 1) * 64 + co;
                    fused[off] = __hip_bfloat16(acc[nt][r] + vbl[co]);
                }
        }
    }
}

// ---------- 3x3 fusion conv (256->64): 16x4 tile, 128 thr, 2 m-tiles/wave ----------
__global__ __launch_bounds__(128) void fusion_mfma(
    const __hip_bfloat16* __restrict__ fB, const unsigned short* __restrict__ fwF,
    const float* __restrict__ fb, float* __restrict__ out)
{
    __shared__ __align__(16) unsigned char smem[16896];
    unsigned short* ah = (unsigned short*)smem;          // [108 px][72]
    float* lds_out = (float*)smem;                       // [64 co][66]
    int t = threadIdx.x;
    int wv = t >> 6, lane = t & 63, lm = lane & 15, quad = lane >> 4;
    int X0 = blockIdx.x * 16, Y0 = blockIdx.y * 4, b = blockIdx.z;
    const unsigned short* fBu = (const unsigned short*)fB;

    f32x4 acc[2][4] = {};

    for (int chunk = 0; chunk < 4; chunk++) {
        __syncthreads();
        #pragma unroll
        for (int ee = 0; ee < 7; ee++) {
            int e = ee * 128 + t;
            if (e < 864) {
                int seg = e & 7, hp = e >> 3;
                int hy = hp / 18, hx = hp - hy * 18;
                int gy = Y0 - 1 + hy, gx = X0 - 1 + hx;
                bool ok = (gy >= 0) & (gy < 96) & (gx >= 0) & (gx < 96);
                short8 v = {};
                if (ok) v = *(const short8*)(fBu + (((size_t)(b * HW + gy * 96 + gx)) << 8) + chunk * 64 + seg * 8);
                *(short8*)&ah[hp * 72 + seg * 8] = v;
            }
        }
        __syncthreads();
        #pragma unroll
        for (int ky = 0; ky < 3; ky++) {
            #pragma unroll
            for (int kx = 0; kx < 3; kx++) {
                #pragma unroll
                for (int kf = 0; kf < 2; kf++) {
                    int kc = (ky * 3 + kx) * 8 + chunk * 2 + kf;
                    const unsigned short* bp = fwF + ((size_t)(kc * 4) * 64 + lane) * 8;
                    short8 b0 = *(const short8*)(bp);
                    short8 b1 = *(const short8*)(bp + 512);
                    short8 b2 = *(const short8*)(bp + 1024);
                    short8 b3 = *(const short8*)(bp + 1536);
                    #pragma unroll
                    for (int mt = 0; mt < 2; mt++) {
                        int R = 2 * wv + mt;
                        short8 a = *(const short8*)&ah[((R + ky) * 18 + lm + kx) * 72 + kf * 32 + quad * 8];
                        acc[mt][0] = __builtin_amdgcn_mfma_f32_16x16x32_bf16(a, b0, acc[mt][0], 0, 0, 0);
                        acc[mt][1] = __builtin_amdgcn_mfma_f32_16x16x32_bf16(a, b1, acc[mt][1], 0, 0, 0);
                        acc[mt][2] = __builtin_amdgcn_mfma_f32_16x16x32_bf16(a, b2, acc[mt][2], 0, 0, 0);
                        acc[mt][3] = __builtin_amdgcn_mfma_f32_16x16x32_bf16(a, b3, acc[mt][3], 0, 0, 0);
                    }
                }
            }
        }
    }

    __syncthreads();
    #pragma unroll
    for (int mt = 0; mt < 2; mt++)
        #pragma unroll
        for (int nt = 0; nt < 4; nt++)
            #pragma unroll
            for (int r = 0; r < 4; r++) {
                int p = (2 * wv + mt) * 16 + quad * 4 + r;
                int co = nt * 16 + lm;
                lds_out[co * 66 + p] = acc[mt][nt][r];
            }
    __syncthreads();

    int p2 = t & 63, py = p2 >> 4, px2 = p2 & 15;
    float* ob = out + ((size_t)(b * 64) * 96 + Y0 + py) * 96 + X0 + px2;
    #pragma unroll 4
    for (int i = 0; i < 32; i++) {
        int co = (t >> 6) * 32 + i;
        float v = lds_out[co * 66 + p2] + fb[co];
        ob[(size_t)co * HW] = v > 0.f ? v : 0.f;
    }
}

extern "C" void kernel_launch(void* const* d_in, const int* in_sizes, int n_in,
                              void* d_out, int out_size, void* d_ws, size_t ws_size,
                              hipStream_t stream) {
    const float* sup = (const float*)d_in[0];
    const float* key = (const float*)d_in[1];
    const float* smw = (const float*)d_in[2];
    const float* smb = (const float*)d_in[3];
    const float* rw  = (const float*)d_in[4];
    const float* rb  = (const float*)d_in[5];
    const float *vw[3], *vb[3], *rpb[3];
    if (in_sizes[8] == 25) {
        for (int l = 0; l < 3; l++) {
            vw[l]  = (const float*)d_in[6 + 3 * l];
            vb[l]  = (const float*)d_in[7 + 3 * l];
            rpb[l] = (const float*)d_in[8 + 3 * l];
        }
    } else {
        for (int l = 0; l < 3; l++) {
            vw[l]  = (const float*)d_in[6 + 2 * l];
            vb[l]  = (const float*)d_in[7 + 2 * l];
            rpb[l] = (const float*)d_in[12 + l];
        }
    }
    const float* fw = (const float*)d_in[15];
    const float* fb = (const float*)d_in[16];
    float* out = (float*)d_out;

    float* wsf    = (float*)d_ws;
    unsigned short* smoothB = (unsigned short*)wsf;            // 2359296 bf16 (NCHW)
    unsigned short* sup2B = (unsigned short*)(wsf + 2359296);  // 2359296 bf16 (NHWC)
    __hip_bfloat16* qBuf = (__hip_bfloat16*)(wsf + 4718592);   // 2359296 bf16
    unsigned short* rwF = (unsigned short*)(wsf + 7077888);    // 8192 bf16
    unsigned short* vwF = (unsigned short*)(wsf + 7086080);    // 12288 bf16
    __hip_bfloat16* fusedB = (__hip_bfloat16*)(wsf + 7092224);  // 9437184 bf16
    unsigned short* fwF    = (unsigned short*)(wsf + 11810816); // 147456 bf16

    pack_kernel<<<dim3(3, 2, 384), dim3(32, 8), 0, stream>>>(key, sup, qBuf, fusedB,
        rw, vw[0], vw[1], vw[2], fw, rwF, vwF, fwF);
    shift_smooth<<<dim3(288), dim3(256), 0, stream>>>(sup, smw, smb, smoothB);
    reduce_mfma<<<dim3(576), dim3(256), 0, stream>>>(fusedB, smoothB, rwF, rb, sup2B);
    natten_fused<<<dim3(288, 4), dim3(256), 0, stream>>>(qBuf, sup2B, vwF,
        vb[0], vb[1], vb[2], rpb[0], rpb[1], rpb[2], fusedB);
    fusion_mfma<<<dim3(6, 24, 4), dim3(128), 0, stream>>>(fusedB, fwF, fb, out);
}